// Round 5
// baseline (5178.919 us; speedup 1.0000x reference)
//
#include <hip/hip_runtime.h>
#include <hip/hip_bf16.h>
#include <math.h>

typedef unsigned int   u32;
typedef unsigned short u16;
typedef __bf16 bf16x8 __attribute__((ext_vector_type(8)));
typedef float  f32x4  __attribute__((ext_vector_type(4)));
typedef u16    u16x8  __attribute__((ext_vector_type(8)));

constexpr int BB = 32, DD = 768, LL = 197, HH = 12, NTOK = 196;
constexpr int MROWS = BB * LL;        // 6304
constexpr int MTOK  = BB * NTOK;      // 6272

__device__ __forceinline__ u16 f2bf(float f) {
    union { float f; u32 u; } v; v.f = f;
    u32 r = v.u + 0x7fff + ((v.u >> 16) & 1);
    return (u16)(r >> 16);
}
__device__ __forceinline__ float bf2f(u16 u) {
    union { u32 u; float f; } v; v.u = ((u32)u) << 16;
    return v.f;
}

#define AS1 __attribute__((address_space(1)))
#define AS3 __attribute__((address_space(3)))
__device__ __forceinline__ void gload_lds16(const void* g, void* l) {
    __builtin_amdgcn_global_load_lds((const AS1 u32*)g, (AS3 u32*)l, 16, 0, 0);
}

// ---------------------------------------------------------------------------
__global__ void cast_kernel(const float* __restrict__ in, u16* __restrict__ out, int n)
{
    int i4 = (blockIdx.x * 256 + threadIdx.x) * 4;
    if (i4 >= n) return;
    float4 v = *reinterpret_cast<const float4*>(in + i4);
    out[i4]   = f2bf(v.x); out[i4+1] = f2bf(v.y);
    out[i4+2] = f2bf(v.z); out[i4+3] = f2bf(v.w);
}

__global__ void cast4_kernel(const float* s0, int n0, const float* s1, int n1,
                             const float* s2, int n2, const float* s3, int n3,
                             u16* d0, u16* d1, u16* d2, u16* d3)
{
    int i4 = (blockIdx.x * 256 + threadIdx.x) * 4;
    const float* s; u16* d; int off;
    if      (i4 < n0)            { s = s0; d = d0; off = i4; }
    else if (i4 < n0+n1)         { s = s1; d = d1; off = i4 - n0; }
    else if (i4 < n0+n1+n2)      { s = s2; d = d2; off = i4 - n0 - n1; }
    else if (i4 < n0+n1+n2+n3)   { s = s3; d = d3; off = i4 - n0 - n1 - n2; }
    else return;
    float4 v = *reinterpret_cast<const float4*>(s + off);
    d[off]   = f2bf(v.x); d[off+1] = f2bf(v.y);
    d[off+2] = f2bf(v.z); d[off+3] = f2bf(v.w);
}

// ---------------------------------------------------------------------------
__global__ void patchify_kernel(const float* __restrict__ src, int C,
                                u16* __restrict__ out, int total)
{
    int idx = blockIdx.x * 256 + threadIdx.x;
    if (idx >= total) return;
    int K = C * 256;
    int row = idx / K, k = idx % K;
    int b = row / NTOK, n = row % NTOK;
    int c = k >> 8, rem = k & 255, pi = rem >> 4, pj = rem & 15;
    int i14 = n / 14, j14 = n % 14;
    float v = src[(((size_t)b * C + c) * 224 + i14 * 16 + pi) * 224 + j14 * 16 + pj];
    out[idx] = f2bf(v);
}

// ---------------------------------------------------------------------------
// bf16 MFMA GEMM, 128x64 tile, BK=64, 4 waves (2Mx2N, 64x32 each), 16x16x32.
// LDS per tile: elem(R,k) = (R>>4)*1024 + (k>>3)*128 + (R&15)*8 + (k&7)
//   staged via global_load_lds units of 512 elems (unit u covers seg u>>1,
//   col-half u&1; lane l -> row lo, col half*32+hi*8; dest = u*512 + l*8 —
//   exactly linear, so the DMA lane-order matches the layout).
//   fragment ds_read_b128 banks = lo*4 mod 32 -> 2-way (free).
// Double-buffered: STAGE(next) issued before COMPUTE(cur), 1 barrier/K-step.
// XCD-bijective block swizzle for A-panel L2 locality.
// MODE 0: f32 out +bias      MODE 1: GELU -> bf16 out, +bias
// MODE 2: f32 out +bias+res  MODE 3: batched bias-GEMM    MODE 4: bf16 +bias
// ---------------------------------------------------------------------------
template<int MODE>
__global__ __launch_bounds__(256) void gemm_bf16(
    const u16* __restrict__ A, const u16* __restrict__ W,
    const float* __restrict__ bias, const float* __restrict__ res,
    void* __restrict__ Cout, int M, int N, int K, long long strideA)
{
    __shared__ u16 As[2][8192];   // 128 x 64
    __shared__ u16 Bs[2][4096];   // 64 x 64
    const int tid  = threadIdx.x;
    const int wave = tid >> 6, lane = tid & 63;
    const int lo = lane & 15, hi = lane >> 4;
    const int wr = wave >> 1, wc = wave & 1;

    // bijective XCD swizzle (m204)
    const int gx = gridDim.x;
    const int nwg = gx * gridDim.y;
    int wg = blockIdx.y * gx + blockIdx.x;
    {
        int q = nwg >> 3, r = nwg & 7;
        int xcd = wg & 7, idx = wg >> 3;
        wg = (xcd < r ? xcd * (q + 1) : r * (q + 1) + (xcd - r) * q) + idx;
    }
    const int m0 = (wg / gx) * 128, n0 = (wg % gx) * 64;
    if (MODE == 3) { A += blockIdx.z * strideA; W += blockIdx.z * strideA; }

    const int limA = M - 1;
    const int limB = (MODE == 3 ? M : N) - 1;

    // per-unit global base pointers (unit u = wave + 4*t)
    const u16* Aptr[4];
    const u16* Bptr[2];
    #pragma unroll
    for (int t = 0; t < 4; ++t) {
        int u = wave + 4 * t;
        int r = m0 + (u >> 1) * 16 + lo; if (r > limA) r = limA;
        Aptr[t] = A + (size_t)r * K + (u & 1) * 32 + hi * 8;
    }
    #pragma unroll
    for (int t = 0; t < 2; ++t) {
        int u = wave + 4 * t;
        int r = n0 + (u >> 1) * 16 + lo; if (r > limB) r = limB;
        Bptr[t] = W + (size_t)r * K + (u & 1) * 32 + hi * 8;
    }

    f32x4 acc[4][2] = {};

    #define STAGE(bf_, k0_)                                                 \
        do {                                                                \
            _Pragma("unroll")                                               \
            for (int t = 0; t < 4; ++t)                                     \
                gload_lds16(Aptr[t] + (k0_), &As[bf_][(wave + 4 * t) * 512]);\
            _Pragma("unroll")                                               \
            for (int t = 0; t < 2; ++t)                                     \
                gload_lds16(Bptr[t] + (k0_), &Bs[bf_][(wave + 4 * t) * 512]);\
        } while (0)

    #define COMPUTE(bf_)                                                        \
        do {                                                                    \
            _Pragma("unroll")                                                   \
            for (int s = 0; s < 2; ++s) {                                       \
                bf16x8 af[4], bfr[2];                                           \
                _Pragma("unroll")                                               \
                for (int i = 0; i < 4; ++i)                                     \
                    af[i] = *reinterpret_cast<const bf16x8*>(                   \
                        &As[bf_][(wr * 4 + i) * 1024 + (s * 4 + hi) * 128 + lo * 8]); \
                _Pragma("unroll")                                               \
                for (int j = 0; j < 2; ++j)                                     \
                    bfr[j] = *reinterpret_cast<const bf16x8*>(                  \
                        &Bs[bf_][(wc * 2 + j) * 1024 + (s * 4 + hi) * 128 + lo * 8]); \
                _Pragma("unroll")                                               \
                for (int i = 0; i < 4; ++i)                                     \
                    _Pragma("unroll")                                           \
                    for (int j = 0; j < 2; ++j)                                 \
                        acc[i][j] = __builtin_amdgcn_mfma_f32_16x16x32_bf16(    \
                            af[i], bfr[j], acc[i][j], 0, 0, 0);                 \
            }                                                                   \
        } while (0)

    STAGE(0, 0);
    __syncthreads();
    int buf = 0;
    for (int k0 = 64; k0 < K; k0 += 64) {
        STAGE(buf ^ 1, k0);      // prefetch next K-tile (overlaps compute)
        COMPUTE(buf);
        __syncthreads();
        buf ^= 1;
    }
    COMPUTE(buf);
    #undef STAGE
    #undef COMPUTE

    const int cr = hi * 4;
    #pragma unroll
    for (int i = 0; i < 4; ++i) {
        #pragma unroll
        for (int r = 0; r < 4; ++r) {
            int m = m0 + wr * 64 + i * 16 + cr + r;
            if (MODE != 3 && m >= M) continue;
            #pragma unroll
            for (int j = 0; j < 2; ++j) {
                int n = n0 + wc * 32 + j * 16 + lo;
                float v = acc[i][j][r];
                if (MODE == 0) {
                    ((float*)Cout)[(size_t)m * N + n] = v + bias[n];
                } else if (MODE == 1) {
                    float t = v + bias[n];
                    t = 0.5f * t * (1.f + erff(t * 0.70710678118654752f));
                    ((u16*)Cout)[(size_t)m * N + n] = f2bf(t);
                } else if (MODE == 2) {
                    ((float*)Cout)[(size_t)m * N + n] = v + bias[n] + res[(size_t)m * N + n];
                } else if (MODE == 4) {
                    ((u16*)Cout)[(size_t)m * N + n] = f2bf(v + bias[n]);
                } else { // MODE 3
                    if (m < M && n < M) {
                        float* C3 = (float*)Cout + (size_t)blockIdx.z * LL * LL;
                        C3[(size_t)(m + 1) * LL + (n + 1)] = v * 0.03608439182435161f;
                    }
                }
            }
        }
    }
}

__global__ void bias_edge_kernel(float* __restrict__ bias)
{
    int b = blockIdx.x, t = threadIdx.x;
    if (t < LL) {
        bias[((size_t)b * LL + 0) * LL + t] = 0.f;
        bias[((size_t)b * LL + t) * LL + 0] = 0.f;
    }
}

// ---------------------------------------------------------------------------
__global__ void combine_kernel(
    const float* __restrict__ toki, const float* __restrict__ tokm,
    const float* __restrict__ cls, const float* __restrict__ pos,
    float* __restrict__ x)
{
    size_t idx = (size_t)blockIdx.x * 256 + threadIdx.x;
    if (idx >= (size_t)MROWS * DD) return;
    int d = (int)(idx % DD);
    size_t bl = idx / DD;
    int l = (int)(bl % LL);
    int b = (int)(bl / LL);
    float v;
    if (l == 0) v = cls[d];
    else {
        size_t tix = ((size_t)b * NTOK + (l - 1)) * DD + d;
        v = toki[tix] + 0.5f * tokm[tix];
    }
    x[idx] = v + pos[(size_t)l * DD + d];
}

// ---------------------------------------------------------------------------
template<int OUT>
__global__ __launch_bounds__(256) void ln_kernel(
    const float* __restrict__ in, const float* __restrict__ g,
    const float* __restrict__ beta, float* __restrict__ outf,
    u16* __restrict__ outb)
{
    int row = blockIdx.x;
    int tid = threadIdx.x;
    const float* xr = in + (size_t)row * DD;
    float v[3];
    #pragma unroll
    for (int r = 0; r < 3; ++r) v[r] = xr[tid + r * 256];
    __shared__ float red[256];
    red[tid] = v[0] + v[1] + v[2];
    __syncthreads();
    for (int off = 128; off; off >>= 1) {
        if (tid < off) red[tid] += red[tid + off];
        __syncthreads();
    }
    float mean = red[0] * (1.f / 768.f);
    __syncthreads();
    float q = 0.f;
    #pragma unroll
    for (int r = 0; r < 3; ++r) { float dv = v[r] - mean; q += dv * dv; }
    red[tid] = q;
    __syncthreads();
    for (int off = 128; off; off >>= 1) {
        if (tid < off) red[tid] += red[tid + off];
        __syncthreads();
    }
    float rstd = rsqrtf(red[0] * (1.f / 768.f) + 1e-5f);
    #pragma unroll
    for (int r = 0; r < 3; ++r) {
        int d = tid + r * 256;
        float o = g[d] * (v[r] - mean) * rstd + beta[d];
        if (OUT == 0 || OUT == 2) outf[(size_t)row * DD + d] = o;
        if (OUT == 1 || OUT == 2) outb[(size_t)row * DD + d] = f2bf(o);
    }
}

// ---------------------------------------------------------------------------
// MFMA attention (unchanged)
// ---------------------------------------------------------------------------
constexpr int KSTRE = 72;
constexpr int VSTRE = 232;
constexpr int PSTRE = 232;

__global__ __launch_bounds__(256) void attn_mfma_kernel(
    const u16* __restrict__ qkv, const float* __restrict__ bias,
    u16* __restrict__ o)
{
    const int h = blockIdx.x, b = blockIdx.y;
    const int tid = threadIdx.x, wave = tid >> 6, lane = tid & 63;
    const int lo = lane & 15, hi = lane >> 4;

    __shared__ u16 Ks[208 * KSTRE];
    __shared__ u16 Vt[64 * VSTRE];
    __shared__ u16 Ps[4][16 * PSTRE];

    const u16* qb = qkv + (size_t)b * LL * 2304;

    for (int idx = tid; idx < 208 * 8; idx += 256) {
        int key = idx >> 3, c8 = idx & 7;
        u16x8 v = {};
        if (key < LL) v = *reinterpret_cast<const u16x8*>(qb + (size_t)key * 2304 + 768 + h * 64 + c8 * 8);
        *reinterpret_cast<u16x8*>(&Ks[key * KSTRE + c8 * 8]) = v;
    }
    for (int idx = tid; idx < 224 * 8; idx += 256) {
        int key = idx >> 3, c8 = idx & 7;
        u16x8 v = {};
        if (key < LL) v = *reinterpret_cast<const u16x8*>(qb + (size_t)key * 2304 + 1536 + h * 64 + c8 * 8);
        #pragma unroll
        for (int e = 0; e < 8; ++e) Vt[(c8 * 8 + e) * VSTRE + key] = v[e];
    }
    __syncthreads();

    u16* P = Ps[wave];
    const float* biasbb = bias + (size_t)b * LL * LL;

    for (int rt = wave; rt < 13; rt += 4) {
        int q = rt * 16 + lo; if (q > LL - 1) q = LL - 1;
        const u16* qrow = qb + (size_t)q * 2304 + h * 64;
        bf16x8 qa0 = *reinterpret_cast<const bf16x8*>(qrow + hi * 8);
        bf16x8 qa1 = *reinterpret_cast<const bf16x8*>(qrow + 32 + hi * 8);

        f32x4 st[13];
        #pragma unroll
        for (int t = 0; t < 13; ++t) {
            int keyc = t * 16 + lo;
            bf16x8 kb0 = *reinterpret_cast<const bf16x8*>(&Ks[keyc * KSTRE + hi * 8]);
            bf16x8 kb1 = *reinterpret_cast<const bf16x8*>(&Ks[keyc * KSTRE + 32 + hi * 8]);
            f32x4 a = {};
            a = __builtin_amdgcn_mfma_f32_16x16x32_bf16(qa0, kb0, a, 0, 0, 0);
            a = __builtin_amdgcn_mfma_f32_16x16x32_bf16(qa1, kb1, a, 0, 0, 0);
            st[t] = a;
        }

        #pragma unroll
        for (int r = 0; r < 4; ++r) {
            int qq = rt * 16 + hi * 4 + r;
            int qc = qq > LL - 1 ? LL - 1 : qq;
            const float* brow = biasbb + (size_t)qc * LL;
            float s[13];
            float m = -1e30f;
            #pragma unroll
            for (int t = 0; t < 13; ++t) {
                int col = t * 16 + lo;
                float v;
                if (col < LL) v = st[t][r] * 0.125f + brow[col];
                else          v = -1e30f;
                s[t] = v;
                m = fmaxf(m, v);
            }
            m = fmaxf(m, __shfl_xor(m, 1));
            m = fmaxf(m, __shfl_xor(m, 2));
            m = fmaxf(m, __shfl_xor(m, 4));
            m = fmaxf(m, __shfl_xor(m, 8));
            float sum = 0.f;
            #pragma unroll
            for (int t = 0; t < 13; ++t) { float e = __expf(s[t] - m); s[t] = e; sum += e; }
            sum += __shfl_xor(sum, 1);
            sum += __shfl_xor(sum, 2);
            sum += __shfl_xor(sum, 4);
            sum += __shfl_xor(sum, 8);
            float inv = 1.f / sum;
            int prow = (hi * 4 + r) * PSTRE;
            #pragma unroll
            for (int t = 0; t < 13; ++t) P[prow + t * 16 + lo] = f2bf(s[t] * inv);
            P[prow + 208 + lo] = 0;
        }

        f32x4 oacc[4] = {};
        #pragma unroll
        for (int kt = 0; kt < 7; ++kt) {
            bf16x8 pa = *reinterpret_cast<const bf16x8*>(&P[lo * PSTRE + kt * 32 + hi * 8]);
            #pragma unroll
            for (int dt = 0; dt < 4; ++dt) {
                bf16x8 vb = *reinterpret_cast<const bf16x8*>(&Vt[(dt * 16 + lo) * VSTRE + kt * 32 + hi * 8]);
                oacc[dt] = __builtin_amdgcn_mfma_f32_16x16x32_bf16(pa, vb, oacc[dt], 0, 0, 0);
            }
        }

        #pragma unroll
        for (int dt = 0; dt < 4; ++dt) {
            #pragma unroll
            for (int r = 0; r < 4; ++r) {
                int qq = rt * 16 + hi * 4 + r;
                if (qq < LL)
                    o[((size_t)(b * LL + qq)) * DD + h * 64 + dt * 16 + lo] = f2bf(oacc[dt][r]);
            }
        }
    }
}

// ---------------------------------------------------------------------------
__global__ __launch_bounds__(256) void final_kernel(
    const float* __restrict__ x,
    const float* __restrict__ eg, const float* __restrict__ eb,
    const float* __restrict__ fg, const float* __restrict__ fb,
    const float* __restrict__ hw, const float* __restrict__ hb,
    float* __restrict__ out)
{
    int b = blockIdx.x;
    int tid = threadIdx.x;
    __shared__ float xs[768];
    __shared__ float red[256];
    const float* xr = x + (size_t)b * LL * DD;
    #pragma unroll
    for (int r = 0; r < 3; ++r) xs[tid + r * 256] = xr[tid + r * 256];
    __syncthreads();
    for (int pass = 0; pass < 2; ++pass) {
        const float* g  = pass ? fg : eg;
        const float* bb = pass ? fb : eb;
        red[tid] = xs[tid] + xs[tid + 256] + xs[tid + 512];
        __syncthreads();
        for (int off = 128; off; off >>= 1) {
            if (tid < off) red[tid] += red[tid + off];
            __syncthreads();
        }
        float mean = red[0] * (1.f / 768.f);
        __syncthreads();
        float q = 0.f;
        #pragma unroll
        for (int r = 0; r < 3; ++r) { float dv = xs[tid + r * 256] - mean; q += dv * dv; }
        red[tid] = q;
        __syncthreads();
        for (int off = 128; off; off >>= 1) {
            if (tid < off) red[tid] += red[tid + off];
            __syncthreads();
        }
        float rstd = rsqrtf(red[0] * (1.f / 768.f) + 1e-5f);
        __syncthreads();
        #pragma unroll
        for (int r = 0; r < 3; ++r) {
            int d = tid + r * 256;
            xs[d] = g[d] * (xs[d] - mean) * rstd + bb[d];
        }
        __syncthreads();
    }
    int c = tid >> 6, lane = tid & 63;
    float part = 0.f;
    for (int d = lane; d < 768; d += 64) part += xs[d] * hw[c * 768 + d];
    #pragma unroll
    for (int off = 32; off; off >>= 1) part += __shfl_down(part, off);
    if (lane == 0) out[b * 4 + c] = part + hb[c];
}

// ---------------------------------------------------------------------------
extern "C" void kernel_launch(void* const* d_in, const int* in_sizes, int n_in,
                              void* d_out, int out_size, void* d_ws, size_t ws_size,
                              hipStream_t stream)
{
    const float* img    = (const float*)d_in[0];
    const float* mask   = (const float*)d_in[1];
    const float* pe_iw  = (const float*)d_in[2];
    const float* pe_ib  = (const float*)d_in[3];
    const float* pe_ig  = (const float*)d_in[4];
    const float* pe_ibb = (const float*)d_in[5];
    const float* pe_mw  = (const float*)d_in[6];
    const float* pe_mb  = (const float*)d_in[7];
    const float* pe_mg  = (const float*)d_in[8];
    const float* pe_mbb = (const float*)d_in[9];
    const float* cls    = (const float*)d_in[10];
    const float* pos    = (const float*)d_in[11];
    const float* ln1_g  = (const float*)d_in[12];
    const float* ln1_b  = (const float*)d_in[13];
    const float* w_qkv  = (const float*)d_in[14];
    const float* b_qkv  = (const float*)d_in[15];
    const float* w_out  = (const float*)d_in[16];
    const float* b_out  = (const float*)d_in[17];
    const float* ln2_g  = (const float*)d_in[18];
    const float* ln2_b  = (const float*)d_in[19];
    const float* w_fc1  = (const float*)d_in[20];
    const float* b_fc1  = (const float*)d_in[21];
    const float* w_fc2  = (const float*)d_in[22];
    const float* b_fc2  = (const float*)d_in[23];
    const float* enc_g  = (const float*)d_in[24];
    const float* enc_b  = (const float*)d_in[25];
    const float* fin_g  = (const float*)d_in[26];
    const float* fin_b  = (const float*)d_in[27];
    const float* head_w = (const float*)d_in[28];
    const float* head_b = (const float*)d_in[29];

    char* wsb = (char*)d_ws;
    size_t off = 0;
    auto alloc = [&](size_t bytes) { void* p = wsb + off; off += (bytes + 255) & ~(size_t)255; return p; };

    float* x     = (float*)alloc((size_t)MROWS * DD * 4);
    u16*   qkvb  = (u16*)  alloc((size_t)MROWS * 3 * DD * 2);
    u16*   hbuf  = (u16*)  alloc((size_t)MROWS * DD * 2);
    u16*   fc1b  = (u16*)  alloc((size_t)MROWS * 4 * DD * 2);
    float* biasb = (float*)alloc((size_t)BB * LL * LL * 4);
    u16*   wqb   = (u16*)  alloc((size_t)3 * DD * DD * 2);
    u16*   wob   = (u16*)  alloc((size_t)DD * DD * 2);
    u16*   w1b   = (u16*)  alloc((size_t)4 * DD * DD * 2);
    u16*   w2b   = (u16*)  alloc((size_t)4 * DD * DD * 2);
    float* toki  = (float*)alloc((size_t)MTOK * DD * 4);
    float* tokm  = (float*)alloc((size_t)MTOK * DD * 4);
    u16*   pa    = fc1b;           // patches alias
    float* ttmp  = (float*)qkvb;   // pe-GEMM f32 out alias
    u16*   tokmb = hbuf;           // bf16 tok_m alias

    // ---- patch embed (img) ----
    cast_kernel<<<(DD * DD / 4 + 255) / 256, 256, 0, stream>>>(pe_iw, wob, DD * DD);
    patchify_kernel<<<(MTOK * DD + 255) / 256, 256, 0, stream>>>(img, 3, pa, MTOK * DD);
    gemm_bf16<0><<<dim3(DD / 64, MTOK / 128), 256, 0, stream>>>(
        pa, wob, pe_ib, nullptr, ttmp, MTOK, DD, DD, 0);
    ln_kernel<0><<<MTOK, 256, 0, stream>>>(ttmp, pe_ig, pe_ibb, toki, nullptr);

    // ---- patch embed (mask) ----
    cast_kernel<<<(DD * 256 / 4 + 255) / 256, 256, 0, stream>>>(pe_mw, wob, DD * 256);
    patchify_kernel<<<(MTOK * 256 + 255) / 256, 256, 0, stream>>>(mask, 1, pa, MTOK * 256);
    gemm_bf16<0><<<dim3(DD / 64, MTOK / 128), 256, 0, stream>>>(
        pa, wob, pe_mb, nullptr, ttmp, MTOK, DD, 256, 0);
    ln_kernel<2><<<MTOK, 256, 0, stream>>>(ttmp, pe_mg, pe_mbb, tokm, tokmb);

    // ---- attention bias ----
    gemm_bf16<3><<<dim3(4, 2, BB), 256, 0, stream>>>(
        tokmb, tokmb, nullptr, nullptr, biasb, NTOK, NTOK, DD, (long long)NTOK * DD);
    bias_edge_kernel<<<BB, 256, 0, stream>>>(biasb);

    // ---- combine ----
    combine_kernel<<<(MROWS * DD + 255) / 256, 256, 0, stream>>>(toki, tokm, cls, pos, x);

    const int mblk = (MROWS + 127) / 128;   // 50
    const int wqn = 3 * DD * DD, won = DD * DD, w1n = 4 * DD * DD, w2n = 4 * DD * DD;
    const int castTot = (wqn + won + w1n + w2n) / 4;
    for (int l = 0; l < 12; ++l) {
        cast4_kernel<<<(castTot + 255) / 256, 256, 0, stream>>>(
            w_qkv + (size_t)l * wqn, wqn, w_out + (size_t)l * won, won,
            w_fc1 + (size_t)l * w1n, w1n, w_fc2 + (size_t)l * w2n, w2n,
            wqb, wob, w1b, w2b);
        ln_kernel<1><<<MROWS, 256, 0, stream>>>(x, ln1_g + l * DD, ln1_b + l * DD, nullptr, hbuf);
        gemm_bf16<4><<<dim3(3 * DD / 64, mblk), 256, 0, stream>>>(
            hbuf, wqb, b_qkv + l * 3 * DD, nullptr, qkvb, MROWS, 3 * DD, DD, 0);
        attn_mfma_kernel<<<dim3(HH, BB), 256, 0, stream>>>(qkvb, biasb, hbuf);
        gemm_bf16<2><<<dim3(DD / 64, mblk), 256, 0, stream>>>(
            hbuf, wob, b_out + l * DD, x, x, MROWS, DD, DD, 0);
        ln_kernel<1><<<MROWS, 256, 0, stream>>>(x, ln2_g + l * DD, ln2_b + l * DD, nullptr, hbuf);
        gemm_bf16<1><<<dim3(4 * DD / 64, mblk), 256, 0, stream>>>(
            hbuf, w1b, b_fc1 + l * 4 * DD, nullptr, fc1b, MROWS, 4 * DD, DD, 0);
        gemm_bf16<2><<<dim3(DD / 64, mblk), 256, 0, stream>>>(
            fc1b, w2b, b_fc2 + l * DD, x, x, MROWS, DD, 4 * DD, 0);
    }
    final_kernel<<<BB, 256, 0, stream>>>(x, enc_g, enc_b, fin_g, fin_b, head_w, head_b, (float*)d_out);
}

// Round 7
// 5123.536 us; speedup vs baseline: 1.0108x; 1.0108x over previous
//
#include <hip/hip_runtime.h>
#include <hip/hip_bf16.h>
#include <math.h>

typedef unsigned int   u32;
typedef unsigned short u16;
typedef __bf16 bf16x8 __attribute__((ext_vector_type(8)));
typedef float  f32x4  __attribute__((ext_vector_type(4)));
typedef u16    u16x8  __attribute__((ext_vector_type(8)));

constexpr int BB = 32, DD = 768, LL = 197, HH = 12, NTOK = 196;
constexpr int MROWS = BB * LL;        // 6304
constexpr int MTOK  = BB * NTOK;      // 6272

__device__ __forceinline__ u16 f2bf(float f) {
    union { float f; u32 u; } v; v.f = f;
    u32 r = v.u + 0x7fff + ((v.u >> 16) & 1);
    return (u16)(r >> 16);
}
__device__ __forceinline__ float bf2f(u16 u) {
    union { u32 u; float f; } v; v.u = ((u32)u) << 16;
    return v.f;
}

// ---------------------------------------------------------------------------
__global__ void cast_kernel(const float* __restrict__ in, u16* __restrict__ out, int n)
{
    int i4 = (blockIdx.x * 256 + threadIdx.x) * 4;
    if (i4 >= n) return;
    float4 v = *reinterpret_cast<const float4*>(in + i4);
    out[i4]   = f2bf(v.x); out[i4+1] = f2bf(v.y);
    out[i4+2] = f2bf(v.z); out[i4+3] = f2bf(v.w);
}

__global__ void cast4_kernel(const float* s0, int n0, const float* s1, int n1,
                             const float* s2, int n2, const float* s3, int n3,
                             u16* d0, u16* d1, u16* d2, u16* d3)
{
    int i4 = (blockIdx.x * 256 + threadIdx.x) * 4;
    const float* s; u16* d; int off;
    if      (i4 < n0)            { s = s0; d = d0; off = i4; }
    else if (i4 < n0+n1)         { s = s1; d = d1; off = i4 - n0; }
    else if (i4 < n0+n1+n2)      { s = s2; d = d2; off = i4 - n0 - n1; }
    else if (i4 < n0+n1+n2+n3)   { s = s3; d = d3; off = i4 - n0 - n1 - n2; }
    else return;
    float4 v = *reinterpret_cast<const float4*>(s + off);
    d[off]   = f2bf(v.x); d[off+1] = f2bf(v.y);
    d[off+2] = f2bf(v.z); d[off+3] = f2bf(v.w);
}

// ---------------------------------------------------------------------------
__global__ void patchify_kernel(const float* __restrict__ src, int C,
                                u16* __restrict__ out, int total)
{
    int idx = blockIdx.x * 256 + threadIdx.x;
    if (idx >= total) return;
    int K = C * 256;
    int row = idx / K, k = idx % K;
    int b = row / NTOK, n = row % NTOK;
    int c = k >> 8, rem = k & 255, pi = rem >> 4, pj = rem & 15;
    int i14 = n / 14, j14 = n % 14;
    float v = src[(((size_t)b * C + c) * 224 + i14 * 16 + pi) * 224 + j14 * 16 + pj];
    out[idx] = f2bf(v);
}

// ---------------------------------------------------------------------------
// bf16 MFMA GEMM, 128x64 tile, BK=64, 4 waves (2Mx2N, 64x32 each), 16x16x32.
// REGISTER-STAGED double-buffer pipeline, one __syncthreads per K-step:
//   gload(tile t+1 -> regs)   [issued before compute -> latency hidden]
//   COMPUTE(buf t&1)
//   ds_write(regs -> buf (t+1)&1)  [readers of that buf done at prev barrier]
//   __syncthreads()
// LDS layout per tile: elem(R,k) = (R>>4)*1024 + (k>>3)*128 + (R&15)*8 + (k&7)
//   chunk c = off>>3: seg=c>>7, q=(c&127)>>4, r16=c&15 -> row seg*16+r16,
//   k = q*8..q*8+7. Thread tid owns chunks {tid+256*u} -> fully linear
//   ds_write_b128 (conflict-free); ds_read fragments 2-way (free).
// XCD-bijective block swizzle for A/W-panel L2 locality.
// MODE 0: f32 out +bias      MODE 1: GELU -> bf16 out, +bias
// MODE 2: f32 out +bias+res  MODE 3: batched bias-GEMM    MODE 4: bf16 +bias
// Requires K % 64 == 0 (call sites: 256, 768, 3072).
// ---------------------------------------------------------------------------
template<int MODE>
__global__ __launch_bounds__(256) void gemm_bf16(
    const u16* __restrict__ A, const u16* __restrict__ W,
    const float* __restrict__ bias, const float* __restrict__ res,
    void* __restrict__ Cout, int M, int N, int K, long long strideA)
{
    __shared__ u16 As[2][8192];   // 128 rows x 64 k
    __shared__ u16 Bs[2][4096];   // 64 rows  x 64 k
    const int tid  = threadIdx.x;
    const int wave = tid >> 6, lane = tid & 63;
    const int lo = lane & 15, hi = lane >> 4;
    const int wr = wave >> 1, wc = wave & 1;

    // bijective XCD swizzle (m204)
    const int gx = gridDim.x;
    const int nwg = gx * gridDim.y;
    int wg = blockIdx.y * gx + blockIdx.x;
    {
        int q = nwg >> 3, r = nwg & 7;
        int xcd = wg & 7, idx = wg >> 3;
        wg = (xcd < r ? xcd * (q + 1) : r * (q + 1) + (xcd - r) * q) + idx;
    }
    const int m0 = (wg / gx) * 128, n0 = (wg % gx) * 64;
    if (MODE == 3) { A += blockIdx.z * strideA; W += blockIdx.z * strideA; }

    const int limA = M - 1;
    const int limB = (MODE == 3 ? M : N) - 1;

    // staging chunk decode: thread owns A-chunks tid+256u (u=0..3), B-chunks tid+256u (u=0..1)
    const u16* Ag[4];
    const u16* Bg[2];
    #pragma unroll
    for (int u = 0; u < 4; ++u) {
        int c = tid + 256 * u;
        int seg = c >> 7, rem = c & 127, q = rem >> 4, r16 = rem & 15;
        int ra = m0 + seg * 16 + r16; if (ra > limA) ra = limA;
        Ag[u] = A + (size_t)ra * K + q * 8;
    }
    #pragma unroll
    for (int u = 0; u < 2; ++u) {
        int c = tid + 256 * u;
        int seg = c >> 7, rem = c & 127, q = rem >> 4, r16 = rem & 15;
        int rb = n0 + seg * 16 + r16; if (rb > limB) rb = limB;
        Bg[u] = W + (size_t)rb * K + q * 8;
    }

    f32x4 acc[4][2] = {};

    #define COMPUTE(bf_)                                                         \
        do {                                                                     \
            _Pragma("unroll")                                                    \
            for (int kk = 0; kk < 2; ++kk) {                                     \
                bf16x8 af[4], bfr[2];                                            \
                _Pragma("unroll")                                                \
                for (int i = 0; i < 4; ++i)                                      \
                    af[i] = *reinterpret_cast<const bf16x8*>(                    \
                        &As[bf_][(wr * 4 + i) * 1024 + (kk * 4 + hi) * 128 + lo * 8]); \
                _Pragma("unroll")                                                \
                for (int j = 0; j < 2; ++j)                                      \
                    bfr[j] = *reinterpret_cast<const bf16x8*>(                   \
                        &Bs[bf_][(wc * 2 + j) * 1024 + (kk * 4 + hi) * 128 + lo * 8]); \
                _Pragma("unroll")                                                \
                for (int i = 0; i < 4; ++i)                                      \
                    _Pragma("unroll")                                            \
                    for (int j = 0; j < 2; ++j)                                  \
                        acc[i][j] = __builtin_amdgcn_mfma_f32_16x16x32_bf16(     \
                            af[i], bfr[j], acc[i][j], 0, 0, 0);                  \
            }                                                                    \
        } while (0)

    const int nt = K >> 6;
    bf16x8 va[4], vb[2];
    // prologue: tile 0 -> regs -> LDS buf0
    #pragma unroll
    for (int u = 0; u < 4; ++u) va[u] = *reinterpret_cast<const bf16x8*>(Ag[u]);
    #pragma unroll
    for (int u = 0; u < 2; ++u) vb[u] = *reinterpret_cast<const bf16x8*>(Bg[u]);
    #pragma unroll
    for (int u = 0; u < 4; ++u) *reinterpret_cast<bf16x8*>(&As[0][(tid + 256 * u) * 8]) = va[u];
    #pragma unroll
    for (int u = 0; u < 2; ++u) *reinterpret_cast<bf16x8*>(&Bs[0][(tid + 256 * u) * 8]) = vb[u];
    __syncthreads();

    for (int t = 0; t < nt; ++t) {
        const int k0n = (t + 1) * 64;
        if (t + 1 < nt) {     // issue next tile's loads BEFORE compute
            #pragma unroll
            for (int u = 0; u < 4; ++u) va[u] = *reinterpret_cast<const bf16x8*>(Ag[u] + k0n);
            #pragma unroll
            for (int u = 0; u < 2; ++u) vb[u] = *reinterpret_cast<const bf16x8*>(Bg[u] + k0n);
        }
        COMPUTE(t & 1);
        if (t + 1 < nt) {     // write-late into the other buffer
            #pragma unroll
            for (int u = 0; u < 4; ++u)
                *reinterpret_cast<bf16x8*>(&As[(t + 1) & 1][(tid + 256 * u) * 8]) = va[u];
            #pragma unroll
            for (int u = 0; u < 2; ++u)
                *reinterpret_cast<bf16x8*>(&Bs[(t + 1) & 1][(tid + 256 * u) * 8]) = vb[u];
        }
        __syncthreads();
    }
    #undef COMPUTE

    const int cr = hi * 4;
    #pragma unroll
    for (int i = 0; i < 4; ++i) {
        #pragma unroll
        for (int r = 0; r < 4; ++r) {
            int m = m0 + wr * 64 + i * 16 + cr + r;
            if (MODE != 3 && m >= M) continue;
            #pragma unroll
            for (int j = 0; j < 2; ++j) {
                int n = n0 + wc * 32 + j * 16 + lo;
                float v = acc[i][j][r];
                if (MODE == 0) {
                    ((float*)Cout)[(size_t)m * N + n] = v + bias[n];
                } else if (MODE == 1) {
                    float t = v + bias[n];
                    t = 0.5f * t * (1.f + erff(t * 0.70710678118654752f));
                    ((u16*)Cout)[(size_t)m * N + n] = f2bf(t);
                } else if (MODE == 2) {
                    ((float*)Cout)[(size_t)m * N + n] = v + bias[n] + res[(size_t)m * N + n];
                } else if (MODE == 4) {
                    ((u16*)Cout)[(size_t)m * N + n] = f2bf(v + bias[n]);
                } else { // MODE 3
                    if (m < M && n < M) {
                        float* C3 = (float*)Cout + (size_t)blockIdx.z * LL * LL;
                        C3[(size_t)(m + 1) * LL + (n + 1)] = v * 0.03608439182435161f;
                    }
                }
            }
        }
    }
}

__global__ void bias_edge_kernel(float* __restrict__ bias)
{
    int b = blockIdx.x, t = threadIdx.x;
    if (t < LL) {
        bias[((size_t)b * LL + 0) * LL + t] = 0.f;
        bias[((size_t)b * LL + t) * LL + 0] = 0.f;
    }
}

// ---------------------------------------------------------------------------
__global__ void combine_kernel(
    const float* __restrict__ toki, const float* __restrict__ tokm,
    const float* __restrict__ cls, const float* __restrict__ pos,
    float* __restrict__ x)
{
    size_t idx = (size_t)blockIdx.x * 256 + threadIdx.x;
    if (idx >= (size_t)MROWS * DD) return;
    int d = (int)(idx % DD);
    size_t bl = idx / DD;
    int l = (int)(bl % LL);
    int b = (int)(bl / LL);
    float v;
    if (l == 0) v = cls[d];
    else {
        size_t tix = ((size_t)b * NTOK + (l - 1)) * DD + d;
        v = toki[tix] + 0.5f * tokm[tix];
    }
    x[idx] = v + pos[(size_t)l * DD + d];
}

// ---------------------------------------------------------------------------
template<int OUT>
__global__ __launch_bounds__(256) void ln_kernel(
    const float* __restrict__ in, const float* __restrict__ g,
    const float* __restrict__ beta, float* __restrict__ outf,
    u16* __restrict__ outb)
{
    int row = blockIdx.x;
    int tid = threadIdx.x;
    const float* xr = in + (size_t)row * DD;
    float v[3];
    #pragma unroll
    for (int r = 0; r < 3; ++r) v[r] = xr[tid + r * 256];
    __shared__ float red[256];
    red[tid] = v[0] + v[1] + v[2];
    __syncthreads();
    for (int off = 128; off; off >>= 1) {
        if (tid < off) red[tid] += red[tid + off];
        __syncthreads();
    }
    float mean = red[0] * (1.f / 768.f);
    __syncthreads();
    float q = 0.f;
    #pragma unroll
    for (int r = 0; r < 3; ++r) { float dv = v[r] - mean; q += dv * dv; }
    red[tid] = q;
    __syncthreads();
    for (int off = 128; off; off >>= 1) {
        if (tid < off) red[tid] += red[tid + off];
        __syncthreads();
    }
    float rstd = rsqrtf(red[0] * (1.f / 768.f) + 1e-5f);
    #pragma unroll
    for (int r = 0; r < 3; ++r) {
        int d = tid + r * 256;
        float o = g[d] * (v[r] - mean) * rstd + beta[d];
        if (OUT == 0 || OUT == 2) outf[(size_t)row * DD + d] = o;
        if (OUT == 1 || OUT == 2) outb[(size_t)row * DD + d] = f2bf(o);
    }
}

// ---------------------------------------------------------------------------
// MFMA attention (unchanged)
// ---------------------------------------------------------------------------
constexpr int KSTRE = 72;
constexpr int VSTRE = 232;
constexpr int PSTRE = 232;

__global__ __launch_bounds__(256) void attn_mfma_kernel(
    const u16* __restrict__ qkv, const float* __restrict__ bias,
    u16* __restrict__ o)
{
    const int h = blockIdx.x, b = blockIdx.y;
    const int tid = threadIdx.x, wave = tid >> 6, lane = tid & 63;
    const int lo = lane & 15, hi = lane >> 4;

    __shared__ u16 Ks[208 * KSTRE];
    __shared__ u16 Vt[64 * VSTRE];
    __shared__ u16 Ps[4][16 * PSTRE];

    const u16* qb = qkv + (size_t)b * LL * 2304;

    for (int idx = tid; idx < 208 * 8; idx += 256) {
        int key = idx >> 3, c8 = idx & 7;
        u16x8 v = {};
        if (key < LL) v = *reinterpret_cast<const u16x8*>(qb + (size_t)key * 2304 + 768 + h * 64 + c8 * 8);
        *reinterpret_cast<u16x8*>(&Ks[key * KSTRE + c8 * 8]) = v;
    }
    for (int idx = tid; idx < 224 * 8; idx += 256) {
        int key = idx >> 3, c8 = idx & 7;
        u16x8 v = {};
        if (key < LL) v = *reinterpret_cast<const u16x8*>(qb + (size_t)key * 2304 + 1536 + h * 64 + c8 * 8);
        #pragma unroll
        for (int e = 0; e < 8; ++e) Vt[(c8 * 8 + e) * VSTRE + key] = v[e];
    }
    __syncthreads();

    u16* P = Ps[wave];
    const float* biasbb = bias + (size_t)b * LL * LL;

    for (int rt = wave; rt < 13; rt += 4) {
        int q = rt * 16 + lo; if (q > LL - 1) q = LL - 1;
        const u16* qrow = qb + (size_t)q * 2304 + h * 64;
        bf16x8 qa0 = *reinterpret_cast<const bf16x8*>(qrow + hi * 8);
        bf16x8 qa1 = *reinterpret_cast<const bf16x8*>(qrow + 32 + hi * 8);

        f32x4 st[13];
        #pragma unroll
        for (int t = 0; t < 13; ++t) {
            int keyc = t * 16 + lo;
            bf16x8 kb0 = *reinterpret_cast<const bf16x8*>(&Ks[keyc * KSTRE + hi * 8]);
            bf16x8 kb1 = *reinterpret_cast<const bf16x8*>(&Ks[keyc * KSTRE + 32 + hi * 8]);
            f32x4 a = {};
            a = __builtin_amdgcn_mfma_f32_16x16x32_bf16(qa0, kb0, a, 0, 0, 0);
            a = __builtin_amdgcn_mfma_f32_16x16x32_bf16(qa1, kb1, a, 0, 0, 0);
            st[t] = a;
        }

        #pragma unroll
        for (int r = 0; r < 4; ++r) {
            int qq = rt * 16 + hi * 4 + r;
            int qc = qq > LL - 1 ? LL - 1 : qq;
            const float* brow = biasbb + (size_t)qc * LL;
            float s[13];
            float m = -1e30f;
            #pragma unroll
            for (int t = 0; t < 13; ++t) {
                int col = t * 16 + lo;
                float v;
                if (col < LL) v = st[t][r] * 0.125f + brow[col];
                else          v = -1e30f;
                s[t] = v;
                m = fmaxf(m, v);
            }
            m = fmaxf(m, __shfl_xor(m, 1));
            m = fmaxf(m, __shfl_xor(m, 2));
            m = fmaxf(m, __shfl_xor(m, 4));
            m = fmaxf(m, __shfl_xor(m, 8));
            float sum = 0.f;
            #pragma unroll
            for (int t = 0; t < 13; ++t) { float e = __expf(s[t] - m); s[t] = e; sum += e; }
            sum += __shfl_xor(sum, 1);
            sum += __shfl_xor(sum, 2);
            sum += __shfl_xor(sum, 4);
            sum += __shfl_xor(sum, 8);
            float inv = 1.f / sum;
            int prow = (hi * 4 + r) * PSTRE;
            #pragma unroll
            for (int t = 0; t < 13; ++t) P[prow + t * 16 + lo] = f2bf(s[t] * inv);
            P[prow + 208 + lo] = 0;
        }

        f32x4 oacc[4] = {};
        #pragma unroll
        for (int kt = 0; kt < 7; ++kt) {
            bf16x8 pa = *reinterpret_cast<const bf16x8*>(&P[lo * PSTRE + kt * 32 + hi * 8]);
            #pragma unroll
            for (int dt = 0; dt < 4; ++dt) {
                bf16x8 vb = *reinterpret_cast<const bf16x8*>(&Vt[(dt * 16 + lo) * VSTRE + kt * 32 + hi * 8]);
                oacc[dt] = __builtin_amdgcn_mfma_f32_16x16x32_bf16(pa, vb, oacc[dt], 0, 0, 0);
            }
        }

        #pragma unroll
        for (int dt = 0; dt < 4; ++dt) {
            #pragma unroll
            for (int r = 0; r < 4; ++r) {
                int qq = rt * 16 + hi * 4 + r;
                if (qq < LL)
                    o[((size_t)(b * LL + qq)) * DD + h * 64 + dt * 16 + lo] = f2bf(oacc[dt][r]);
            }
        }
    }
}

// ---------------------------------------------------------------------------
__global__ __launch_bounds__(256) void final_kernel(
    const float* __restrict__ x,
    const float* __restrict__ eg, const float* __restrict__ eb,
    const float* __restrict__ fg, const float* __restrict__ fb,
    const float* __restrict__ hw, const float* __restrict__ hb,
    float* __restrict__ out)
{
    int b = blockIdx.x;
    int tid = threadIdx.x;
    __shared__ float xs[768];
    __shared__ float red[256];
    const float* xr = x + (size_t)b * LL * DD;
    #pragma unroll
    for (int r = 0; r < 3; ++r) xs[tid + r * 256] = xr[tid + r * 256];
    __syncthreads();
    for (int pass = 0; pass < 2; ++pass) {
        const float* g  = pass ? fg : eg;
        const float* bb = pass ? fb : eb;
        red[tid] = xs[tid] + xs[tid + 256] + xs[tid + 512];
        __syncthreads();
        for (int off = 128; off; off >>= 1) {
            if (tid < off) red[tid] += red[tid + off];
            __syncthreads();
        }
        float mean = red[0] * (1.f / 768.f);
        __syncthreads();
        float q = 0.f;
        #pragma unroll
        for (int r = 0; r < 3; ++r) { float dv = xs[tid + r * 256] - mean; q += dv * dv; }
        red[tid] = q;
        __syncthreads();
        for (int off = 128; off; off >>= 1) {
            if (tid < off) red[tid] += red[tid + off];
            __syncthreads();
        }
        float rstd = rsqrtf(red[0] * (1.f / 768.f) + 1e-5f);
        __syncthreads();
        #pragma unroll
        for (int r = 0; r < 3; ++r) {
            int d = tid + r * 256;
            xs[d] = g[d] * (xs[d] - mean) * rstd + bb[d];
        }
        __syncthreads();
    }
    int c = tid >> 6, lane = tid & 63;
    float part = 0.f;
    for (int d = lane; d < 768; d += 64) part += xs[d] * hw[c * 768 + d];
    #pragma unroll
    for (int off = 32; off; off >>= 1) part += __shfl_down(part, off);
    if (lane == 0) out[b * 4 + c] = part + hb[c];
}

// ---------------------------------------------------------------------------
extern "C" void kernel_launch(void* const* d_in, const int* in_sizes, int n_in,
                              void* d_out, int out_size, void* d_ws, size_t ws_size,
                              hipStream_t stream)
{
    const float* img    = (const float*)d_in[0];
    const float* mask   = (const float*)d_in[1];
    const float* pe_iw  = (const float*)d_in[2];
    const float* pe_ib  = (const float*)d_in[3];
    const float* pe_ig  = (const float*)d_in[4];
    const float* pe_ibb = (const float*)d_in[5];
    const float* pe_mw  = (const float*)d_in[6];
    const float* pe_mb  = (const float*)d_in[7];
    const float* pe_mg  = (const float*)d_in[8];
    const float* pe_mbb = (const float*)d_in[9];
    const float* cls    = (const float*)d_in[10];
    const float* pos    = (const float*)d_in[11];
    const float* ln1_g  = (const float*)d_in[12];
    const float* ln1_b  = (const float*)d_in[13];
    const float* w_qkv  = (const float*)d_in[14];
    const float* b_qkv  = (const float*)d_in[15];
    const float* w_out  = (const float*)d_in[16];
    const float* b_out  = (const float*)d_in[17];
    const float* ln2_g  = (const float*)d_in[18];
    const float* ln2_b  = (const float*)d_in[19];
    const float* w_fc1  = (const float*)d_in[20];
    const float* b_fc1  = (const float*)d_in[21];
    const float* w_fc2  = (const float*)d_in[22];
    const float* b_fc2  = (const float*)d_in[23];
    const float* enc_g  = (const float*)d_in[24];
    const float* enc_b  = (const float*)d_in[25];
    const float* fin_g  = (const float*)d_in[26];
    const float* fin_b  = (const float*)d_in[27];
    const float* head_w = (const float*)d_in[28];
    const float* head_b = (const float*)d_in[29];

    char* wsb = (char*)d_ws;
    size_t off = 0;
    auto alloc = [&](size_t bytes) { void* p = wsb + off; off += (bytes + 255) & ~(size_t)255; return p; };

    float* x     = (float*)alloc((size_t)MROWS * DD * 4);
    u16*   qkvb  = (u16*)  alloc((size_t)MROWS * 3 * DD * 2);
    u16*   hbuf  = (u16*)  alloc((size_t)MROWS * DD * 2);
    u16*   fc1b  = (u16*)  alloc((size_t)MROWS * 4 * DD * 2);
    float* biasb = (float*)alloc((size_t)BB * LL * LL * 4);
    u16*   wqb   = (u16*)  alloc((size_t)3 * DD * DD * 2);
    u16*   wob   = (u16*)  alloc((size_t)DD * DD * 2);
    u16*   w1b   = (u16*)  alloc((size_t)4 * DD * DD * 2);
    u16*   w2b   = (u16*)  alloc((size_t)4 * DD * DD * 2);
    float* toki  = (float*)alloc((size_t)MTOK * DD * 4);
    float* tokm  = (float*)alloc((size_t)MTOK * DD * 4);
    u16*   pa    = fc1b;           // patches alias
    float* ttmp  = (float*)qkvb;   // pe-GEMM f32 out alias
    u16*   tokmb = hbuf;           // bf16 tok_m alias

    // ---- patch embed (img) ----
    cast_kernel<<<(DD * DD / 4 + 255) / 256, 256, 0, stream>>>(pe_iw, wob, DD * DD);
    patchify_kernel<<<(MTOK * DD + 255) / 256, 256, 0, stream>>>(img, 3, pa, MTOK * DD);
    gemm_bf16<0><<<dim3(DD / 64, MTOK / 128), 256, 0, stream>>>(
        pa, wob, pe_ib, nullptr, ttmp, MTOK, DD, DD, 0);
    ln_kernel<0><<<MTOK, 256, 0, stream>>>(ttmp, pe_ig, pe_ibb, toki, nullptr);

    // ---- patch embed (mask) ----
    cast_kernel<<<(DD * 256 / 4 + 255) / 256, 256, 0, stream>>>(pe_mw, wob, DD * 256);
    patchify_kernel<<<(MTOK * 256 + 255) / 256, 256, 0, stream>>>(mask, 1, pa, MTOK * 256);
    gemm_bf16<0><<<dim3(DD / 64, MTOK / 128), 256, 0, stream>>>(
        pa, wob, pe_mb, nullptr, ttmp, MTOK, DD, 256, 0);
    ln_kernel<2><<<MTOK, 256, 0, stream>>>(ttmp, pe_mg, pe_mbb, tokm, tokmb);

    // ---- attention bias ----
    gemm_bf16<3><<<dim3(4, 2, BB), 256, 0, stream>>>(
        tokmb, tokmb, nullptr, nullptr, biasb, NTOK, NTOK, DD, (long long)NTOK * DD);
    bias_edge_kernel<<<BB, 256, 0, stream>>>(biasb);

    // ---- combine ----
    combine_kernel<<<(MROWS * DD + 255) / 256, 256, 0, stream>>>(toki, tokm, cls, pos, x);

    const int mblk = (MROWS + 127) / 128;   // 50
    const int wqn = 3 * DD * DD, won = DD * DD, w1n = 4 * DD * DD, w2n = 4 * DD * DD;
    const int castTot = (wqn + won + w1n + w2n) / 4;
    for (int l = 0; l < 12; ++l) {
        cast4_kernel<<<(castTot + 255) / 256, 256, 0, stream>>>(
            w_qkv + (size_t)l * wqn, wqn, w_out + (size_t)l * won, won,
            w_fc1 + (size_t)l * w1n, w1n, w_fc2 + (size_t)l * w2n, w2n,
            wqb, wob, w1b, w2b);
        ln_kernel<1><<<MROWS, 256, 0, stream>>>(x, ln1_g + l * DD, ln1_b + l * DD, nullptr, hbuf);
        gemm_bf16<4><<<dim3(3 * DD / 64, mblk), 256, 0, stream>>>(
            hbuf, wqb, b_qkv + l * 3 * DD, nullptr, qkvb, MROWS, 3 * DD, DD, 0);
        attn_mfma_kernel<<<dim3(HH, BB), 256, 0, stream>>>(qkvb, biasb, hbuf);
        gemm_bf16<2><<<dim3(DD / 64, mblk), 256, 0, stream>>>(
            hbuf, wob, b_out + l * DD, x, x, MROWS, DD, DD, 0);
        ln_kernel<1><<<MROWS, 256, 0, stream>>>(x, ln2_g + l * DD, ln2_b + l * DD, nullptr, hbuf);
        gemm_bf16<1><<<dim3(4 * DD / 64, mblk), 256, 0, stream>>>(
            hbuf, w1b, b_fc1 + l * 4 * DD, nullptr, fc1b, MROWS, 4 * DD, DD, 0);
        gemm_bf16<2><<<dim3(DD / 64, mblk), 256, 0, stream>>>(
            fc1b, w2b, b_fc2 + l * DD, x, x, MROWS, DD, 4 * DD, 0);
    }
    final_kernel<<<BB, 256, 0, stream>>>(x, enc_g, enc_b, fin_g, fin_b, head_w, head_b, (float*)d_out);
}

// Round 8
// 5056.183 us; speedup vs baseline: 1.0243x; 1.0133x over previous
//
#include <hip/hip_runtime.h>
#include <hip/hip_bf16.h>
#include <math.h>

typedef unsigned int   u32;
typedef unsigned short u16;
typedef __bf16 bf16x8 __attribute__((ext_vector_type(8)));
typedef float  f32x4  __attribute__((ext_vector_type(4)));
typedef u16    u16x8  __attribute__((ext_vector_type(8)));

constexpr int BB = 32, DD = 768, LL = 197, HH = 12, NTOK = 196;
constexpr int MROWS = BB * LL;        // 6304
constexpr int MTOK  = BB * NTOK;      // 6272

__device__ __forceinline__ u16 f2bf(float f) {
    union { float f; u32 u; } v; v.f = f;
    u32 r = v.u + 0x7fff + ((v.u >> 16) & 1);
    return (u16)(r >> 16);
}
__device__ __forceinline__ float bf2f(u16 u) {
    union { u32 u; float f; } v; v.u = ((u32)u) << 16;
    return v.f;
}

// ---------------------------------------------------------------------------
__global__ void cast_kernel(const float* __restrict__ in, u16* __restrict__ out, int n)
{
    int i4 = (blockIdx.x * 256 + threadIdx.x) * 4;
    if (i4 >= n) return;
    float4 v = *reinterpret_cast<const float4*>(in + i4);
    out[i4]   = f2bf(v.x); out[i4+1] = f2bf(v.y);
    out[i4+2] = f2bf(v.z); out[i4+3] = f2bf(v.w);
}

__global__ void cast4_kernel(const float* s0, int n0, const float* s1, int n1,
                             const float* s2, int n2, const float* s3, int n3,
                             u16* d0, u16* d1, u16* d2, u16* d3)
{
    int i4 = (blockIdx.x * 256 + threadIdx.x) * 4;
    const float* s; u16* d; int off;
    if      (i4 < n0)            { s = s0; d = d0; off = i4; }
    else if (i4 < n0+n1)         { s = s1; d = d1; off = i4 - n0; }
    else if (i4 < n0+n1+n2)      { s = s2; d = d2; off = i4 - n0 - n1; }
    else if (i4 < n0+n1+n2+n3)   { s = s3; d = d3; off = i4 - n0 - n1 - n2; }
    else return;
    float4 v = *reinterpret_cast<const float4*>(s + off);
    d[off]   = f2bf(v.x); d[off+1] = f2bf(v.y);
    d[off+2] = f2bf(v.z); d[off+3] = f2bf(v.w);
}

// ---------------------------------------------------------------------------
__global__ void patchify_kernel(const float* __restrict__ src, int C,
                                u16* __restrict__ out, int total)
{
    int idx = blockIdx.x * 256 + threadIdx.x;
    if (idx >= total) return;
    int K = C * 256;
    int row = idx / K, k = idx % K;
    int b = row / NTOK, n = row % NTOK;
    int c = k >> 8, rem = k & 255, pi = rem >> 4, pj = rem & 15;
    int i14 = n / 14, j14 = n % 14;
    float v = src[(((size_t)b * C + c) * 224 + i14 * 16 + pi) * 224 + j14 * 16 + pj];
    out[idx] = f2bf(v);
}

// ---------------------------------------------------------------------------
// bf16 MFMA GEMM, 128x64 tile, BK=64, 4 waves (2Mx2N, 64x32 each), 16x16x32.
// REGISTER-STAGED 2-DEEP pipeline (pure C++ data deps, no inline asm):
//   two named reg sets A/B hold tiles t, t+1; loads for t+2 are issued a full
//   2 steps before their ds_write consumes them, so HBM/L3 latency spans two
//   compute phases (T4 semantics via compiler-enforced register waits).
// Steady state (2-step unroll):
//   even t: issue(t+2 -> setA); COMPUTE(buf0); ds_write(setB -> buf1); bar
//   odd  t: issue(t+3 -> setB); COMPUTE(buf1); ds_write(setA -> buf0); bar
// LDS layout per tile: elem(R,k) = (R>>4)*1024 + (k>>3)*128 + (R&15)*8 + (k&7)
//   thread tid owns chunks {tid+256u} -> linear ds_write_b128, conflict-free;
//   fragment ds_read_b128 2-way (free).  XCD-bijective block swizzle.
// MODE 0: f32 out +bias      MODE 1: GELU -> bf16 out, +bias
// MODE 2: f32 out +bias+res  MODE 3: batched bias-GEMM    MODE 4: bf16 +bias
// Requires K % 128 == 0 (call sites: 256, 768, 3072 -> nt even >= 2).
// ---------------------------------------------------------------------------
template<int MODE>
__global__ __launch_bounds__(256) void gemm_bf16(
    const u16* __restrict__ A, const u16* __restrict__ W,
    const float* __restrict__ bias, const float* __restrict__ res,
    void* __restrict__ Cout, int M, int N, int K, long long strideA)
{
    __shared__ u16 As[2][8192];   // 128 rows x 64 k
    __shared__ u16 Bs[2][4096];   // 64 rows  x 64 k
    const int tid  = threadIdx.x;
    const int wave = tid >> 6, lane = tid & 63;
    const int lo = lane & 15, hi = lane >> 4;
    const int wr = wave >> 1, wc = wave & 1;

    // bijective XCD swizzle (m204)
    const int gx = gridDim.x;
    const int nwg = gx * gridDim.y;
    int wg = blockIdx.y * gx + blockIdx.x;
    {
        int q = nwg >> 3, r = nwg & 7;
        int xcd = wg & 7, idx = wg >> 3;
        wg = (xcd < r ? xcd * (q + 1) : r * (q + 1) + (xcd - r) * q) + idx;
    }
    const int m0 = (wg / gx) * 128, n0 = (wg % gx) * 64;
    if (MODE == 3) { A += blockIdx.z * strideA; W += blockIdx.z * strideA; }

    const int limA = M - 1;
    const int limB = (MODE == 3 ? M : N) - 1;

    // staging chunk decode: thread owns A-chunks tid+256u (u=0..3), B-chunks tid+256u (u=0..1)
    const u16* Ag[4];
    const u16* Bg[2];
    #pragma unroll
    for (int u = 0; u < 4; ++u) {
        int c = tid + 256 * u;
        int seg = c >> 7, rem = c & 127, q = rem >> 4, r16 = rem & 15;
        int ra = m0 + seg * 16 + r16; if (ra > limA) ra = limA;
        Ag[u] = A + (size_t)ra * K + q * 8;
    }
    #pragma unroll
    for (int u = 0; u < 2; ++u) {
        int c = tid + 256 * u;
        int seg = c >> 7, rem = c & 127, q = rem >> 4, r16 = rem & 15;
        int rb = n0 + seg * 16 + r16; if (rb > limB) rb = limB;
        Bg[u] = W + (size_t)rb * K + q * 8;
    }

    f32x4 acc[4][2] = {};

    bf16x8 vaA0, vaA1, vaA2, vaA3, vbA0, vbA1;   // set A
    bf16x8 vaB0, vaB1, vaB2, vaB3, vbB0, vbB1;   // set B

    #define LOADSET_A(k0_)                                              \
        do {                                                            \
            vaA0 = *reinterpret_cast<const bf16x8*>(Ag[0] + (k0_));     \
            vaA1 = *reinterpret_cast<const bf16x8*>(Ag[1] + (k0_));     \
            vaA2 = *reinterpret_cast<const bf16x8*>(Ag[2] + (k0_));     \
            vaA3 = *reinterpret_cast<const bf16x8*>(Ag[3] + (k0_));     \
            vbA0 = *reinterpret_cast<const bf16x8*>(Bg[0] + (k0_));     \
            vbA1 = *reinterpret_cast<const bf16x8*>(Bg[1] + (k0_));     \
        } while (0)
    #define LOADSET_B(k0_)                                              \
        do {                                                            \
            vaB0 = *reinterpret_cast<const bf16x8*>(Ag[0] + (k0_));     \
            vaB1 = *reinterpret_cast<const bf16x8*>(Ag[1] + (k0_));     \
            vaB2 = *reinterpret_cast<const bf16x8*>(Ag[2] + (k0_));     \
            vaB3 = *reinterpret_cast<const bf16x8*>(Ag[3] + (k0_));     \
            vbB0 = *reinterpret_cast<const bf16x8*>(Bg[0] + (k0_));     \
            vbB1 = *reinterpret_cast<const bf16x8*>(Bg[1] + (k0_));     \
        } while (0)
    #define WRITESET_A(bf_)                                                          \
        do {                                                                         \
            *reinterpret_cast<bf16x8*>(&As[bf_][(tid      ) * 8]) = vaA0;            \
            *reinterpret_cast<bf16x8*>(&As[bf_][(tid + 256) * 8]) = vaA1;            \
            *reinterpret_cast<bf16x8*>(&As[bf_][(tid + 512) * 8]) = vaA2;            \
            *reinterpret_cast<bf16x8*>(&As[bf_][(tid + 768) * 8]) = vaA3;            \
            *reinterpret_cast<bf16x8*>(&Bs[bf_][(tid      ) * 8]) = vbA0;            \
            *reinterpret_cast<bf16x8*>(&Bs[bf_][(tid + 256) * 8]) = vbA1;            \
        } while (0)
    #define WRITESET_B(bf_)                                                          \
        do {                                                                         \
            *reinterpret_cast<bf16x8*>(&As[bf_][(tid      ) * 8]) = vaB0;            \
            *reinterpret_cast<bf16x8*>(&As[bf_][(tid + 256) * 8]) = vaB1;            \
            *reinterpret_cast<bf16x8*>(&As[bf_][(tid + 512) * 8]) = vaB2;            \
            *reinterpret_cast<bf16x8*>(&As[bf_][(tid + 768) * 8]) = vaB3;            \
            *reinterpret_cast<bf16x8*>(&Bs[bf_][(tid      ) * 8]) = vbB0;            \
            *reinterpret_cast<bf16x8*>(&Bs[bf_][(tid + 256) * 8]) = vbB1;            \
        } while (0)

    #define COMPUTE(bf_)                                                         \
        do {                                                                     \
            _Pragma("unroll")                                                    \
            for (int kk = 0; kk < 2; ++kk) {                                     \
                bf16x8 af[4], bfr[2];                                            \
                _Pragma("unroll")                                                \
                for (int i = 0; i < 4; ++i)                                      \
                    af[i] = *reinterpret_cast<const bf16x8*>(                    \
                        &As[bf_][(wr * 4 + i) * 1024 + (kk * 4 + hi) * 128 + lo * 8]); \
                _Pragma("unroll")                                                \
                for (int j = 0; j < 2; ++j)                                      \
                    bfr[j] = *reinterpret_cast<const bf16x8*>(                   \
                        &Bs[bf_][(wc * 2 + j) * 1024 + (kk * 4 + hi) * 128 + lo * 8]); \
                _Pragma("unroll")                                                \
                for (int i = 0; i < 4; ++i)                                      \
                    _Pragma("unroll")                                            \
                    for (int j = 0; j < 2; ++j)                                  \
                        acc[i][j] = __builtin_amdgcn_mfma_f32_16x16x32_bf16(     \
                            af[i], bfr[j], acc[i][j], 0, 0, 0);                  \
            }                                                                    \
        } while (0)

    const int nt = K >> 6;    // even, >= 2 at all call sites
    // prologue: tile0 -> setA, tile1 -> setB (in flight), setA -> buf0
    LOADSET_A(0);
    LOADSET_B(64);
    WRITESET_A(0);
    __syncthreads();

    for (int t = 0; t + 2 <= nt; t += 2) {
        // even step t: compute tile t (buf0)
        if (t + 2 < nt) LOADSET_A((t + 2) * 64);
        COMPUTE(0);
        WRITESET_B(1);                     // tile t+1 -> buf1 (loads 1+ steps old)
        __syncthreads();
        // odd step t+1: compute tile t+1 (buf1)
        if (t + 3 < nt) LOADSET_B((t + 3) * 64);
        COMPUTE(1);
        if (t + 2 < nt) WRITESET_A(0);     // tile t+2 -> buf0
        __syncthreads();
    }
    #undef LOADSET_A
    #undef LOADSET_B
    #undef WRITESET_A
    #undef WRITESET_B
    #undef COMPUTE

    const int cr = hi * 4;
    #pragma unroll
    for (int i = 0; i < 4; ++i) {
        #pragma unroll
        for (int r = 0; r < 4; ++r) {
            int m = m0 + wr * 64 + i * 16 + cr + r;
            if (MODE != 3 && m >= M) continue;
            #pragma unroll
            for (int j = 0; j < 2; ++j) {
                int n = n0 + wc * 32 + j * 16 + lo;
                float v = acc[i][j][r];
                if (MODE == 0) {
                    ((float*)Cout)[(size_t)m * N + n] = v + bias[n];
                } else if (MODE == 1) {
                    float t = v + bias[n];
                    t = 0.5f * t * (1.f + erff(t * 0.70710678118654752f));
                    ((u16*)Cout)[(size_t)m * N + n] = f2bf(t);
                } else if (MODE == 2) {
                    ((float*)Cout)[(size_t)m * N + n] = v + bias[n] + res[(size_t)m * N + n];
                } else if (MODE == 4) {
                    ((u16*)Cout)[(size_t)m * N + n] = f2bf(v + bias[n]);
                } else { // MODE 3
                    if (m < M && n < M) {
                        float* C3 = (float*)Cout + (size_t)blockIdx.z * LL * LL;
                        C3[(size_t)(m + 1) * LL + (n + 1)] = v * 0.03608439182435161f;
                    }
                }
            }
        }
    }
}

__global__ void bias_edge_kernel(float* __restrict__ bias)
{
    int b = blockIdx.x, t = threadIdx.x;
    if (t < LL) {
        bias[((size_t)b * LL + 0) * LL + t] = 0.f;
        bias[((size_t)b * LL + t) * LL + 0] = 0.f;
    }
}

// ---------------------------------------------------------------------------
__global__ void combine_kernel(
    const float* __restrict__ toki, const float* __restrict__ tokm,
    const float* __restrict__ cls, const float* __restrict__ pos,
    float* __restrict__ x)
{
    size_t idx = (size_t)blockIdx.x * 256 + threadIdx.x;
    if (idx >= (size_t)MROWS * DD) return;
    int d = (int)(idx % DD);
    size_t bl = idx / DD;
    int l = (int)(bl % LL);
    int b = (int)(bl / LL);
    float v;
    if (l == 0) v = cls[d];
    else {
        size_t tix = ((size_t)b * NTOK + (l - 1)) * DD + d;
        v = toki[tix] + 0.5f * tokm[tix];
    }
    x[idx] = v + pos[(size_t)l * DD + d];
}

// ---------------------------------------------------------------------------
template<int OUT>
__global__ __launch_bounds__(256) void ln_kernel(
    const float* __restrict__ in, const float* __restrict__ g,
    const float* __restrict__ beta, float* __restrict__ outf,
    u16* __restrict__ outb)
{
    int row = blockIdx.x;
    int tid = threadIdx.x;
    const float* xr = in + (size_t)row * DD;
    float v[3];
    #pragma unroll
    for (int r = 0; r < 3; ++r) v[r] = xr[tid + r * 256];
    __shared__ float red[256];
    red[tid] = v[0] + v[1] + v[2];
    __syncthreads();
    for (int off = 128; off; off >>= 1) {
        if (tid < off) red[tid] += red[tid + off];
        __syncthreads();
    }
    float mean = red[0] * (1.f / 768.f);
    __syncthreads();
    float q = 0.f;
    #pragma unroll
    for (int r = 0; r < 3; ++r) { float dv = v[r] - mean; q += dv * dv; }
    red[tid] = q;
    __syncthreads();
    for (int off = 128; off; off >>= 1) {
        if (tid < off) red[tid] += red[tid + off];
        __syncthreads();
    }
    float rstd = rsqrtf(red[0] * (1.f / 768.f) + 1e-5f);
    #pragma unroll
    for (int r = 0; r < 3; ++r) {
        int d = tid + r * 256;
        float o = g[d] * (v[r] - mean) * rstd + beta[d];
        if (OUT == 0 || OUT == 2) outf[(size_t)row * DD + d] = o;
        if (OUT == 1 || OUT == 2) outb[(size_t)row * DD + d] = f2bf(o);
    }
}

// ---------------------------------------------------------------------------
// MFMA attention (unchanged)
// ---------------------------------------------------------------------------
constexpr int KSTRE = 72;
constexpr int VSTRE = 232;
constexpr int PSTRE = 232;

__global__ __launch_bounds__(256) void attn_mfma_kernel(
    const u16* __restrict__ qkv, const float* __restrict__ bias,
    u16* __restrict__ o)
{
    const int h = blockIdx.x, b = blockIdx.y;
    const int tid = threadIdx.x, wave = tid >> 6, lane = tid & 63;
    const int lo = lane & 15, hi = lane >> 4;

    __shared__ u16 Ks[208 * KSTRE];
    __shared__ u16 Vt[64 * VSTRE];
    __shared__ u16 Ps[4][16 * PSTRE];

    const u16* qb = qkv + (size_t)b * LL * 2304;

    for (int idx = tid; idx < 208 * 8; idx += 256) {
        int key = idx >> 3, c8 = idx & 7;
        u16x8 v = {};
        if (key < LL) v = *reinterpret_cast<const u16x8*>(qb + (size_t)key * 2304 + 768 + h * 64 + c8 * 8);
        *reinterpret_cast<u16x8*>(&Ks[key * KSTRE + c8 * 8]) = v;
    }
    for (int idx = tid; idx < 224 * 8; idx += 256) {
        int key = idx >> 3, c8 = idx & 7;
        u16x8 v = {};
        if (key < LL) v = *reinterpret_cast<const u16x8*>(qb + (size_t)key * 2304 + 1536 + h * 64 + c8 * 8);
        #pragma unroll
        for (int e = 0; e < 8; ++e) Vt[(c8 * 8 + e) * VSTRE + key] = v[e];
    }
    __syncthreads();

    u16* P = Ps[wave];
    const float* biasbb = bias + (size_t)b * LL * LL;

    for (int rt = wave; rt < 13; rt += 4) {
        int q = rt * 16 + lo; if (q > LL - 1) q = LL - 1;
        const u16* qrow = qb + (size_t)q * 2304 + h * 64;
        bf16x8 qa0 = *reinterpret_cast<const bf16x8*>(qrow + hi * 8);
        bf16x8 qa1 = *reinterpret_cast<const bf16x8*>(qrow + 32 + hi * 8);

        f32x4 st[13];
        #pragma unroll
        for (int t = 0; t < 13; ++t) {
            int keyc = t * 16 + lo;
            bf16x8 kb0 = *reinterpret_cast<const bf16x8*>(&Ks[keyc * KSTRE + hi * 8]);
            bf16x8 kb1 = *reinterpret_cast<const bf16x8*>(&Ks[keyc * KSTRE + 32 + hi * 8]);
            f32x4 a = {};
            a = __builtin_amdgcn_mfma_f32_16x16x32_bf16(qa0, kb0, a, 0, 0, 0);
            a = __builtin_amdgcn_mfma_f32_16x16x32_bf16(qa1, kb1, a, 0, 0, 0);
            st[t] = a;
        }

        #pragma unroll
        for (int r = 0; r < 4; ++r) {
            int qq = rt * 16 + hi * 4 + r;
            int qc = qq > LL - 1 ? LL - 1 : qq;
            const float* brow = biasbb + (size_t)qc * LL;
            float s[13];
            float m = -1e30f;
            #pragma unroll
            for (int t = 0; t < 13; ++t) {
                int col = t * 16 + lo;
                float v;
                if (col < LL) v = st[t][r] * 0.125f + brow[col];
                else          v = -1e30f;
                s[t] = v;
                m = fmaxf(m, v);
            }
            m = fmaxf(m, __shfl_xor(m, 1));
            m = fmaxf(m, __shfl_xor(m, 2));
            m = fmaxf(m, __shfl_xor(m, 4));
            m = fmaxf(m, __shfl_xor(m, 8));
            float sum = 0.f;
            #pragma unroll
            for (int t = 0; t < 13; ++t) { float e = __expf(s[t] - m); s[t] = e; sum += e; }
            sum += __shfl_xor(sum, 1);
            sum += __shfl_xor(sum, 2);
            sum += __shfl_xor(sum, 4);
            sum += __shfl_xor(sum, 8);
            float inv = 1.f / sum;
            int prow = (hi * 4 + r) * PSTRE;
            #pragma unroll
            for (int t = 0; t < 13; ++t) P[prow + t * 16 + lo] = f2bf(s[t] * inv);
            P[prow + 208 + lo] = 0;
        }

        f32x4 oacc[4] = {};
        #pragma unroll
        for (int kt = 0; kt < 7; ++kt) {
            bf16x8 pa = *reinterpret_cast<const bf16x8*>(&P[lo * PSTRE + kt * 32 + hi * 8]);
            #pragma unroll
            for (int dt = 0; dt < 4; ++dt) {
                bf16x8 vb = *reinterpret_cast<const bf16x8*>(&Vt[(dt * 16 + lo) * VSTRE + kt * 32 + hi * 8]);
                oacc[dt] = __builtin_amdgcn_mfma_f32_16x16x32_bf16(pa, vb, oacc[dt], 0, 0, 0);
            }
        }

        #pragma unroll
        for (int dt = 0; dt < 4; ++dt) {
            #pragma unroll
            for (int r = 0; r < 4; ++r) {
                int qq = rt * 16 + hi * 4 + r;
                if (qq < LL)
                    o[((size_t)(b * LL + qq)) * DD + h * 64 + dt * 16 + lo] = f2bf(oacc[dt][r]);
            }
        }
    }
}

// ---------------------------------------------------------------------------
__global__ __launch_bounds__(256) void final_kernel(
    const float* __restrict__ x,
    const float* __restrict__ eg, const float* __restrict__ eb,
    const float* __restrict__ fg, const float* __restrict__ fb,
    const float* __restrict__ hw, const float* __restrict__ hb,
    float* __restrict__ out)
{
    int b = blockIdx.x;
    int tid = threadIdx.x;
    __shared__ float xs[768];
    __shared__ float red[256];
    const float* xr = x + (size_t)b * LL * DD;
    #pragma unroll
    for (int r = 0; r < 3; ++r) xs[tid + r * 256] = xr[tid + r * 256];
    __syncthreads();
    for (int pass = 0; pass < 2; ++pass) {
        const float* g  = pass ? fg : eg;
        const float* bb = pass ? fb : eb;
        red[tid] = xs[tid] + xs[tid + 256] + xs[tid + 512];
        __syncthreads();
        for (int off = 128; off; off >>= 1) {
            if (tid < off) red[tid] += red[tid + off];
            __syncthreads();
        }
        float mean = red[0] * (1.f / 768.f);
        __syncthreads();
        float q = 0.f;
        #pragma unroll
        for (int r = 0; r < 3; ++r) { float dv = xs[tid + r * 256] - mean; q += dv * dv; }
        red[tid] = q;
        __syncthreads();
        for (int off = 128; off; off >>= 1) {
            if (tid < off) red[tid] += red[tid + off];
            __syncthreads();
        }
        float rstd = rsqrtf(red[0] * (1.f / 768.f) + 1e-5f);
        __syncthreads();
        #pragma unroll
        for (int r = 0; r < 3; ++r) {
            int d = tid + r * 256;
            xs[d] = g[d] * (xs[d] - mean) * rstd + bb[d];
        }
        __syncthreads();
    }
    int c = tid >> 6, lane = tid & 63;
    float part = 0.f;
    for (int d = lane; d < 768; d += 64) part += xs[d] * hw[c * 768 + d];
    #pragma unroll
    for (int off = 32; off; off >>= 1) part += __shfl_down(part, off);
    if (lane == 0) out[b * 4 + c] = part + hb[c];
}

// ---------------------------------------------------------------------------
extern "C" void kernel_launch(void* const* d_in, const int* in_sizes, int n_in,
                              void* d_out, int out_size, void* d_ws, size_t ws_size,
                              hipStream_t stream)
{
    const float* img    = (const float*)d_in[0];
    const float* mask   = (const float*)d_in[1];
    const float* pe_iw  = (const float*)d_in[2];
    const float* pe_ib  = (const float*)d_in[3];
    const float* pe_ig  = (const float*)d_in[4];
    const float* pe_ibb = (const float*)d_in[5];
    const float* pe_mw  = (const float*)d_in[6];
    const float* pe_mb  = (const float*)d_in[7];
    const float* pe_mg  = (const float*)d_in[8];
    const float* pe_mbb = (const float*)d_in[9];
    const float* cls    = (const float*)d_in[10];
    const float* pos    = (const float*)d_in[11];
    const float* ln1_g  = (const float*)d_in[12];
    const float* ln1_b  = (const float*)d_in[13];
    const float* w_qkv  = (const float*)d_in[14];
    const float* b_qkv  = (const float*)d_in[15];
    const float* w_out  = (const float*)d_in[16];
    const float* b_out  = (const float*)d_in[17];
    const float* ln2_g  = (const float*)d_in[18];
    const float* ln2_b  = (const float*)d_in[19];
    const float* w_fc1  = (const float*)d_in[20];
    const float* b_fc1  = (const float*)d_in[21];
    const float* w_fc2  = (const float*)d_in[22];
    const float* b_fc2  = (const float*)d_in[23];
    const float* enc_g  = (const float*)d_in[24];
    const float* enc_b  = (const float*)d_in[25];
    const float* fin_g  = (const float*)d_in[26];
    const float* fin_b  = (const float*)d_in[27];
    const float* head_w = (const float*)d_in[28];
    const float* head_b = (const float*)d_in[29];

    char* wsb = (char*)d_ws;
    size_t off = 0;
    auto alloc = [&](size_t bytes) { void* p = wsb + off; off += (bytes + 255) & ~(size_t)255; return p; };

    float* x     = (float*)alloc((size_t)MROWS * DD * 4);
    u16*   qkvb  = (u16*)  alloc((size_t)MROWS * 3 * DD * 2);
    u16*   hbuf  = (u16*)  alloc((size_t)MROWS * DD * 2);
    u16*   fc1b  = (u16*)  alloc((size_t)MROWS * 4 * DD * 2);
    float* biasb = (float*)alloc((size_t)BB * LL * LL * 4);
    u16*   wqb   = (u16*)  alloc((size_t)3 * DD * DD * 2);
    u16*   wob   = (u16*)  alloc((size_t)DD * DD * 2);
    u16*   w1b   = (u16*)  alloc((size_t)4 * DD * DD * 2);
    u16*   w2b   = (u16*)  alloc((size_t)4 * DD * DD * 2);
    float* toki  = (float*)alloc((size_t)MTOK * DD * 4);
    float* tokm  = (float*)alloc((size_t)MTOK * DD * 4);
    u16*   pa    = fc1b;           // patches alias
    float* ttmp  = (float*)qkvb;   // pe-GEMM f32 out alias
    u16*   tokmb = hbuf;           // bf16 tok_m alias

    // ---- patch embed (img) ----
    cast_kernel<<<(DD * DD / 4 + 255) / 256, 256, 0, stream>>>(pe_iw, wob, DD * DD);
    patchify_kernel<<<(MTOK * DD + 255) / 256, 256, 0, stream>>>(img, 3, pa, MTOK * DD);
    gemm_bf16<0><<<dim3(DD / 64, MTOK / 128), 256, 0, stream>>>(
        pa, wob, pe_ib, nullptr, ttmp, MTOK, DD, DD, 0);
    ln_kernel<0><<<MTOK, 256, 0, stream>>>(ttmp, pe_ig, pe_ibb, toki, nullptr);

    // ---- patch embed (mask) ----
    cast_kernel<<<(DD * 256 / 4 + 255) / 256, 256, 0, stream>>>(pe_mw, wob, DD * 256);
    patchify_kernel<<<(MTOK * 256 + 255) / 256, 256, 0, stream>>>(mask, 1, pa, MTOK * 256);
    gemm_bf16<0><<<dim3(DD / 64, MTOK / 128), 256, 0, stream>>>(
        pa, wob, pe_mb, nullptr, ttmp, MTOK, DD, 256, 0);
    ln_kernel<2><<<MTOK, 256, 0, stream>>>(ttmp, pe_mg, pe_mbb, tokm, tokmb);

    // ---- attention bias ----
    gemm_bf16<3><<<dim3(4, 2, BB), 256, 0, stream>>>(
        tokmb, tokmb, nullptr, nullptr, biasb, NTOK, NTOK, DD, (long long)NTOK * DD);
    bias_edge_kernel<<<BB, 256, 0, stream>>>(biasb);

    // ---- combine ----
    combine_kernel<<<(MROWS * DD + 255) / 256, 256, 0, stream>>>(toki, tokm, cls, pos, x);

    const int mblk = (MROWS + 127) / 128;   // 50
    const int wqn = 3 * DD * DD, won = DD * DD, w1n = 4 * DD * DD, w2n = 4 * DD * DD;
    const int castTot = (wqn + won + w1n + w2n) / 4;
    for (int l = 0; l < 12; ++l) {
        cast4_kernel<<<(castTot + 255) / 256, 256, 0, stream>>>(
            w_qkv + (size_t)l * wqn, wqn, w_out + (size_t)l * won, won,
            w_fc1 + (size_t)l * w1n, w1n, w_fc2 + (size_t)l * w2n, w2n,
            wqb, wob, w1b, w2b);
        ln_kernel<1><<<MROWS, 256, 0, stream>>>(x, ln1_g + l * DD, ln1_b + l * DD, nullptr, hbuf);
        gemm_bf16<4><<<dim3(3 * DD / 64, mblk), 256, 0, stream>>>(
            hbuf, wqb, b_qkv + l * 3 * DD, nullptr, qkvb, MROWS, 3 * DD, DD, 0);
        attn_mfma_kernel<<<dim3(HH, BB), 256, 0, stream>>>(qkvb, biasb, hbuf);
        gemm_bf16<2><<<dim3(DD / 64, mblk), 256, 0, stream>>>(
            hbuf, wob, b_out + l * DD, x, x, MROWS, DD, DD, 0);
        ln_kernel<1><<<MROWS, 256, 0, stream>>>(x, ln2_g + l * DD, ln2_b + l * DD, nullptr, hbuf);
        gemm_bf16<1><<<dim3(4 * DD / 64, mblk), 256, 0, stream>>>(
            hbuf, w1b, b_fc1 + l * 4 * DD, nullptr, fc1b, MROWS, 4 * DD, DD, 0);
        gemm_bf16<2><<<dim3(DD / 64, mblk), 256, 0, stream>>>(
            fc1b, w2b, b_fc2 + l * DD, x, x, MROWS, DD, 4 * DD, 0);
    }
    final_kernel<<<BB, 256, 0, stream>>>(x, enc_g, enc_b, fin_g, fin_b, head_w, head_b, (float*)d_out);
}

// Round 9
// 4495.076 us; speedup vs baseline: 1.1521x; 1.1248x over previous
//
#include <hip/hip_runtime.h>
#include <hip/hip_bf16.h>
#include <math.h>

typedef unsigned int   u32;
typedef unsigned short u16;
typedef __bf16 bf16x8 __attribute__((ext_vector_type(8)));
typedef float  f32x4  __attribute__((ext_vector_type(4)));
typedef u16    u16x8  __attribute__((ext_vector_type(8)));
typedef u16    u16x4  __attribute__((ext_vector_type(4)));

constexpr int BB = 32, DD = 768, LL = 197, HH = 12, NTOK = 196;
constexpr int MROWS = BB * LL;        // 6304
constexpr int MTOK  = BB * NTOK;      // 6272

__device__ __forceinline__ u16 f2bf(float f) {
    union { float f; u32 u; } v; v.f = f;
    u32 r = v.u + 0x7fff + ((v.u >> 16) & 1);
    return (u16)(r >> 16);
}
__device__ __forceinline__ float bf2f(u16 u) {
    union { u32 u; float f; } v; v.u = ((u32)u) << 16;
    return v.f;
}

#define AS1 __attribute__((address_space(1)))
#define AS3 __attribute__((address_space(3)))
__device__ __forceinline__ void gload_lds16(const void* g, void* l) {
    __builtin_amdgcn_global_load_lds((const AS1 u32*)g, (AS3 u32*)l, 16, 0, 0);
}

// ---------------------------------------------------------------------------
__global__ void cast_kernel(const float* __restrict__ in, u16* __restrict__ out, int n)
{
    int i4 = (blockIdx.x * 256 + threadIdx.x) * 4;
    if (i4 >= n) return;
    float4 v = *reinterpret_cast<const float4*>(in + i4);
    out[i4]   = f2bf(v.x); out[i4+1] = f2bf(v.y);
    out[i4+2] = f2bf(v.z); out[i4+3] = f2bf(v.w);
}

__global__ void cast4_kernel(const float* s0, int n0, const float* s1, int n1,
                             const float* s2, int n2, const float* s3, int n3,
                             u16* d0, u16* d1, u16* d2, u16* d3)
{
    int i4 = (blockIdx.x * 256 + threadIdx.x) * 4;
    const float* s; u16* d; int off;
    if      (i4 < n0)            { s = s0; d = d0; off = i4; }
    else if (i4 < n0+n1)         { s = s1; d = d1; off = i4 - n0; }
    else if (i4 < n0+n1+n2)      { s = s2; d = d2; off = i4 - n0 - n1; }
    else if (i4 < n0+n1+n2+n3)   { s = s3; d = d3; off = i4 - n0 - n1 - n2; }
    else return;
    float4 v = *reinterpret_cast<const float4*>(s + off);
    d[off]   = f2bf(v.x); d[off+1] = f2bf(v.y);
    d[off+2] = f2bf(v.z); d[off+3] = f2bf(v.w);
}

// ---------------------------------------------------------------------------
__global__ void patchify_kernel(const float* __restrict__ src, int C,
                                u16* __restrict__ out, int total)
{
    int idx = blockIdx.x * 256 + threadIdx.x;
    if (idx >= total) return;
    int K = C * 256;
    int row = idx / K, k = idx % K;
    int b = row / NTOK, n = row % NTOK;
    int c = k >> 8, rem = k & 255, pi = rem >> 4, pj = rem & 15;
    int i14 = n / 14, j14 = n % 14;
    float v = src[(((size_t)b * C + c) * 224 + i14 * 16 + pi) * 224 + j14 * 16 + pj];
    out[idx] = f2bf(v);
}

// ---------------------------------------------------------------------------
// bf16 MFMA GEMM — r2-proven structure (128x128 tile, BK=32, 4 waves,
// global_load_lds staging, single-buffered, 2 barriers/K-step) with exactly
// two changes vs r2:
//  (1) chunked LDS layout: elem(R,k) = (R>>4)*512 + (k>>3)*128 + (R&15)*8 + (k&7).
//      Staged with lane l -> row (l&15), k (l>>4)*8 (DMA dest linear = layout).
//      Fragment ds_read_b128: each wave reads one contiguous 1KB region ->
//      conflict-free (was 8-way, 3.69M SQ_LDS_BANK_CONFLICT in r2).
//  (2) bijective XCD swizzle (m204) for A/W-panel L2 locality (FETCH drop
//      verified in r4).
// MODE 0: f32 out +bias      MODE 1: GELU -> bf16 out, +bias
// MODE 2: f32 out +bias+res  MODE 3: batched bias-GEMM    MODE 4: bf16 +bias
// ---------------------------------------------------------------------------
template<int MODE>
__global__ __launch_bounds__(256) void gemm_bf16(
    const u16* __restrict__ A, const u16* __restrict__ W,
    const float* __restrict__ bias, const float* __restrict__ res,
    void* __restrict__ Cout, int M, int N, int K, long long strideA)
{
    __shared__ u16 As[128 * 32];
    __shared__ u16 Bs[128 * 32];
    const int tid  = threadIdx.x;
    const int wave = tid >> 6, lane = tid & 63;
    const int lo = lane & 15, hi = lane >> 4;
    const int wr = wave >> 1, wc = wave & 1;

    // bijective XCD swizzle (m204)
    const int gx = gridDim.x;
    const int nwg = gx * gridDim.y;
    int wg = blockIdx.y * gx + blockIdx.x;
    {
        int q = nwg >> 3, r = nwg & 7;
        int xcd = wg & 7, idx = wg >> 3;
        wg = (xcd < r ? xcd * (q + 1) : r * (q + 1) + (xcd - r) * q) + idx;
    }
    const int m0 = (wg / gx) * 128, n0 = (wg % gx) * 128;
    if (MODE == 3) { A += blockIdx.z * strideA; W += blockIdx.z * strideA; }

    const int limA = M - 1;
    const int limB = (MODE == 3 ? M : N) - 1;
    // chunked staging: wave handles A-units s=wave (rows m0+wave*16..+15) and
    // s=wave+4 (rows m0+64+wave*16..); lane l -> row +（l&15), k (l>>4)*8
    int ra0 = m0 + wave * 16 + lo;      if (ra0 > limA) ra0 = limA;
    int ra1 = m0 + 64 + wave * 16 + lo; if (ra1 > limA) ra1 = limA;
    int rb0 = n0 + wave * 16 + lo;      if (rb0 > limB) rb0 = limB;
    int rb1 = n0 + 64 + wave * 16 + lo; if (rb1 > limB) rb1 = limB;
    const u16* Arow0 = A + (size_t)ra0 * K + hi * 8;
    const u16* Arow1 = A + (size_t)ra1 * K + hi * 8;
    const u16* Brow0 = W + (size_t)rb0 * K + hi * 8;
    const u16* Brow1 = W + (size_t)rb1 * K + hi * 8;

    u16* ldsA0 = &As[wave * 512];
    u16* ldsA1 = &As[2048 + wave * 512];
    u16* ldsB0 = &Bs[wave * 512];
    u16* ldsB1 = &Bs[2048 + wave * 512];

    f32x4 acc[4][4] = {};

    for (int k0 = 0; k0 < K; k0 += 32) {
        gload_lds16(Arow0 + k0, ldsA0);
        gload_lds16(Arow1 + k0, ldsA1);
        gload_lds16(Brow0 + k0, ldsB0);
        gload_lds16(Brow1 + k0, ldsB1);
        __syncthreads();
        bf16x8 af[4], bfr[4];
        #pragma unroll
        for (int i = 0; i < 4; ++i)
            af[i] = *reinterpret_cast<const bf16x8*>(&As[(wr * 4 + i) * 512 + hi * 128 + lo * 8]);
        #pragma unroll
        for (int j = 0; j < 4; ++j)
            bfr[j] = *reinterpret_cast<const bf16x8*>(&Bs[(wc * 4 + j) * 512 + hi * 128 + lo * 8]);
        #pragma unroll
        for (int i = 0; i < 4; ++i)
            #pragma unroll
            for (int j = 0; j < 4; ++j)
                acc[i][j] = __builtin_amdgcn_mfma_f32_16x16x32_bf16(af[i], bfr[j], acc[i][j], 0, 0, 0);
        __syncthreads();
    }

    const int cr = hi * 4;
    const int cc = lo;
    #pragma unroll
    for (int i = 0; i < 4; ++i) {
        #pragma unroll
        for (int r = 0; r < 4; ++r) {
            int m = m0 + wr * 64 + i * 16 + cr + r;
            if (MODE != 3 && m >= M) continue;
            #pragma unroll
            for (int j = 0; j < 4; ++j) {
                int n = n0 + wc * 64 + j * 16 + cc;
                float v = acc[i][j][r];
                if (MODE == 0) {
                    ((float*)Cout)[(size_t)m * N + n] = v + bias[n];
                } else if (MODE == 1) {
                    float t = v + bias[n];
                    t = 0.5f * t * (1.f + erff(t * 0.70710678118654752f));
                    ((u16*)Cout)[(size_t)m * N + n] = f2bf(t);
                } else if (MODE == 2) {
                    ((float*)Cout)[(size_t)m * N + n] = v + bias[n] + res[(size_t)m * N + n];
                } else if (MODE == 4) {
                    ((u16*)Cout)[(size_t)m * N + n] = f2bf(v + bias[n]);
                } else { // MODE 3
                    if (m < M && n < M) {
                        float* C3 = (float*)Cout + (size_t)blockIdx.z * LL * LL;
                        C3[(size_t)(m + 1) * LL + (n + 1)] = v * 0.03608439182435161f;
                    }
                }
            }
        }
    }
}

__global__ void bias_edge_kernel(float* __restrict__ bias)
{
    int b = blockIdx.x, t = threadIdx.x;
    if (t < LL) {
        bias[((size_t)b * LL + 0) * LL + t] = 0.f;
        bias[((size_t)b * LL + t) * LL + 0] = 0.f;
    }
}

// ---------------------------------------------------------------------------
__global__ void combine_kernel(
    const float* __restrict__ toki, const float* __restrict__ tokm,
    const float* __restrict__ cls, const float* __restrict__ pos,
    float* __restrict__ x)
{
    size_t idx = (size_t)blockIdx.x * 256 + threadIdx.x;
    if (idx >= (size_t)MROWS * DD) return;
    int d = (int)(idx % DD);
    size_t bl = idx / DD;
    int l = (int)(bl % LL);
    int b = (int)(bl / LL);
    float v;
    if (l == 0) v = cls[d];
    else {
        size_t tix = ((size_t)b * NTOK + (l - 1)) * DD + d;
        v = toki[tix] + 0.5f * tokm[tix];
    }
    x[idx] = v + pos[(size_t)l * DD + d];
}

// ---------------------------------------------------------------------------
// LayerNorm: ONE WAVE PER ROW (shfl-only reductions, zero __syncthreads).
// 4 rows per 256-thread block. OUT: 0 = f32 only, 1 = bf16 only, 2 = both.
// nrows must be a multiple of 4 (6304, 6272 both are).
// ---------------------------------------------------------------------------
template<int OUT>
__global__ __launch_bounds__(256) void ln_kernel(
    const float* __restrict__ in, const float* __restrict__ g,
    const float* __restrict__ beta, float* __restrict__ outf,
    u16* __restrict__ outb, int nrows)
{
    int row = blockIdx.x * 4 + (threadIdx.x >> 6);
    if (row >= nrows) return;
    int lane = threadIdx.x & 63;
    const float* xr = in + (size_t)row * DD;
    float4 v[3];
    #pragma unroll
    for (int p = 0; p < 3; ++p)
        v[p] = *reinterpret_cast<const float4*>(xr + p * 256 + lane * 4);
    float s = 0.f;
    #pragma unroll
    for (int p = 0; p < 3; ++p) s += v[p].x + v[p].y + v[p].z + v[p].w;
    #pragma unroll
    for (int off = 32; off; off >>= 1) s += __shfl_xor(s, off);
    float mean = s * (1.f / 768.f);
    float q = 0.f;
    #pragma unroll
    for (int p = 0; p < 3; ++p) {
        float a = v[p].x - mean, b = v[p].y - mean, c = v[p].z - mean, d = v[p].w - mean;
        q += a * a + b * b + c * c + d * d;
    }
    #pragma unroll
    for (int off = 32; off; off >>= 1) q += __shfl_xor(q, off);
    float rstd = rsqrtf(q * (1.f / 768.f) + 1e-5f);
    #pragma unroll
    for (int p = 0; p < 3; ++p) {
        int d0 = p * 256 + lane * 4;
        float4 gg = *reinterpret_cast<const float4*>(g + d0);
        float4 bb = *reinterpret_cast<const float4*>(beta + d0);
        float o0 = gg.x * (v[p].x - mean) * rstd + bb.x;
        float o1 = gg.y * (v[p].y - mean) * rstd + bb.y;
        float o2 = gg.z * (v[p].z - mean) * rstd + bb.z;
        float o3 = gg.w * (v[p].w - mean) * rstd + bb.w;
        if (OUT == 0 || OUT == 2) {
            float4 of = make_float4(o0, o1, o2, o3);
            *reinterpret_cast<float4*>(outf + (size_t)row * DD + d0) = of;
        }
        if (OUT == 1 || OUT == 2) {
            u16x4 ob = { f2bf(o0), f2bf(o1), f2bf(o2), f2bf(o3) };
            *reinterpret_cast<u16x4*>(outb + (size_t)row * DD + d0) = ob;
        }
    }
}

// ---------------------------------------------------------------------------
// MFMA attention (unchanged, passing since r3)
// ---------------------------------------------------------------------------
constexpr int KSTRE = 72;
constexpr int VSTRE = 232;
constexpr int PSTRE = 232;

__global__ __launch_bounds__(256) void attn_mfma_kernel(
    const u16* __restrict__ qkv, const float* __restrict__ bias,
    u16* __restrict__ o)
{
    const int h = blockIdx.x, b = blockIdx.y;
    const int tid = threadIdx.x, wave = tid >> 6, lane = tid & 63;
    const int lo = lane & 15, hi = lane >> 4;

    __shared__ u16 Ks[208 * KSTRE];
    __shared__ u16 Vt[64 * VSTRE];
    __shared__ u16 Ps[4][16 * PSTRE];

    const u16* qb = qkv + (size_t)b * LL * 2304;

    for (int idx = tid; idx < 208 * 8; idx += 256) {
        int key = idx >> 3, c8 = idx & 7;
        u16x8 v = {};
        if (key < LL) v = *reinterpret_cast<const u16x8*>(qb + (size_t)key * 2304 + 768 + h * 64 + c8 * 8);
        *reinterpret_cast<u16x8*>(&Ks[key * KSTRE + c8 * 8]) = v;
    }
    for (int idx = tid; idx < 224 * 8; idx += 256) {
        int key = idx >> 3, c8 = idx & 7;
        u16x8 v = {};
        if (key < LL) v = *reinterpret_cast<const u16x8*>(qb + (size_t)key * 2304 + 1536 + h * 64 + c8 * 8);
        #pragma unroll
        for (int e = 0; e < 8; ++e) Vt[(c8 * 8 + e) * VSTRE + key] = v[e];
    }
    __syncthreads();

    u16* P = Ps[wave];
    const float* biasbb = bias + (size_t)b * LL * LL;

    for (int rt = wave; rt < 13; rt += 4) {
        int q = rt * 16 + lo; if (q > LL - 1) q = LL - 1;
        const u16* qrow = qb + (size_t)q * 2304 + h * 64;
        bf16x8 qa0 = *reinterpret_cast<const bf16x8*>(qrow + hi * 8);
        bf16x8 qa1 = *reinterpret_cast<const bf16x8*>(qrow + 32 + hi * 8);

        f32x4 st[13];
        #pragma unroll
        for (int t = 0; t < 13; ++t) {
            int keyc = t * 16 + lo;
            bf16x8 kb0 = *reinterpret_cast<const bf16x8*>(&Ks[keyc * KSTRE + hi * 8]);
            bf16x8 kb1 = *reinterpret_cast<const bf16x8*>(&Ks[keyc * KSTRE + 32 + hi * 8]);
            f32x4 a = {};
            a = __builtin_amdgcn_mfma_f32_16x16x32_bf16(qa0, kb0, a, 0, 0, 0);
            a = __builtin_amdgcn_mfma_f32_16x16x32_bf16(qa1, kb1, a, 0, 0, 0);
            st[t] = a;
        }

        #pragma unroll
        for (int r = 0; r < 4; ++r) {
            int qq = rt * 16 + hi * 4 + r;
            int qc = qq > LL - 1 ? LL - 1 : qq;
            const float* brow = biasbb + (size_t)qc * LL;
            float s[13];
            float m = -1e30f;
            #pragma unroll
            for (int t = 0; t < 13; ++t) {
                int col = t * 16 + lo;
                float v;
                if (col < LL) v = st[t][r] * 0.125f + brow[col];
                else          v = -1e30f;
                s[t] = v;
                m = fmaxf(m, v);
            }
            m = fmaxf(m, __shfl_xor(m, 1));
            m = fmaxf(m, __shfl_xor(m, 2));
            m = fmaxf(m, __shfl_xor(m, 4));
            m = fmaxf(m, __shfl_xor(m, 8));
            float sum = 0.f;
            #pragma unroll
            for (int t = 0; t < 13; ++t) { float e = __expf(s[t] - m); s[t] = e; sum += e; }
            sum += __shfl_xor(sum, 1);
            sum += __shfl_xor(sum, 2);
            sum += __shfl_xor(sum, 4);
            sum += __shfl_xor(sum, 8);
            float inv = 1.f / sum;
            int prow = (hi * 4 + r) * PSTRE;
            #pragma unroll
            for (int t = 0; t < 13; ++t) P[prow + t * 16 + lo] = f2bf(s[t] * inv);
            P[prow + 208 + lo] = 0;
        }

        f32x4 oacc[4] = {};
        #pragma unroll
        for (int kt = 0; kt < 7; ++kt) {
            bf16x8 pa = *reinterpret_cast<const bf16x8*>(&P[lo * PSTRE + kt * 32 + hi * 8]);
            #pragma unroll
            for (int dt = 0; dt < 4; ++dt) {
                bf16x8 vb = *reinterpret_cast<const bf16x8*>(&Vt[(dt * 16 + lo) * VSTRE + kt * 32 + hi * 8]);
                oacc[dt] = __builtin_amdgcn_mfma_f32_16x16x32_bf16(pa, vb, oacc[dt], 0, 0, 0);
            }
        }

        #pragma unroll
        for (int dt = 0; dt < 4; ++dt) {
            #pragma unroll
            for (int r = 0; r < 4; ++r) {
                int qq = rt * 16 + hi * 4 + r;
                if (qq < LL)
                    o[((size_t)(b * LL + qq)) * DD + h * 64 + dt * 16 + lo] = f2bf(oacc[dt][r]);
            }
        }
    }
}

// ---------------------------------------------------------------------------
__global__ __launch_bounds__(256) void final_kernel(
    const float* __restrict__ x,
    const float* __restrict__ eg, const float* __restrict__ eb,
    const float* __restrict__ fg, const float* __restrict__ fb,
    const float* __restrict__ hw, const float* __restrict__ hb,
    float* __restrict__ out)
{
    int b = blockIdx.x;
    int tid = threadIdx.x;
    __shared__ float xs[768];
    __shared__ float red[256];
    const float* xr = x + (size_t)b * LL * DD;
    #pragma unroll
    for (int r = 0; r < 3; ++r) xs[tid + r * 256] = xr[tid + r * 256];
    __syncthreads();
    for (int pass = 0; pass < 2; ++pass) {
        const float* g  = pass ? fg : eg;
        const float* bb = pass ? fb : eb;
        red[tid] = xs[tid] + xs[tid + 256] + xs[tid + 512];
        __syncthreads();
        for (int off = 128; off; off >>= 1) {
            if (tid < off) red[tid] += red[tid + off];
            __syncthreads();
        }
        float mean = red[0] * (1.f / 768.f);
        __syncthreads();
        float q = 0.f;
        #pragma unroll
        for (int r = 0; r < 3; ++r) { float dv = xs[tid + r * 256] - mean; q += dv * dv; }
        red[tid] = q;
        __syncthreads();
        for (int off = 128; off; off >>= 1) {
            if (tid < off) red[tid] += red[tid + off];
            __syncthreads();
        }
        float rstd = rsqrtf(red[0] * (1.f / 768.f) + 1e-5f);
        __syncthreads();
        #pragma unroll
        for (int r = 0; r < 3; ++r) {
            int d = tid + r * 256;
            xs[d] = g[d] * (xs[d] - mean) * rstd + bb[d];
        }
        __syncthreads();
    }
    int c = tid >> 6, lane = tid & 63;
    float part = 0.f;
    for (int d = lane; d < 768; d += 64) part += xs[d] * hw[c * 768 + d];
    #pragma unroll
    for (int off = 32; off; off >>= 1) part += __shfl_down(part, off);
    if (lane == 0) out[b * 4 + c] = part + hb[c];
}

// ---------------------------------------------------------------------------
extern "C" void kernel_launch(void* const* d_in, const int* in_sizes, int n_in,
                              void* d_out, int out_size, void* d_ws, size_t ws_size,
                              hipStream_t stream)
{
    const float* img    = (const float*)d_in[0];
    const float* mask   = (const float*)d_in[1];
    const float* pe_iw  = (const float*)d_in[2];
    const float* pe_ib  = (const float*)d_in[3];
    const float* pe_ig  = (const float*)d_in[4];
    const float* pe_ibb = (const float*)d_in[5];
    const float* pe_mw  = (const float*)d_in[6];
    const float* pe_mb  = (const float*)d_in[7];
    const float* pe_mg  = (const float*)d_in[8];
    const float* pe_mbb = (const float*)d_in[9];
    const float* cls    = (const float*)d_in[10];
    const float* pos    = (const float*)d_in[11];
    const float* ln1_g  = (const float*)d_in[12];
    const float* ln1_b  = (const float*)d_in[13];
    const float* w_qkv  = (const float*)d_in[14];
    const float* b_qkv  = (const float*)d_in[15];
    const float* w_out  = (const float*)d_in[16];
    const float* b_out  = (const float*)d_in[17];
    const float* ln2_g  = (const float*)d_in[18];
    const float* ln2_b  = (const float*)d_in[19];
    const float* w_fc1  = (const float*)d_in[20];
    const float* b_fc1  = (const float*)d_in[21];
    const float* w_fc2  = (const float*)d_in[22];
    const float* b_fc2  = (const float*)d_in[23];
    const float* enc_g  = (const float*)d_in[24];
    const float* enc_b  = (const float*)d_in[25];
    const float* fin_g  = (const float*)d_in[26];
    const float* fin_b  = (const float*)d_in[27];
    const float* head_w = (const float*)d_in[28];
    const float* head_b = (const float*)d_in[29];

    char* wsb = (char*)d_ws;
    size_t off = 0;
    auto alloc = [&](size_t bytes) { void* p = wsb + off; off += (bytes + 255) & ~(size_t)255; return p; };

    float* x     = (float*)alloc((size_t)MROWS * DD * 4);
    u16*   qkvb  = (u16*)  alloc((size_t)MROWS * 3 * DD * 2);
    u16*   hbuf  = (u16*)  alloc((size_t)MROWS * DD * 2);
    u16*   fc1b  = (u16*)  alloc((size_t)MROWS * 4 * DD * 2);
    float* biasb = (float*)alloc((size_t)BB * LL * LL * 4);
    u16*   wqb   = (u16*)  alloc((size_t)3 * DD * DD * 2);
    u16*   wob   = (u16*)  alloc((size_t)DD * DD * 2);
    u16*   w1b   = (u16*)  alloc((size_t)4 * DD * DD * 2);
    u16*   w2b   = (u16*)  alloc((size_t)4 * DD * DD * 2);
    float* toki  = (float*)alloc((size_t)MTOK * DD * 4);
    float* tokm  = (float*)alloc((size_t)MTOK * DD * 4);
    u16*   pa    = fc1b;           // patches alias
    float* ttmp  = (float*)qkvb;   // pe-GEMM f32 out alias
    u16*   tokmb = hbuf;           // bf16 tok_m alias

    // ---- patch embed (img) ----
    cast_kernel<<<(DD * DD / 4 + 255) / 256, 256, 0, stream>>>(pe_iw, wob, DD * DD);
    patchify_kernel<<<(MTOK * DD + 255) / 256, 256, 0, stream>>>(img, 3, pa, MTOK * DD);
    gemm_bf16<0><<<dim3(DD / 128, MTOK / 128), 256, 0, stream>>>(
        pa, wob, pe_ib, nullptr, ttmp, MTOK, DD, DD, 0);
    ln_kernel<0><<<MTOK / 4, 256, 0, stream>>>(ttmp, pe_ig, pe_ibb, toki, nullptr, MTOK);

    // ---- patch embed (mask) ----
    cast_kernel<<<(DD * 256 / 4 + 255) / 256, 256, 0, stream>>>(pe_mw, wob, DD * 256);
    patchify_kernel<<<(MTOK * 256 + 255) / 256, 256, 0, stream>>>(mask, 1, pa, MTOK * 256);
    gemm_bf16<0><<<dim3(DD / 128, MTOK / 128), 256, 0, stream>>>(
        pa, wob, pe_mb, nullptr, ttmp, MTOK, DD, 256, 0);
    ln_kernel<2><<<MTOK / 4, 256, 0, stream>>>(ttmp, pe_mg, pe_mbb, tokm, tokmb, MTOK);

    // ---- attention bias ----
    gemm_bf16<3><<<dim3(2, 2, BB), 256, 0, stream>>>(
        tokmb, tokmb, nullptr, nullptr, biasb, NTOK, NTOK, DD, (long long)NTOK * DD);
    bias_edge_kernel<<<BB, 256, 0, stream>>>(biasb);

    // ---- combine ----
    combine_kernel<<<(MROWS * DD + 255) / 256, 256, 0, stream>>>(toki, tokm, cls, pos, x);

    const int mblk = (MROWS + 127) / 128;   // 50
    const int wqn = 3 * DD * DD, won = DD * DD, w1n = 4 * DD * DD, w2n = 4 * DD * DD;
    const int castTot = (wqn + won + w1n + w2n) / 4;
    for (int l = 0; l < 12; ++l) {
        cast4_kernel<<<(castTot + 255) / 256, 256, 0, stream>>>(
            w_qkv + (size_t)l * wqn, wqn, w_out + (size_t)l * won, won,
            w_fc1 + (size_t)l * w1n, w1n, w_fc2 + (size_t)l * w2n, w2n,
            wqb, wob, w1b, w2b);
        ln_kernel<1><<<MROWS / 4, 256, 0, stream>>>(x, ln1_g + l * DD, ln1_b + l * DD, nullptr, hbuf, MROWS);
        gemm_bf16<4><<<dim3(3 * DD / 128, mblk), 256, 0, stream>>>(
            hbuf, wqb, b_qkv + l * 3 * DD, nullptr, qkvb, MROWS, 3 * DD, DD, 0);
        attn_mfma_kernel<<<dim3(HH, BB), 256, 0, stream>>>(qkvb, biasb, hbuf);
        gemm_bf16<2><<<dim3(DD / 128, mblk), 256, 0, stream>>>(
            hbuf, wob, b_out + l * DD, x, x, MROWS, DD, DD, 0);
        ln_kernel<1><<<MROWS / 4, 256, 0, stream>>>(x, ln2_g + l * DD, ln2_b + l * DD, nullptr, hbuf, MROWS);
        gemm_bf16<1><<<dim3(4 * DD / 128, mblk), 256, 0, stream>>>(
            hbuf, w1b, b_fc1 + l * 4 * DD, nullptr, fc1b, MROWS, 4 * DD, DD, 0);
        gemm_bf16<2><<<dim3(DD / 128, mblk), 256, 0, stream>>>(
            fc1b, w2b, b_fc2 + l * DD, x, x, MROWS, DD, 4 * DD, 0);
    }
    final_kernel<<<BB, 256, 0, stream>>>(x, enc_g, enc_b, fin_g, fin_b, head_w, head_b, (float*)d_out);
}

// Round 10
// 3727.744 us; speedup vs baseline: 1.3893x; 1.2058x over previous
//
#include <hip/hip_runtime.h>
#include <hip/hip_bf16.h>
#include <math.h>

typedef unsigned int   u32;
typedef unsigned short u16;
typedef __bf16 bf16x8 __attribute__((ext_vector_type(8)));
typedef float  f32x4  __attribute__((ext_vector_type(4)));
typedef u16    u16x8  __attribute__((ext_vector_type(8)));
typedef u16    u16x4  __attribute__((ext_vector_type(4)));

constexpr int BB = 32, DD = 768, LL = 197, HH = 12, NTOK = 196;
constexpr int MROWS = BB * LL;        // 6304
constexpr int MTOK  = BB * NTOK;      // 6272

__device__ __forceinline__ u16 f2bf(float f) {
    union { float f; u32 u; } v; v.f = f;
    u32 r = v.u + 0x7fff + ((v.u >> 16) & 1);
    return (u16)(r >> 16);
}
__device__ __forceinline__ float bf2f(u16 u) {
    union { u32 u; float f; } v; v.u = ((u32)u) << 16;
    return v.f;
}

#define AS1 __attribute__((address_space(1)))
#define AS3 __attribute__((address_space(3)))
__device__ __forceinline__ void gload_lds16(const void* g, void* l) {
    __builtin_amdgcn_global_load_lds((const AS1 u32*)g, (AS3 u32*)l, 16, 0, 0);
}

// ---------------------------------------------------------------------------
__global__ void cast_kernel(const float* __restrict__ in, u16* __restrict__ out, int n)
{
    int i4 = (blockIdx.x * 256 + threadIdx.x) * 4;
    if (i4 >= n) return;
    float4 v = *reinterpret_cast<const float4*>(in + i4);
    out[i4]   = f2bf(v.x); out[i4+1] = f2bf(v.y);
    out[i4+2] = f2bf(v.z); out[i4+3] = f2bf(v.w);
}

__global__ void cast4_kernel(const float* s0, int n0, const float* s1, int n1,
                             const float* s2, int n2, const float* s3, int n3,
                             u16* d0, u16* d1, u16* d2, u16* d3)
{
    int i4 = (blockIdx.x * 256 + threadIdx.x) * 4;
    const float* s; u16* d; int off;
    if      (i4 < n0)            { s = s0; d = d0; off = i4; }
    else if (i4 < n0+n1)         { s = s1; d = d1; off = i4 - n0; }
    else if (i4 < n0+n1+n2)      { s = s2; d = d2; off = i4 - n0 - n1; }
    else if (i4 < n0+n1+n2+n3)   { s = s3; d = d3; off = i4 - n0 - n1 - n2; }
    else return;
    float4 v = *reinterpret_cast<const float4*>(s + off);
    d[off]   = f2bf(v.x); d[off+1] = f2bf(v.y);
    d[off+2] = f2bf(v.z); d[off+3] = f2bf(v.w);
}

// ---------------------------------------------------------------------------
__global__ void patchify_kernel(const float* __restrict__ src, int C,
                                u16* __restrict__ out, int total)
{
    int idx = blockIdx.x * 256 + threadIdx.x;
    if (idx >= total) return;
    int K = C * 256;
    int row = idx / K, k = idx % K;
    int b = row / NTOK, n = row % NTOK;
    int c = k >> 8, rem = k & 255, pi = rem >> 4, pj = rem & 15;
    int i14 = n / 14, j14 = n % 14;
    float v = src[(((size_t)b * C + c) * 224 + i14 * 16 + pi) * 224 + j14 * 16 + pj];
    out[idx] = f2bf(v);
}

// ---------------------------------------------------------------------------
// bf16 MFMA GEMM — r2 base (128x128, BK=32, 4 waves, global_load_lds,
// single-buffered, 2 barriers/K-step, NO block swizzle) with the T2/T21
// XOR-swizzled-source fix:
//   staging lane l: row (l>>2), 16B-chunk ((l&3) ^ ((l>>2)&3))  -> global
//     coalescing identical to r2 (each 16-lane group = 4 full 64B lines);
//   fragment read: As[unit*512 + (lane&15)*32 + ((lane>>4)^(lane&3))*8]
//     -> bijection over the 1KB wave region -> zero bank conflicts.
// MODE 0: f32 +bias   MODE 1: GELU->bf16 +bias   MODE 2: f32 +bias+res
// MODE 3: batched bias-GEMM   MODE 4: bf16 +bias
// MODE 5: split-K=2, raw f32 partial store to Cout + z*M*N (no bias)
// ---------------------------------------------------------------------------
template<int MODE>
__global__ __launch_bounds__(256) void gemm_bf16(
    const u16* __restrict__ A, const u16* __restrict__ W,
    const float* __restrict__ bias, const float* __restrict__ res,
    void* __restrict__ Cout, int M, int N, int K, long long strideA)
{
    __shared__ u16 As[128 * 32];
    __shared__ u16 Bs[128 * 32];
    const int tid  = threadIdx.x;
    const int wave = tid >> 6, lane = tid & 63;
    const int lo = lane & 15, hi = lane >> 4;
    const int wr = wave >> 1, wc = wave & 1;

    const int m0 = blockIdx.y * 128, n0 = blockIdx.x * 128;
    if (MODE == 3) { A += blockIdx.z * strideA; W += blockIdx.z * strideA; }

    const int Klen = (MODE == 5) ? (K >> 1) : K;
    const int kb   = (MODE == 5) ? blockIdx.z * Klen : 0;

    const int limA = M - 1;
    const int limB = (MODE == 3 ? M : N) - 1;
    // XOR-swizzled source staging (row-contiguous per 4 lanes)
    const int srow = lane >> 2;
    const int scol = (((lane & 3) ^ (srow & 3))) << 3;
    int ra0 = m0 + wave * 16 + srow;      if (ra0 > limA) ra0 = limA;
    int ra1 = m0 + 64 + wave * 16 + srow; if (ra1 > limA) ra1 = limA;
    int rb0 = n0 + wave * 16 + srow;      if (rb0 > limB) rb0 = limB;
    int rb1 = n0 + 64 + wave * 16 + srow; if (rb1 > limB) rb1 = limB;
    const u16* Arow0 = A + (size_t)ra0 * K + kb + scol;
    const u16* Arow1 = A + (size_t)ra1 * K + kb + scol;
    const u16* Brow0 = W + (size_t)rb0 * K + kb + scol;
    const u16* Brow1 = W + (size_t)rb1 * K + kb + scol;

    u16* ldsA0 = &As[wave * 512];
    u16* ldsA1 = &As[2048 + wave * 512];
    u16* ldsB0 = &Bs[wave * 512];
    u16* ldsB1 = &Bs[2048 + wave * 512];

    // XOR'd fragment read offset within a 16x32 unit
    const int fro = lo * 32 + ((hi ^ (lo & 3)) << 3);

    f32x4 acc[4][4] = {};

    for (int k0 = 0; k0 < Klen; k0 += 32) {
        gload_lds16(Arow0 + k0, ldsA0);
        gload_lds16(Arow1 + k0, ldsA1);
        gload_lds16(Brow0 + k0, ldsB0);
        gload_lds16(Brow1 + k0, ldsB1);
        __syncthreads();
        bf16x8 af[4], bfr[4];
        #pragma unroll
        for (int i = 0; i < 4; ++i)
            af[i] = *reinterpret_cast<const bf16x8*>(&As[(wr * 4 + i) * 512 + fro]);
        #pragma unroll
        for (int j = 0; j < 4; ++j)
            bfr[j] = *reinterpret_cast<const bf16x8*>(&Bs[(wc * 4 + j) * 512 + fro]);
        #pragma unroll
        for (int i = 0; i < 4; ++i)
            #pragma unroll
            for (int j = 0; j < 4; ++j)
                acc[i][j] = __builtin_amdgcn_mfma_f32_16x16x32_bf16(af[i], bfr[j], acc[i][j], 0, 0, 0);
        __syncthreads();
    }

    const size_t zoff = (MODE == 5) ? (size_t)blockIdx.z * M * N : 0;
    const int cr = hi * 4;
    const int cc = lo;
    #pragma unroll
    for (int i = 0; i < 4; ++i) {
        #pragma unroll
        for (int r = 0; r < 4; ++r) {
            int m = m0 + wr * 64 + i * 16 + cr + r;
            if (MODE != 3 && m >= M) continue;
            #pragma unroll
            for (int j = 0; j < 4; ++j) {
                int n = n0 + wc * 64 + j * 16 + cc;
                float v = acc[i][j][r];
                if (MODE == 0) {
                    ((float*)Cout)[(size_t)m * N + n] = v + bias[n];
                } else if (MODE == 1) {
                    float t = v + bias[n];
                    t = 0.5f * t * (1.f + erff(t * 0.70710678118654752f));
                    ((u16*)Cout)[(size_t)m * N + n] = f2bf(t);
                } else if (MODE == 2) {
                    ((float*)Cout)[(size_t)m * N + n] = v + bias[n] + res[(size_t)m * N + n];
                } else if (MODE == 4) {
                    ((u16*)Cout)[(size_t)m * N + n] = f2bf(v + bias[n]);
                } else if (MODE == 5) {
                    ((float*)Cout)[zoff + (size_t)m * N + n] = v;
                } else { // MODE 3
                    if (m < M && n < M) {
                        float* C3 = (float*)Cout + (size_t)blockIdx.z * LL * LL;
                        C3[(size_t)(m + 1) * LL + (n + 1)] = v * 0.03608439182435161f;
                    }
                }
            }
        }
    }
}

// x[i] += p0[i] + p1[i] + bias[i % N]   (split-K reduce, N % 4 == 0)
__global__ void splitk_reduce_kernel(float* __restrict__ x, const float* __restrict__ p,
                                     const float* __restrict__ bias, int MN, int N)
{
    int i4 = (blockIdx.x * 256 + threadIdx.x) * 4;
    if (i4 >= MN) return;
    float4 a  = *reinterpret_cast<const float4*>(x + i4);
    float4 p0 = *reinterpret_cast<const float4*>(p + i4);
    float4 p1 = *reinterpret_cast<const float4*>(p + (size_t)MN + i4);
    float4 b  = *reinterpret_cast<const float4*>(bias + (i4 % N));
    a.x += p0.x + p1.x + b.x;
    a.y += p0.y + p1.y + b.y;
    a.z += p0.z + p1.z + b.z;
    a.w += p0.w + p1.w + b.w;
    *reinterpret_cast<float4*>(x + i4) = a;
}

__global__ void bias_edge_kernel(float* __restrict__ bias)
{
    int b = blockIdx.x, t = threadIdx.x;
    if (t < LL) {
        bias[((size_t)b * LL + 0) * LL + t] = 0.f;
        bias[((size_t)b * LL + t) * LL + 0] = 0.f;
    }
}

// ---------------------------------------------------------------------------
__global__ void combine_kernel(
    const float* __restrict__ toki, const float* __restrict__ tokm,
    const float* __restrict__ cls, const float* __restrict__ pos,
    float* __restrict__ x)
{
    size_t idx = (size_t)blockIdx.x * 256 + threadIdx.x;
    if (idx >= (size_t)MROWS * DD) return;
    int d = (int)(idx % DD);
    size_t bl = idx / DD;
    int l = (int)(bl % LL);
    int b = (int)(bl / LL);
    float v;
    if (l == 0) v = cls[d];
    else {
        size_t tix = ((size_t)b * NTOK + (l - 1)) * DD + d;
        v = toki[tix] + 0.5f * tokm[tix];
    }
    x[idx] = v + pos[(size_t)l * DD + d];
}

// ---------------------------------------------------------------------------
// LayerNorm: one wave per row, shfl-only. 4 rows/block.
// ---------------------------------------------------------------------------
template<int OUT>
__global__ __launch_bounds__(256) void ln_kernel(
    const float* __restrict__ in, const float* __restrict__ g,
    const float* __restrict__ beta, float* __restrict__ outf,
    u16* __restrict__ outb, int nrows)
{
    int row = blockIdx.x * 4 + (threadIdx.x >> 6);
    if (row >= nrows) return;
    int lane = threadIdx.x & 63;
    const float* xr = in + (size_t)row * DD;
    float4 v[3];
    #pragma unroll
    for (int p = 0; p < 3; ++p)
        v[p] = *reinterpret_cast<const float4*>(xr + p * 256 + lane * 4);
    float s = 0.f;
    #pragma unroll
    for (int p = 0; p < 3; ++p) s += v[p].x + v[p].y + v[p].z + v[p].w;
    #pragma unroll
    for (int off = 32; off; off >>= 1) s += __shfl_xor(s, off);
    float mean = s * (1.f / 768.f);
    float q = 0.f;
    #pragma unroll
    for (int p = 0; p < 3; ++p) {
        float a = v[p].x - mean, b = v[p].y - mean, c = v[p].z - mean, d = v[p].w - mean;
        q += a * a + b * b + c * c + d * d;
    }
    #pragma unroll
    for (int off = 32; off; off >>= 1) q += __shfl_xor(q, off);
    float rstd = rsqrtf(q * (1.f / 768.f) + 1e-5f);
    #pragma unroll
    for (int p = 0; p < 3; ++p) {
        int d0 = p * 256 + lane * 4;
        float4 gg = *reinterpret_cast<const float4*>(g + d0);
        float4 bb = *reinterpret_cast<const float4*>(beta + d0);
        float o0 = gg.x * (v[p].x - mean) * rstd + bb.x;
        float o1 = gg.y * (v[p].y - mean) * rstd + bb.y;
        float o2 = gg.z * (v[p].z - mean) * rstd + bb.z;
        float o3 = gg.w * (v[p].w - mean) * rstd + bb.w;
        if (OUT == 0 || OUT == 2) {
            float4 of = make_float4(o0, o1, o2, o3);
            *reinterpret_cast<float4*>(outf + (size_t)row * DD + d0) = of;
        }
        if (OUT == 1 || OUT == 2) {
            u16x4 ob = { f2bf(o0), f2bf(o1), f2bf(o2), f2bf(o3) };
            *reinterpret_cast<u16x4*>(outb + (size_t)row * DD + d0) = ob;
        }
    }
}

// ---------------------------------------------------------------------------
// MFMA attention (unchanged, passing since r3)
// ---------------------------------------------------------------------------
constexpr int KSTRE = 72;
constexpr int VSTRE = 232;
constexpr int PSTRE = 232;

__global__ __launch_bounds__(256) void attn_mfma_kernel(
    const u16* __restrict__ qkv, const float* __restrict__ bias,
    u16* __restrict__ o)
{
    const int h = blockIdx.x, b = blockIdx.y;
    const int tid = threadIdx.x, wave = tid >> 6, lane = tid & 63;
    const int lo = lane & 15, hi = lane >> 4;

    __shared__ u16 Ks[208 * KSTRE];
    __shared__ u16 Vt[64 * VSTRE];
    __shared__ u16 Ps[4][16 * PSTRE];

    const u16* qb = qkv + (size_t)b * LL * 2304;

    for (int idx = tid; idx < 208 * 8; idx += 256) {
        int key = idx >> 3, c8 = idx & 7;
        u16x8 v = {};
        if (key < LL) v = *reinterpret_cast<const u16x8*>(qb + (size_t)key * 2304 + 768 + h * 64 + c8 * 8);
        *reinterpret_cast<u16x8*>(&Ks[key * KSTRE + c8 * 8]) = v;
    }
    for (int idx = tid; idx < 224 * 8; idx += 256) {
        int key = idx >> 3, c8 = idx & 7;
        u16x8 v = {};
        if (key < LL) v = *reinterpret_cast<const u16x8*>(qb + (size_t)key * 2304 + 1536 + h * 64 + c8 * 8);
        #pragma unroll
        for (int e = 0; e < 8; ++e) Vt[(c8 * 8 + e) * VSTRE + key] = v[e];
    }
    __syncthreads();

    u16* P = Ps[wave];
    const float* biasbb = bias + (size_t)b * LL * LL;

    for (int rt = wave; rt < 13; rt += 4) {
        int q = rt * 16 + lo; if (q > LL - 1) q = LL - 1;
        const u16* qrow = qb + (size_t)q * 2304 + h * 64;
        bf16x8 qa0 = *reinterpret_cast<const bf16x8*>(qrow + hi * 8);
        bf16x8 qa1 = *reinterpret_cast<const bf16x8*>(qrow + 32 + hi * 8);

        f32x4 st[13];
        #pragma unroll
        for (int t = 0; t < 13; ++t) {
            int keyc = t * 16 + lo;
            bf16x8 kb0 = *reinterpret_cast<const bf16x8*>(&Ks[keyc * KSTRE + hi * 8]);
            bf16x8 kb1 = *reinterpret_cast<const bf16x8*>(&Ks[keyc * KSTRE + 32 + hi * 8]);
            f32x4 a = {};
            a = __builtin_amdgcn_mfma_f32_16x16x32_bf16(qa0, kb0, a, 0, 0, 0);
            a = __builtin_amdgcn_mfma_f32_16x16x32_bf16(qa1, kb1, a, 0, 0, 0);
            st[t] = a;
        }

        #pragma unroll
        for (int r = 0; r < 4; ++r) {
            int qq = rt * 16 + hi * 4 + r;
            int qc = qq > LL - 1 ? LL - 1 : qq;
            const float* brow = biasbb + (size_t)qc * LL;
            float s[13];
            float m = -1e30f;
            #pragma unroll
            for (int t = 0; t < 13; ++t) {
                int col = t * 16 + lo;
                float v;
                if (col < LL) v = st[t][r] * 0.125f + brow[col];
                else          v = -1e30f;
                s[t] = v;
                m = fmaxf(m, v);
            }
            m = fmaxf(m, __shfl_xor(m, 1));
            m = fmaxf(m, __shfl_xor(m, 2));
            m = fmaxf(m, __shfl_xor(m, 4));
            m = fmaxf(m, __shfl_xor(m, 8));
            float sum = 0.f;
            #pragma unroll
            for (int t = 0; t < 13; ++t) { float e = __expf(s[t] - m); s[t] = e; sum += e; }
            sum += __shfl_xor(sum, 1);
            sum += __shfl_xor(sum, 2);
            sum += __shfl_xor(sum, 4);
            sum += __shfl_xor(sum, 8);
            float inv = 1.f / sum;
            int prow = (hi * 4 + r) * PSTRE;
            #pragma unroll
            for (int t = 0; t < 13; ++t) P[prow + t * 16 + lo] = f2bf(s[t] * inv);
            P[prow + 208 + lo] = 0;
        }

        f32x4 oacc[4] = {};
        #pragma unroll
        for (int kt = 0; kt < 7; ++kt) {
            bf16x8 pa = *reinterpret_cast<const bf16x8*>(&P[lo * PSTRE + kt * 32 + hi * 8]);
            #pragma unroll
            for (int dt = 0; dt < 4; ++dt) {
                bf16x8 vb = *reinterpret_cast<const bf16x8*>(&Vt[(dt * 16 + lo) * VSTRE + kt * 32 + hi * 8]);
                oacc[dt] = __builtin_amdgcn_mfma_f32_16x16x32_bf16(pa, vb, oacc[dt], 0, 0, 0);
            }
        }

        #pragma unroll
        for (int dt = 0; dt < 4; ++dt) {
            #pragma unroll
            for (int r = 0; r < 4; ++r) {
                int qq = rt * 16 + hi * 4 + r;
                if (qq < LL)
                    o[((size_t)(b * LL + qq)) * DD + h * 64 + dt * 16 + lo] = f2bf(oacc[dt][r]);
            }
        }
    }
}

// ---------------------------------------------------------------------------
__global__ __launch_bounds__(256) void final_kernel(
    const float* __restrict__ x,
    const float* __restrict__ eg, const float* __restrict__ eb,
    const float* __restrict__ fg, const float* __restrict__ fb,
    const float* __restrict__ hw, const float* __restrict__ hb,
    float* __restrict__ out)
{
    int b = blockIdx.x;
    int tid = threadIdx.x;
    __shared__ float xs[768];
    __shared__ float red[256];
    const float* xr = x + (size_t)b * LL * DD;
    #pragma unroll
    for (int r = 0; r < 3; ++r) xs[tid + r * 256] = xr[tid + r * 256];
    __syncthreads();
    for (int pass = 0; pass < 2; ++pass) {
        const float* g  = pass ? fg : eg;
        const float* bb = pass ? fb : eb;
        red[tid] = xs[tid] + xs[tid + 256] + xs[tid + 512];
        __syncthreads();
        for (int off = 128; off; off >>= 1) {
            if (tid < off) red[tid] += red[tid + off];
            __syncthreads();
        }
        float mean = red[0] * (1.f / 768.f);
        __syncthreads();
        float q = 0.f;
        #pragma unroll
        for (int r = 0; r < 3; ++r) { float dv = xs[tid + r * 256] - mean; q += dv * dv; }
        red[tid] = q;
        __syncthreads();
        for (int off = 128; off; off >>= 1) {
            if (tid < off) red[tid] += red[tid + off];
            __syncthreads();
        }
        float rstd = rsqrtf(red[0] * (1.f / 768.f) + 1e-5f);
        __syncthreads();
        #pragma unroll
        for (int r = 0; r < 3; ++r) {
            int d = tid + r * 256;
            xs[d] = g[d] * (xs[d] - mean) * rstd + bb[d];
        }
        __syncthreads();
    }
    int c = tid >> 6, lane = tid & 63;
    float part = 0.f;
    for (int d = lane; d < 768; d += 64) part += xs[d] * hw[c * 768 + d];
    #pragma unroll
    for (int off = 32; off; off >>= 1) part += __shfl_down(part, off);
    if (lane == 0) out[b * 4 + c] = part + hb[c];
}

// ---------------------------------------------------------------------------
extern "C" void kernel_launch(void* const* d_in, const int* in_sizes, int n_in,
                              void* d_out, int out_size, void* d_ws, size_t ws_size,
                              hipStream_t stream)
{
    const float* img    = (const float*)d_in[0];
    const float* mask   = (const float*)d_in[1];
    const float* pe_iw  = (const float*)d_in[2];
    const float* pe_ib  = (const float*)d_in[3];
    const float* pe_ig  = (const float*)d_in[4];
    const float* pe_ibb = (const float*)d_in[5];
    const float* pe_mw  = (const float*)d_in[6];
    const float* pe_mb  = (const float*)d_in[7];
    const float* pe_mg  = (const float*)d_in[8];
    const float* pe_mbb = (const float*)d_in[9];
    const float* cls    = (const float*)d_in[10];
    const float* pos    = (const float*)d_in[11];
    const float* ln1_g  = (const float*)d_in[12];
    const float* ln1_b  = (const float*)d_in[13];
    const float* w_qkv  = (const float*)d_in[14];
    const float* b_qkv  = (const float*)d_in[15];
    const float* w_out  = (const float*)d_in[16];
    const float* b_out  = (const float*)d_in[17];
    const float* ln2_g  = (const float*)d_in[18];
    const float* ln2_b  = (const float*)d_in[19];
    const float* w_fc1  = (const float*)d_in[20];
    const float* b_fc1  = (const float*)d_in[21];
    const float* w_fc2  = (const float*)d_in[22];
    const float* b_fc2  = (const float*)d_in[23];
    const float* enc_g  = (const float*)d_in[24];
    const float* enc_b  = (const float*)d_in[25];
    const float* fin_g  = (const float*)d_in[26];
    const float* fin_b  = (const float*)d_in[27];
    const float* head_w = (const float*)d_in[28];
    const float* head_b = (const float*)d_in[29];

    char* wsb = (char*)d_ws;
    size_t off = 0;
    auto alloc = [&](size_t bytes) { void* p = wsb + off; off += (bytes + 255) & ~(size_t)255; return p; };

    float* x     = (float*)alloc((size_t)MROWS * DD * 4);
    u16*   qkvb  = (u16*)  alloc((size_t)MROWS * 3 * DD * 2);
    u16*   hbuf  = (u16*)  alloc((size_t)MROWS * DD * 2);
    u16*   fc1b  = (u16*)  alloc((size_t)MROWS * 4 * DD * 2);
    float* biasb = (float*)alloc((size_t)BB * LL * LL * 4);
    u16*   wqb   = (u16*)  alloc((size_t)3 * DD * DD * 2);
    u16*   wob   = (u16*)  alloc((size_t)DD * DD * 2);
    u16*   w1b   = (u16*)  alloc((size_t)4 * DD * DD * 2);
    u16*   w2b   = (u16*)  alloc((size_t)4 * DD * DD * 2);
    float* toki  = (float*)alloc((size_t)MTOK * DD * 4);
    float* tokm  = (float*)alloc((size_t)MTOK * DD * 4);
    u16*   pa    = fc1b;            // patches alias
    float* ttmp  = (float*)qkvb;    // pe-GEMM f32 out alias
    u16*   tokmb = hbuf;            // bf16 tok_m alias
    float* partf = (float*)qkvb;    // split-K partials: 2 x MROWS*DD f32 over qkvb+hbuf
                                    // (= 38,731,776 B exactly; qkvb dead after attn,
                                    //  hbuf dead after fc1 at fc2 time)

    // ---- patch embed (img) ----
    cast_kernel<<<(DD * DD / 4 + 255) / 256, 256, 0, stream>>>(pe_iw, wob, DD * DD);
    patchify_kernel<<<(MTOK * DD + 255) / 256, 256, 0, stream>>>(img, 3, pa, MTOK * DD);
    gemm_bf16<0><<<dim3(DD / 128, MTOK / 128), 256, 0, stream>>>(
        pa, wob, pe_ib, nullptr, ttmp, MTOK, DD, DD, 0);
    ln_kernel<0><<<MTOK / 4, 256, 0, stream>>>(ttmp, pe_ig, pe_ibb, toki, nullptr, MTOK);

    // ---- patch embed (mask) ----
    cast_kernel<<<(DD * 256 / 4 + 255) / 256, 256, 0, stream>>>(pe_mw, wob, DD * 256);
    patchify_kernel<<<(MTOK * 256 + 255) / 256, 256, 0, stream>>>(mask, 1, pa, MTOK * 256);
    gemm_bf16<0><<<dim3(DD / 128, MTOK / 128), 256, 0, stream>>>(
        pa, wob, pe_mb, nullptr, ttmp, MTOK, DD, 256, 0);
    ln_kernel<2><<<MTOK / 4, 256, 0, stream>>>(ttmp, pe_mg, pe_mbb, tokm, tokmb, MTOK);

    // ---- attention bias ----
    gemm_bf16<3><<<dim3(2, 2, BB), 256, 0, stream>>>(
        tokmb, tokmb, nullptr, nullptr, biasb, NTOK, NTOK, DD, (long long)NTOK * DD);
    bias_edge_kernel<<<BB, 256, 0, stream>>>(biasb);

    // ---- combine ----
    combine_kernel<<<(MROWS * DD + 255) / 256, 256, 0, stream>>>(toki, tokm, cls, pos, x);

    const int mblk = (MROWS + 127) / 128;   // 50
    const int MN = MROWS * DD;
    const int wqn = 3 * DD * DD, won = DD * DD, w1n = 4 * DD * DD, w2n = 4 * DD * DD;
    const int castTot = (wqn + won + w1n + w2n) / 4;
    for (int l = 0; l < 12; ++l) {
        cast4_kernel<<<(castTot + 255) / 256, 256, 0, stream>>>(
            w_qkv + (size_t)l * wqn, wqn, w_out + (size_t)l * won, won,
            w_fc1 + (size_t)l * w1n, w1n, w_fc2 + (size_t)l * w2n, w2n,
            wqb, wob, w1b, w2b);
        ln_kernel<1><<<MROWS / 4, 256, 0, stream>>>(x, ln1_g + l * DD, ln1_b + l * DD, nullptr, hbuf, MROWS);
        gemm_bf16<4><<<dim3(3 * DD / 128, mblk), 256, 0, stream>>>(
            hbuf, wqb, b_qkv + l * 3 * DD, nullptr, qkvb, MROWS, 3 * DD, DD, 0);
        attn_mfma_kernel<<<dim3(HH, BB), 256, 0, stream>>>(qkvb, biasb, hbuf);
        gemm_bf16<2><<<dim3(DD / 128, mblk), 256, 0, stream>>>(
            hbuf, wob, b_out + l * DD, x, x, MROWS, DD, DD, 0);
        ln_kernel<1><<<MROWS / 4, 256, 0, stream>>>(x, ln2_g + l * DD, ln2_b + l * DD, nullptr, hbuf, MROWS);
        gemm_bf16<1><<<dim3(4 * DD / 128, mblk), 256, 0, stream>>>(
            hbuf, w1b, b_fc1 + l * 4 * DD, nullptr, fc1b, MROWS, 4 * DD, DD, 0);
        // fc2 split-K=2: partials into qkvb+hbuf region (both dead here)
        gemm_bf16<5><<<dim3(DD / 128, mblk, 2), 256, 0, stream>>>(
            fc1b, w2b, nullptr, nullptr, partf, MROWS, DD, 4 * DD, 0);
        splitk_reduce_kernel<<<(MN / 4 + 255) / 256, 256, 0, stream>>>(
            x, partf, b_fc2 + l * DD, MN, DD);
    }
    final_kernel<<<BB, 256, 0, stream>>>(x, enc_g, enc_b, fin_g, fin_b, head_w, head_b, (float*)d_out);
}

// Round 11
// 3706.358 us; speedup vs baseline: 1.3973x; 1.0058x over previous
//
#include <hip/hip_runtime.h>
#include <hip/hip_bf16.h>
#include <math.h>

typedef unsigned int   u32;
typedef unsigned short u16;
typedef __bf16 bf16x8 __attribute__((ext_vector_type(8)));
typedef float  f32x4  __attribute__((ext_vector_type(4)));
typedef u16    u16x8  __attribute__((ext_vector_type(8)));
typedef u16    u16x4  __attribute__((ext_vector_type(4)));

constexpr int BB = 32, DD = 768, LL = 197, HH = 12, NTOK = 196;
constexpr int MROWS = BB * LL;        // 6304
constexpr int MTOK  = BB * NTOK;      // 6272

__device__ __forceinline__ u16 f2bf(float f) {
    union { float f; u32 u; } v; v.f = f;
    u32 r = v.u + 0x7fff + ((v.u >> 16) & 1);
    return (u16)(r >> 16);
}
__device__ __forceinline__ float bf2f(u16 u) {
    union { u32 u; float f; } v; v.u = ((u32)u) << 16;
    return v.f;
}

#define AS1 __attribute__((address_space(1)))
#define AS3 __attribute__((address_space(3)))
__device__ __forceinline__ void gload_lds16(const void* g, void* l) {
    __builtin_amdgcn_global_load_lds((const AS1 u32*)g, (AS3 u32*)l, 16, 0, 0);
}

// ---------------------------------------------------------------------------
__global__ void cast_kernel(const float* __restrict__ in, u16* __restrict__ out, int n)
{
    int i4 = (blockIdx.x * 256 + threadIdx.x) * 4;
    if (i4 >= n) return;
    float4 v = *reinterpret_cast<const float4*>(in + i4);
    out[i4]   = f2bf(v.x); out[i4+1] = f2bf(v.y);
    out[i4+2] = f2bf(v.z); out[i4+3] = f2bf(v.w);
}

__global__ void cast4_kernel(const float* s0, int n0, const float* s1, int n1,
                             const float* s2, int n2, const float* s3, int n3,
                             u16* d0, u16* d1, u16* d2, u16* d3)
{
    int i4 = (blockIdx.x * 256 + threadIdx.x) * 4;
    const float* s; u16* d; int off;
    if      (i4 < n0)            { s = s0; d = d0; off = i4; }
    else if (i4 < n0+n1)         { s = s1; d = d1; off = i4 - n0; }
    else if (i4 < n0+n1+n2)      { s = s2; d = d2; off = i4 - n0 - n1; }
    else if (i4 < n0+n1+n2+n3)   { s = s3; d = d3; off = i4 - n0 - n1 - n2; }
    else return;
    float4 v = *reinterpret_cast<const float4*>(s + off);
    d[off]   = f2bf(v.x); d[off+1] = f2bf(v.y);
    d[off+2] = f2bf(v.z); d[off+3] = f2bf(v.w);
}

// ---------------------------------------------------------------------------
__global__ void patchify_kernel(const float* __restrict__ src, int C,
                                u16* __restrict__ out, int total)
{
    int idx = blockIdx.x * 256 + threadIdx.x;
    if (idx >= total) return;
    int K = C * 256;
    int row = idx / K, k = idx % K;
    int b = row / NTOK, n = row % NTOK;
    int c = k >> 8, rem = k & 255, pi = rem >> 4, pj = rem & 15;
    int i14 = n / 14, j14 = n % 14;
    float v = src[(((size_t)b * C + c) * 224 + i14 * 16 + pi) * 224 + j14 * 16 + pj];
    out[idx] = f2bf(v);
}

// ---------------------------------------------------------------------------
// bf16 MFMA GEMM — r2 base (128x128, BK=32, 4 waves, global_load_lds,
// single-buffered, 2 barriers/K-step) with CORRECT XOR-swizzled source:
//   s(row) = (row>>1)&3  (r10's row&3 left even rows colliding — counter
//   showed the identical 3.69M conflicts as r2).
//   staging lane l: row (l>>2), 16B-chunk ((l&3) ^ ((l>>3)&3))
//     -> coalescing identical to r2 (4 lanes per 64B line, permuted in-line);
//   fragment read: As[unit*512 + lo*32 + ((hi ^ ((lo>>1)&3))<<3)]
//     -> every consecutive-8-lane group covers 8 distinct 16B slots per 128B
//        bank period -> zero conflicts; bijection over the 1KB unit.
// MODE 0: f32 +bias   MODE 1: GELU->bf16 +bias   MODE 2: f32 +bias+res
// MODE 3: batched bias-GEMM   MODE 4: bf16 +bias
// MODE 5: split-K=2, raw f32 partial store to Cout + z*M*N (no bias)
// ---------------------------------------------------------------------------
template<int MODE>
__global__ __launch_bounds__(256) void gemm_bf16(
    const u16* __restrict__ A, const u16* __restrict__ W,
    const float* __restrict__ bias, const float* __restrict__ res,
    void* __restrict__ Cout, int M, int N, int K, long long strideA)
{
    __shared__ u16 As[128 * 32];
    __shared__ u16 Bs[128 * 32];
    const int tid  = threadIdx.x;
    const int wave = tid >> 6, lane = tid & 63;
    const int lo = lane & 15, hi = lane >> 4;
    const int wr = wave >> 1, wc = wave & 1;

    const int m0 = blockIdx.y * 128, n0 = blockIdx.x * 128;
    if (MODE == 3) { A += blockIdx.z * strideA; W += blockIdx.z * strideA; }

    const int Klen = (MODE == 5) ? (K >> 1) : K;
    const int kb   = (MODE == 5) ? blockIdx.z * Klen : 0;

    const int limA = M - 1;
    const int limB = (MODE == 3 ? M : N) - 1;
    // XOR-swizzled source staging (row-contiguous per 4 lanes):
    //   row = lane>>2, chunk = (lane&3) ^ s(row), s(row) = (row>>1)&3 = (lane>>3)&3
    const int srow = lane >> 2;
    const int scol = ((lane & 3) ^ ((lane >> 3) & 3)) << 3;
    int ra0 = m0 + wave * 16 + srow;      if (ra0 > limA) ra0 = limA;
    int ra1 = m0 + 64 + wave * 16 + srow; if (ra1 > limA) ra1 = limA;
    int rb0 = n0 + wave * 16 + srow;      if (rb0 > limB) rb0 = limB;
    int rb1 = n0 + 64 + wave * 16 + srow; if (rb1 > limB) rb1 = limB;
    const u16* Arow0 = A + (size_t)ra0 * K + kb + scol;
    const u16* Arow1 = A + (size_t)ra1 * K + kb + scol;
    const u16* Brow0 = W + (size_t)rb0 * K + kb + scol;
    const u16* Brow1 = W + (size_t)rb1 * K + kb + scol;

    u16* ldsA0 = &As[wave * 512];
    u16* ldsA1 = &As[2048 + wave * 512];
    u16* ldsB0 = &Bs[wave * 512];
    u16* ldsB1 = &Bs[2048 + wave * 512];

    // XOR'd fragment read offset within a 16x32-elem unit (row lo, chunk hi)
    const int fro = lo * 32 + ((hi ^ ((lo >> 1) & 3)) << 3);

    f32x4 acc[4][4] = {};

    for (int k0 = 0; k0 < Klen; k0 += 32) {
        gload_lds16(Arow0 + k0, ldsA0);
        gload_lds16(Arow1 + k0, ldsA1);
        gload_lds16(Brow0 + k0, ldsB0);
        gload_lds16(Brow1 + k0, ldsB1);
        __syncthreads();
        bf16x8 af[4], bfr[4];
        #pragma unroll
        for (int i = 0; i < 4; ++i)
            af[i] = *reinterpret_cast<const bf16x8*>(&As[(wr * 4 + i) * 512 + fro]);
        #pragma unroll
        for (int j = 0; j < 4; ++j)
            bfr[j] = *reinterpret_cast<const bf16x8*>(&Bs[(wc * 4 + j) * 512 + fro]);
        #pragma unroll
        for (int i = 0; i < 4; ++i)
            #pragma unroll
            for (int j = 0; j < 4; ++j)
                acc[i][j] = __builtin_amdgcn_mfma_f32_16x16x32_bf16(af[i], bfr[j], acc[i][j], 0, 0, 0);
        __syncthreads();
    }

    const size_t zoff = (MODE == 5) ? (size_t)blockIdx.z * M * N : 0;
    const int cr = hi * 4;
    const int cc = lo;
    #pragma unroll
    for (int i = 0; i < 4; ++i) {
        #pragma unroll
        for (int r = 0; r < 4; ++r) {
            int m = m0 + wr * 64 + i * 16 + cr + r;
            if (MODE != 3 && m >= M) continue;
            #pragma unroll
            for (int j = 0; j < 4; ++j) {
                int n = n0 + wc * 64 + j * 16 + cc;
                float v = acc[i][j][r];
                if (MODE == 0) {
                    ((float*)Cout)[(size_t)m * N + n] = v + bias[n];
                } else if (MODE == 1) {
                    float t = v + bias[n];
                    t = 0.5f * t * (1.f + erff(t * 0.70710678118654752f));
                    ((u16*)Cout)[(size_t)m * N + n] = f2bf(t);
                } else if (MODE == 2) {
                    ((float*)Cout)[(size_t)m * N + n] = v + bias[n] + res[(size_t)m * N + n];
                } else if (MODE == 4) {
                    ((u16*)Cout)[(size_t)m * N + n] = f2bf(v + bias[n]);
                } else if (MODE == 5) {
                    ((float*)Cout)[zoff + (size_t)m * N + n] = v;
                } else { // MODE 3
                    if (m < M && n < M) {
                        float* C3 = (float*)Cout + (size_t)blockIdx.z * LL * LL;
                        C3[(size_t)(m + 1) * LL + (n + 1)] = v * 0.03608439182435161f;
                    }
                }
            }
        }
    }
}

// x[i] += p0[i] + p1[i] + bias[i % N]   (split-K reduce, N % 4 == 0)
__global__ void splitk_reduce_kernel(float* __restrict__ x, const float* __restrict__ p,
                                     const float* __restrict__ bias, int MN, int N)
{
    int i4 = (blockIdx.x * 256 + threadIdx.x) * 4;
    if (i4 >= MN) return;
    float4 a  = *reinterpret_cast<const float4*>(x + i4);
    float4 p0 = *reinterpret_cast<const float4*>(p + i4);
    float4 p1 = *reinterpret_cast<const float4*>(p + (size_t)MN + i4);
    float4 b  = *reinterpret_cast<const float4*>(bias + (i4 % N));
    a.x += p0.x + p1.x + b.x;
    a.y += p0.y + p1.y + b.y;
    a.z += p0.z + p1.z + b.z;
    a.w += p0.w + p1.w + b.w;
    *reinterpret_cast<float4*>(x + i4) = a;
}

__global__ void bias_edge_kernel(float* __restrict__ bias)
{
    int b = blockIdx.x, t = threadIdx.x;
    if (t < LL) {
        bias[((size_t)b * LL + 0) * LL + t] = 0.f;
        bias[((size_t)b * LL + t) * LL + 0] = 0.f;
    }
}

// ---------------------------------------------------------------------------
__global__ void combine_kernel(
    const float* __restrict__ toki, const float* __restrict__ tokm,
    const float* __restrict__ cls, const float* __restrict__ pos,
    float* __restrict__ x)
{
    size_t idx = (size_t)blockIdx.x * 256 + threadIdx.x;
    if (idx >= (size_t)MROWS * DD) return;
    int d = (int)(idx % DD);
    size_t bl = idx / DD;
    int l = (int)(bl % LL);
    int b = (int)(bl / LL);
    float v;
    if (l == 0) v = cls[d];
    else {
        size_t tix = ((size_t)b * NTOK + (l - 1)) * DD + d;
        v = toki[tix] + 0.5f * tokm[tix];
    }
    x[idx] = v + pos[(size_t)l * DD + d];
}

// ---------------------------------------------------------------------------
// LayerNorm: one wave per row, shfl-only. 4 rows/block.
// ---------------------------------------------------------------------------
template<int OUT>
__global__ __launch_bounds__(256) void ln_kernel(
    const float* __restrict__ in, const float* __restrict__ g,
    const float* __restrict__ beta, float* __restrict__ outf,
    u16* __restrict__ outb, int nrows)
{
    int row = blockIdx.x * 4 + (threadIdx.x >> 6);
    if (row >= nrows) return;
    int lane = threadIdx.x & 63;
    const float* xr = in + (size_t)row * DD;
    float4 v[3];
    #pragma unroll
    for (int p = 0; p < 3; ++p)
        v[p] = *reinterpret_cast<const float4*>(xr + p * 256 + lane * 4);
    float s = 0.f;
    #pragma unroll
    for (int p = 0; p < 3; ++p) s += v[p].x + v[p].y + v[p].z + v[p].w;
    #pragma unroll
    for (int off = 32; off; off >>= 1) s += __shfl_xor(s, off);
    float mean = s * (1.f / 768.f);
    float q = 0.f;
    #pragma unroll
    for (int p = 0; p < 3; ++p) {
        float a = v[p].x - mean, b = v[p].y - mean, c = v[p].z - mean, d = v[p].w - mean;
        q += a * a + b * b + c * c + d * d;
    }
    #pragma unroll
    for (int off = 32; off; off >>= 1) q += __shfl_xor(q, off);
    float rstd = rsqrtf(q * (1.f / 768.f) + 1e-5f);
    #pragma unroll
    for (int p = 0; p < 3; ++p) {
        int d0 = p * 256 + lane * 4;
        float4 gg = *reinterpret_cast<const float4*>(g + d0);
        float4 bb = *reinterpret_cast<const float4*>(beta + d0);
        float o0 = gg.x * (v[p].x - mean) * rstd + bb.x;
        float o1 = gg.y * (v[p].y - mean) * rstd + bb.y;
        float o2 = gg.z * (v[p].z - mean) * rstd + bb.z;
        float o3 = gg.w * (v[p].w - mean) * rstd + bb.w;
        if (OUT == 0 || OUT == 2) {
            float4 of = make_float4(o0, o1, o2, o3);
            *reinterpret_cast<float4*>(outf + (size_t)row * DD + d0) = of;
        }
        if (OUT == 1 || OUT == 2) {
            u16x4 ob = { f2bf(o0), f2bf(o1), f2bf(o2), f2bf(o3) };
            *reinterpret_cast<u16x4*>(outb + (size_t)row * DD + d0) = ob;
        }
    }
}

// ---------------------------------------------------------------------------
// MFMA attention (unchanged, passing since r3)
// ---------------------------------------------------------------------------
constexpr int KSTRE = 72;
constexpr int VSTRE = 232;
constexpr int PSTRE = 232;

__global__ __launch_bounds__(256) void attn_mfma_kernel(
    const u16* __restrict__ qkv, const float* __restrict__ bias,
    u16* __restrict__ o)
{
    const int h = blockIdx.x, b = blockIdx.y;
    const int tid = threadIdx.x, wave = tid >> 6, lane = tid & 63;
    const int lo = lane & 15, hi = lane >> 4;

    __shared__ u16 Ks[208 * KSTRE];
    __shared__ u16 Vt[64 * VSTRE];
    __shared__ u16 Ps[4][16 * PSTRE];

    const u16* qb = qkv + (size_t)b * LL * 2304;

    for (int idx = tid; idx < 208 * 8; idx += 256) {
        int key = idx >> 3, c8 = idx & 7;
        u16x8 v = {};
        if (key < LL) v = *reinterpret_cast<const u16x8*>(qb + (size_t)key * 2304 + 768 + h * 64 + c8 * 8);
        *reinterpret_cast<u16x8*>(&Ks[key * KSTRE + c8 * 8]) = v;
    }
    for (int idx = tid; idx < 224 * 8; idx += 256) {
        int key = idx >> 3, c8 = idx & 7;
        u16x8 v = {};
        if (key < LL) v = *reinterpret_cast<const u16x8*>(qb + (size_t)key * 2304 + 1536 + h * 64 + c8 * 8);
        #pragma unroll
        for (int e = 0; e < 8; ++e) Vt[(c8 * 8 + e) * VSTRE + key] = v[e];
    }
    __syncthreads();

    u16* P = Ps[wave];
    const float* biasbb = bias + (size_t)b * LL * LL;

    for (int rt = wave; rt < 13; rt += 4) {
        int q = rt * 16 + lo; if (q > LL - 1) q = LL - 1;
        const u16* qrow = qb + (size_t)q * 2304 + h * 64;
        bf16x8 qa0 = *reinterpret_cast<const bf16x8*>(qrow + hi * 8);
        bf16x8 qa1 = *reinterpret_cast<const bf16x8*>(qrow + 32 + hi * 8);

        f32x4 st[13];
        #pragma unroll
        for (int t = 0; t < 13; ++t) {
            int keyc = t * 16 + lo;
            bf16x8 kb0 = *reinterpret_cast<const bf16x8*>(&Ks[keyc * KSTRE + hi * 8]);
            bf16x8 kb1 = *reinterpret_cast<const bf16x8*>(&Ks[keyc * KSTRE + 32 + hi * 8]);
            f32x4 a = {};
            a = __builtin_amdgcn_mfma_f32_16x16x32_bf16(qa0, kb0, a, 0, 0, 0);
            a = __builtin_amdgcn_mfma_f32_16x16x32_bf16(qa1, kb1, a, 0, 0, 0);
            st[t] = a;
        }

        #pragma unroll
        for (int r = 0; r < 4; ++r) {
            int qq = rt * 16 + hi * 4 + r;
            int qc = qq > LL - 1 ? LL - 1 : qq;
            const float* brow = biasbb + (size_t)qc * LL;
            float s[13];
            float m = -1e30f;
            #pragma unroll
            for (int t = 0; t < 13; ++t) {
                int col = t * 16 + lo;
                float v;
                if (col < LL) v = st[t][r] * 0.125f + brow[col];
                else          v = -1e30f;
                s[t] = v;
                m = fmaxf(m, v);
            }
            m = fmaxf(m, __shfl_xor(m, 1));
            m = fmaxf(m, __shfl_xor(m, 2));
            m = fmaxf(m, __shfl_xor(m, 4));
            m = fmaxf(m, __shfl_xor(m, 8));
            float sum = 0.f;
            #pragma unroll
            for (int t = 0; t < 13; ++t) { float e = __expf(s[t] - m); s[t] = e; sum += e; }
            sum += __shfl_xor(sum, 1);
            sum += __shfl_xor(sum, 2);
            sum += __shfl_xor(sum, 4);
            sum += __shfl_xor(sum, 8);
            float inv = 1.f / sum;
            int prow = (hi * 4 + r) * PSTRE;
            #pragma unroll
            for (int t = 0; t < 13; ++t) P[prow + t * 16 + lo] = f2bf(s[t] * inv);
            P[prow + 208 + lo] = 0;
        }

        f32x4 oacc[4] = {};
        #pragma unroll
        for (int kt = 0; kt < 7; ++kt) {
            bf16x8 pa = *reinterpret_cast<const bf16x8*>(&P[lo * PSTRE + kt * 32 + hi * 8]);
            #pragma unroll
            for (int dt = 0; dt < 4; ++dt) {
                bf16x8 vb = *reinterpret_cast<const bf16x8*>(&Vt[(dt * 16 + lo) * VSTRE + kt * 32 + hi * 8]);
                oacc[dt] = __builtin_amdgcn_mfma_f32_16x16x32_bf16(pa, vb, oacc[dt], 0, 0, 0);
            }
        }

        #pragma unroll
        for (int dt = 0; dt < 4; ++dt) {
            #pragma unroll
            for (int r = 0; r < 4; ++r) {
                int qq = rt * 16 + hi * 4 + r;
                if (qq < LL)
                    o[((size_t)(b * LL + qq)) * DD + h * 64 + dt * 16 + lo] = f2bf(oacc[dt][r]);
            }
        }
    }
}

// ---------------------------------------------------------------------------
__global__ __launch_bounds__(256) void final_kernel(
    const float* __restrict__ x,
    const float* __restrict__ eg, const float* __restrict__ eb,
    const float* __restrict__ fg, const float* __restrict__ fb,
    const float* __restrict__ hw, const float* __restrict__ hb,
    float* __restrict__ out)
{
    int b = blockIdx.x;
    int tid = threadIdx.x;
    __shared__ float xs[768];
    __shared__ float red[256];
    const float* xr = x + (size_t)b * LL * DD;
    #pragma unroll
    for (int r = 0; r < 3; ++r) xs[tid + r * 256] = xr[tid + r * 256];
    __syncthreads();
    for (int pass = 0; pass < 2; ++pass) {
        const float* g  = pass ? fg : eg;
        const float* bb = pass ? fb : eb;
        red[tid] = xs[tid] + xs[tid + 256] + xs[tid + 512];
        __syncthreads();
        for (int off = 128; off; off >>= 1) {
            if (tid < off) red[tid] += red[tid + off];
            __syncthreads();
        }
        float mean = red[0] * (1.f / 768.f);
        __syncthreads();
        float q = 0.f;
        #pragma unroll
        for (int r = 0; r < 3; ++r) { float dv = xs[tid + r * 256] - mean; q += dv * dv; }
        red[tid] = q;
        __syncthreads();
        for (int off = 128; off; off >>= 1) {
            if (tid < off) red[tid] += red[tid + off];
            __syncthreads();
        }
        float rstd = rsqrtf(red[0] * (1.f / 768.f) + 1e-5f);
        __syncthreads();
        #pragma unroll
        for (int r = 0; r < 3; ++r) {
            int d = tid + r * 256;
            xs[d] = g[d] * (xs[d] - mean) * rstd + bb[d];
        }
        __syncthreads();
    }
    int c = tid >> 6, lane = tid & 63;
    float part = 0.f;
    for (int d = lane; d < 768; d += 64) part += xs[d] * hw[c * 768 + d];
    #pragma unroll
    for (int off = 32; off; off >>= 1) part += __shfl_down(part, off);
    if (lane == 0) out[b * 4 + c] = part + hb[c];
}

// ---------------------------------------------------------------------------
extern "C" void kernel_launch(void* const* d_in, const int* in_sizes, int n_in,
                              void* d_out, int out_size, void* d_ws, size_t ws_size,
                              hipStream_t stream)
{
    const float* img    = (const float*)d_in[0];
    const float* mask   = (const float*)d_in[1];
    const float* pe_iw  = (const float*)d_in[2];
    const float* pe_ib  = (const float*)d_in[3];
    const float* pe_ig  = (const float*)d_in[4];
    const float* pe_ibb = (const float*)d_in[5];
    const float* pe_mw  = (const float*)d_in[6];
    const float* pe_mb  = (const float*)d_in[7];
    const float* pe_mg  = (const float*)d_in[8];
    const float* pe_mbb = (const float*)d_in[9];
    const float* cls    = (const float*)d_in[10];
    const float* pos    = (const float*)d_in[11];
    const float* ln1_g  = (const float*)d_in[12];
    const float* ln1_b  = (const float*)d_in[13];
    const float* w_qkv  = (const float*)d_in[14];
    const float* b_qkv  = (const float*)d_in[15];
    const float* w_out  = (const float*)d_in[16];
    const float* b_out  = (const float*)d_in[17];
    const float* ln2_g  = (const float*)d_in[18];
    const float* ln2_b  = (const float*)d_in[19];
    const float* w_fc1  = (const float*)d_in[20];
    const float* b_fc1  = (const float*)d_in[21];
    const float* w_fc2  = (const float*)d_in[22];
    const float* b_fc2  = (const float*)d_in[23];
    const float* enc_g  = (const float*)d_in[24];
    const float* enc_b  = (const float*)d_in[25];
    const float* fin_g  = (const float*)d_in[26];
    const float* fin_b  = (const float*)d_in[27];
    const float* head_w = (const float*)d_in[28];
    const float* head_b = (const float*)d_in[29];

    char* wsb = (char*)d_ws;
    size_t off = 0;
    auto alloc = [&](size_t bytes) { void* p = wsb + off; off += (bytes + 255) & ~(size_t)255; return p; };

    float* x     = (float*)alloc((size_t)MROWS * DD * 4);
    u16*   qkvb  = (u16*)  alloc((size_t)MROWS * 3 * DD * 2);
    u16*   hbuf  = (u16*)  alloc((size_t)MROWS * DD * 2);
    u16*   fc1b  = (u16*)  alloc((size_t)MROWS * 4 * DD * 2);
    float* biasb = (float*)alloc((size_t)BB * LL * LL * 4);
    u16*   wqb   = (u16*)  alloc((size_t)3 * DD * DD * 2);
    u16*   wob   = (u16*)  alloc((size_t)DD * DD * 2);
    u16*   w1b   = (u16*)  alloc((size_t)4 * DD * DD * 2);
    u16*   w2b   = (u16*)  alloc((size_t)4 * DD * DD * 2);
    float* toki  = (float*)alloc((size_t)MTOK * DD * 4);
    float* tokm  = (float*)alloc((size_t)MTOK * DD * 4);
    u16*   pa    = fc1b;            // patches alias
    float* ttmp  = (float*)qkvb;    // pe-GEMM f32 out alias
    u16*   tokmb = hbuf;            // bf16 tok_m alias
    float* partf = (float*)qkvb;    // split-K partials: 2 x MROWS*DD f32 over qkvb+hbuf
                                    // (= 38,731,776 B exactly; qkvb dead after attn,
                                    //  hbuf dead after fc1 at fc2 time)

    // ---- patch embed (img) ----
    cast_kernel<<<(DD * DD / 4 + 255) / 256, 256, 0, stream>>>(pe_iw, wob, DD * DD);
    patchify_kernel<<<(MTOK * DD + 255) / 256, 256, 0, stream>>>(img, 3, pa, MTOK * DD);
    gemm_bf16<0><<<dim3(DD / 128, MTOK / 128), 256, 0, stream>>>(
        pa, wob, pe_ib, nullptr, ttmp, MTOK, DD, DD, 0);
    ln_kernel<0><<<MTOK / 4, 256, 0, stream>>>(ttmp, pe_ig, pe_ibb, toki, nullptr, MTOK);

    // ---- patch embed (mask) ----
    cast_kernel<<<(DD * 256 / 4 + 255) / 256, 256, 0, stream>>>(pe_mw, wob, DD * 256);
    patchify_kernel<<<(MTOK * 256 + 255) / 256, 256, 0, stream>>>(mask, 1, pa, MTOK * 256);
    gemm_bf16<0><<<dim3(DD / 128, MTOK / 128), 256, 0, stream>>>(
        pa, wob, pe_mb, nullptr, ttmp, MTOK, DD, 256, 0);
    ln_kernel<2><<<MTOK / 4, 256, 0, stream>>>(ttmp, pe_mg, pe_mbb, tokm, tokmb, MTOK);

    // ---- attention bias ----
    gemm_bf16<3><<<dim3(2, 2, BB), 256, 0, stream>>>(
        tokmb, tokmb, nullptr, nullptr, biasb, NTOK, NTOK, DD, (long long)NTOK * DD);
    bias_edge_kernel<<<BB, 256, 0, stream>>>(biasb);

    // ---- combine ----
    combine_kernel<<<(MROWS * DD + 255) / 256, 256, 0, stream>>>(toki, tokm, cls, pos, x);

    const int mblk = (MROWS + 127) / 128;   // 50
    const int MN = MROWS * DD;
    const int wqn = 3 * DD * DD, won = DD * DD, w1n = 4 * DD * DD, w2n = 4 * DD * DD;
    const int castTot = (wqn + won + w1n + w2n) / 4;
    for (int l = 0; l < 12; ++l) {
        cast4_kernel<<<(castTot + 255) / 256, 256, 0, stream>>>(
            w_qkv + (size_t)l * wqn, wqn, w_out + (size_t)l * won, won,
            w_fc1 + (size_t)l * w1n, w1n, w_fc2 + (size_t)l * w2n, w2n,
            wqb, wob, w1b, w2b);
        ln_kernel<1><<<MROWS / 4, 256, 0, stream>>>(x, ln1_g + l * DD, ln1_b + l * DD, nullptr, hbuf, MROWS);
        gemm_bf16<4><<<dim3(3 * DD / 128, mblk), 256, 0, stream>>>(
            hbuf, wqb, b_qkv + l * 3 * DD, nullptr, qkvb, MROWS, 3 * DD, DD, 0);
        attn_mfma_kernel<<<dim3(HH, BB), 256, 0, stream>>>(qkvb, biasb, hbuf);
        gemm_bf16<2><<<dim3(DD / 128, mblk), 256, 0, stream>>>(
            hbuf, wob, b_out + l * DD, x, x, MROWS, DD, DD, 0);
        ln_kernel<1><<<MROWS / 4, 256, 0, stream>>>(x, ln2_g + l * DD, ln2_b + l * DD, nullptr, hbuf, MROWS);
        gemm_bf16<1><<<dim3(4 * DD / 128, mblk), 256, 0, stream>>>(
            hbuf, w1b, b_fc1 + l * 4 * DD, nullptr, fc1b, MROWS, 4 * DD, DD, 0);
        // fc2 split-K=2: partials into qkvb+hbuf region (both dead here)
        gemm_bf16<5><<<dim3(DD / 128, mblk, 2), 256, 0, stream>>>(
            fc1b, w2b, nullptr, nullptr, partf, MROWS, DD, 4 * DD, 0);
        splitk_reduce_kernel<<<(MN / 4 + 255) / 256, 256, 0, stream>>>(
            x, partf, b_fc2 + l * DD, MN, DD);
    }
    final_kernel<<<BB, 256, 0, stream>>>(x, enc_g, enc_b, fin_g, fin_b, head_w, head_b, (float*)d_out);
}

// Round 12
// 3441.133 us; speedup vs baseline: 1.5050x; 1.0771x over previous
//
#include <hip/hip_runtime.h>
#include <hip/hip_bf16.h>
#include <math.h>

typedef unsigned int   u32;
typedef unsigned short u16;
typedef __bf16 bf16x8 __attribute__((ext_vector_type(8)));
typedef float  f32x4  __attribute__((ext_vector_type(4)));
typedef u16    u16x8  __attribute__((ext_vector_type(8)));
typedef u16    u16x4  __attribute__((ext_vector_type(4)));

constexpr int BB = 32, DD = 768, LL = 197, HH = 12, NTOK = 196;
constexpr int MROWS = BB * LL;        // 6304
constexpr int MTOK  = BB * NTOK;      // 6272

__device__ __forceinline__ u16 f2bf(float f) {
    union { float f; u32 u; } v; v.f = f;
    u32 r = v.u + 0x7fff + ((v.u >> 16) & 1);
    return (u16)(r >> 16);
}
__device__ __forceinline__ float bf2f(u16 u) {
    union { u32 u; float f; } v; v.u = ((u32)u) << 16;
    return v.f;
}

#define AS1 __attribute__((address_space(1)))
#define AS3 __attribute__((address_space(3)))
__device__ __forceinline__ void gload_lds16(const void* g, void* l) {
    __builtin_amdgcn_global_load_lds((const AS1 u32*)g, (AS3 u32*)l, 16, 0, 0);
}

// ---------------------------------------------------------------------------
__global__ void cast_kernel(const float* __restrict__ in, u16* __restrict__ out, int n)
{
    int i4 = (blockIdx.x * 256 + threadIdx.x) * 4;
    if (i4 >= n) return;
    float4 v = *reinterpret_cast<const float4*>(in + i4);
    out[i4]   = f2bf(v.x); out[i4+1] = f2bf(v.y);
    out[i4+2] = f2bf(v.z); out[i4+3] = f2bf(v.w);
}

__global__ void cast4_kernel(const float* s0, int n0, const float* s1, int n1,
                             const float* s2, int n2, const float* s3, int n3,
                             u16* d0, u16* d1, u16* d2, u16* d3)
{
    int i4 = (blockIdx.x * 256 + threadIdx.x) * 4;
    const float* s; u16* d; int off;
    if      (i4 < n0)            { s = s0; d = d0; off = i4; }
    else if (i4 < n0+n1)         { s = s1; d = d1; off = i4 - n0; }
    else if (i4 < n0+n1+n2)      { s = s2; d = d2; off = i4 - n0 - n1; }
    else if (i4 < n0+n1+n2+n3)   { s = s3; d = d3; off = i4 - n0 - n1 - n2; }
    else return;
    float4 v = *reinterpret_cast<const float4*>(s + off);
    d[off]   = f2bf(v.x); d[off+1] = f2bf(v.y);
    d[off+2] = f2bf(v.z); d[off+3] = f2bf(v.w);
}

// ---------------------------------------------------------------------------
__global__ void patchify_kernel(const float* __restrict__ src, int C,
                                u16* __restrict__ out, int total)
{
    int idx = blockIdx.x * 256 + threadIdx.x;
    if (idx >= total) return;
    int K = C * 256;
    int row = idx / K, k = idx % K;
    int b = row / NTOK, n = row % NTOK;
    int c = k >> 8, rem = k & 255, pi = rem >> 4, pj = rem & 15;
    int i14 = n / 14, j14 = n % 14;
    float v = src[(((size_t)b * C + c) * 224 + i14 * 16 + pi) * 224 + j14 * 16 + pj];
    out[idx] = f2bf(v);
}

// ---------------------------------------------------------------------------
// bf16 MFMA GEMM — unchanged from r11 (conflict-free XOR swizzle verified:
// SQ_LDS_BANK_CONFLICT 3.69M -> 0, FETCH identical).
// MODE 0: f32 +bias   MODE 1: GELU->bf16 +bias   MODE 2: f32 +bias+res
// MODE 3: batched bias-GEMM   MODE 4: bf16 +bias
// MODE 5: split-K=2, raw f32 partial store to Cout + z*M*N (no bias)
// ---------------------------------------------------------------------------
template<int MODE>
__global__ __launch_bounds__(256) void gemm_bf16(
    const u16* __restrict__ A, const u16* __restrict__ W,
    const float* __restrict__ bias, const float* __restrict__ res,
    void* __restrict__ Cout, int M, int N, int K, long long strideA)
{
    __shared__ u16 As[128 * 32];
    __shared__ u16 Bs[128 * 32];
    const int tid  = threadIdx.x;
    const int wave = tid >> 6, lane = tid & 63;
    const int lo = lane & 15, hi = lane >> 4;
    const int wr = wave >> 1, wc = wave & 1;

    const int m0 = blockIdx.y * 128, n0 = blockIdx.x * 128;
    if (MODE == 3) { A += blockIdx.z * strideA; W += blockIdx.z * strideA; }

    const int Klen = (MODE == 5) ? (K >> 1) : K;
    const int kb   = (MODE == 5) ? blockIdx.z * Klen : 0;

    const int limA = M - 1;
    const int limB = (MODE == 3 ? M : N) - 1;
    const int srow = lane >> 2;
    const int scol = ((lane & 3) ^ ((lane >> 3) & 3)) << 3;
    int ra0 = m0 + wave * 16 + srow;      if (ra0 > limA) ra0 = limA;
    int ra1 = m0 + 64 + wave * 16 + srow; if (ra1 > limA) ra1 = limA;
    int rb0 = n0 + wave * 16 + srow;      if (rb0 > limB) rb0 = limB;
    int rb1 = n0 + 64 + wave * 16 + srow; if (rb1 > limB) rb1 = limB;
    const u16* Arow0 = A + (size_t)ra0 * K + kb + scol;
    const u16* Arow1 = A + (size_t)ra1 * K + kb + scol;
    const u16* Brow0 = W + (size_t)rb0 * K + kb + scol;
    const u16* Brow1 = W + (size_t)rb1 * K + kb + scol;

    u16* ldsA0 = &As[wave * 512];
    u16* ldsA1 = &As[2048 + wave * 512];
    u16* ldsB0 = &Bs[wave * 512];
    u16* ldsB1 = &Bs[2048 + wave * 512];

    const int fro = lo * 32 + ((hi ^ ((lo >> 1) & 3)) << 3);

    f32x4 acc[4][4] = {};

    for (int k0 = 0; k0 < Klen; k0 += 32) {
        gload_lds16(Arow0 + k0, ldsA0);
        gload_lds16(Arow1 + k0, ldsA1);
        gload_lds16(Brow0 + k0, ldsB0);
        gload_lds16(Brow1 + k0, ldsB1);
        __syncthreads();
        bf16x8 af[4], bfr[4];
        #pragma unroll
        for (int i = 0; i < 4; ++i)
            af[i] = *reinterpret_cast<const bf16x8*>(&As[(wr * 4 + i) * 512 + fro]);
        #pragma unroll
        for (int j = 0; j < 4; ++j)
            bfr[j] = *reinterpret_cast<const bf16x8*>(&Bs[(wc * 4 + j) * 512 + fro]);
        #pragma unroll
        for (int i = 0; i < 4; ++i)
            #pragma unroll
            for (int j = 0; j < 4; ++j)
                acc[i][j] = __builtin_amdgcn_mfma_f32_16x16x32_bf16(af[i], bfr[j], acc[i][j], 0, 0, 0);
        __syncthreads();
    }

    const size_t zoff = (MODE == 5) ? (size_t)blockIdx.z * M * N : 0;
    const int cr = hi * 4;
    const int cc = lo;
    #pragma unroll
    for (int i = 0; i < 4; ++i) {
        #pragma unroll
        for (int r = 0; r < 4; ++r) {
            int m = m0 + wr * 64 + i * 16 + cr + r;
            if (MODE != 3 && m >= M) continue;
            #pragma unroll
            for (int j = 0; j < 4; ++j) {
                int n = n0 + wc * 64 + j * 16 + cc;
                float v = acc[i][j][r];
                if (MODE == 0) {
                    ((float*)Cout)[(size_t)m * N + n] = v + bias[n];
                } else if (MODE == 1) {
                    float t = v + bias[n];
                    t = 0.5f * t * (1.f + erff(t * 0.70710678118654752f));
                    ((u16*)Cout)[(size_t)m * N + n] = f2bf(t);
                } else if (MODE == 2) {
                    ((float*)Cout)[(size_t)m * N + n] = v + bias[n] + res[(size_t)m * N + n];
                } else if (MODE == 4) {
                    ((u16*)Cout)[(size_t)m * N + n] = f2bf(v + bias[n]);
                } else if (MODE == 5) {
                    ((float*)Cout)[zoff + (size_t)m * N + n] = v;
                } else { // MODE 3
                    if (m < M && n < M) {
                        float* C3 = (float*)Cout + (size_t)blockIdx.z * LL * LL;
                        C3[(size_t)(m + 1) * LL + (n + 1)] = v * 0.03608439182435161f;
                    }
                }
            }
        }
    }
}

// x[i] += p0[i] + p1[i] + bias[i % N]   (split-K reduce, N % 4 == 0)
__global__ void splitk_reduce_kernel(float* __restrict__ x, const float* __restrict__ p,
                                     const float* __restrict__ bias, int MN, int N)
{
    int i4 = (blockIdx.x * 256 + threadIdx.x) * 4;
    if (i4 >= MN) return;
    float4 a  = *reinterpret_cast<const float4*>(x + i4);
    float4 p0 = *reinterpret_cast<const float4*>(p + i4);
    float4 p1 = *reinterpret_cast<const float4*>(p + (size_t)MN + i4);
    float4 b  = *reinterpret_cast<const float4*>(bias + (i4 % N));
    a.x += p0.x + p1.x + b.x;
    a.y += p0.y + p1.y + b.y;
    a.z += p0.z + p1.z + b.z;
    a.w += p0.w + p1.w + b.w;
    *reinterpret_cast<float4*>(x + i4) = a;
}

__global__ void bias_edge_kernel(float* __restrict__ bias)
{
    int b = blockIdx.x, t = threadIdx.x;
    if (t < LL) {
        bias[((size_t)b * LL + 0) * LL + t] = 0.f;
        bias[((size_t)b * LL + t) * LL + 0] = 0.f;
    }
}

// ---------------------------------------------------------------------------
__global__ void combine_kernel(
    const float* __restrict__ toki, const float* __restrict__ tokm,
    const float* __restrict__ cls, const float* __restrict__ pos,
    float* __restrict__ x)
{
    size_t idx = (size_t)blockIdx.x * 256 + threadIdx.x;
    if (idx >= (size_t)MROWS * DD) return;
    int d = (int)(idx % DD);
    size_t bl = idx / DD;
    int l = (int)(bl % LL);
    int b = (int)(bl / LL);
    float v;
    if (l == 0) v = cls[d];
    else {
        size_t tix = ((size_t)b * NTOK + (l - 1)) * DD + d;
        v = toki[tix] + 0.5f * tokm[tix];
    }
    x[idx] = v + pos[(size_t)l * DD + d];
}

// ---------------------------------------------------------------------------
// LayerNorm: one wave per row, shfl-only. 4 rows/block.
// ---------------------------------------------------------------------------
template<int OUT>
__global__ __launch_bounds__(256) void ln_kernel(
    const float* __restrict__ in, const float* __restrict__ g,
    const float* __restrict__ beta, float* __restrict__ outf,
    u16* __restrict__ outb, int nrows)
{
    int row = blockIdx.x * 4 + (threadIdx.x >> 6);
    if (row >= nrows) return;
    int lane = threadIdx.x & 63;
    const float* xr = in + (size_t)row * DD;
    float4 v[3];
    #pragma unroll
    for (int p = 0; p < 3; ++p)
        v[p] = *reinterpret_cast<const float4*>(xr + p * 256 + lane * 4);
    float s = 0.f;
    #pragma unroll
    for (int p = 0; p < 3; ++p) s += v[p].x + v[p].y + v[p].z + v[p].w;
    #pragma unroll
    for (int off = 32; off; off >>= 1) s += __shfl_xor(s, off);
    float mean = s * (1.f / 768.f);
    float q = 0.f;
    #pragma unroll
    for (int p = 0; p < 3; ++p) {
        float a = v[p].x - mean, b = v[p].y - mean, c = v[p].z - mean, d = v[p].w - mean;
        q += a * a + b * b + c * c + d * d;
    }
    #pragma unroll
    for (int off = 32; off; off >>= 1) q += __shfl_xor(q, off);
    float rstd = rsqrtf(q * (1.f / 768.f) + 1e-5f);
    #pragma unroll
    for (int p = 0; p < 3; ++p) {
        int d0 = p * 256 + lane * 4;
        float4 gg = *reinterpret_cast<const float4*>(g + d0);
        float4 bb = *reinterpret_cast<const float4*>(beta + d0);
        float o0 = gg.x * (v[p].x - mean) * rstd + bb.x;
        float o1 = gg.y * (v[p].y - mean) * rstd + bb.y;
        float o2 = gg.z * (v[p].z - mean) * rstd + bb.z;
        float o3 = gg.w * (v[p].w - mean) * rstd + bb.w;
        if (OUT == 0 || OUT == 2) {
            float4 of = make_float4(o0, o1, o2, o3);
            *reinterpret_cast<float4*>(outf + (size_t)row * DD + d0) = of;
        }
        if (OUT == 1 || OUT == 2) {
            u16x4 ob = { f2bf(o0), f2bf(o1), f2bf(o2), f2bf(o3) };
            *reinterpret_cast<u16x4*>(outb + (size_t)row * DD + d0) = ob;
        }
    }
}

// ---------------------------------------------------------------------------
// MFMA attention — 8 WAVES (512 threads): was 4 waves = 1 wave/SIMD with
// 89KB LDS capping 1 block/CU (zero TLP; softmax VALU couldn't overlap MFMA
// across waves) and 13 row-tiles over 4 waves = 4 serial rounds.
// Now: Ps has 8 strips (LDS 119KB, still 1 block/CU but 2 waves/SIMD),
// rt += 8 -> 2 rounds. Per-wave code identical to the r3-verified version.
// ---------------------------------------------------------------------------
constexpr int KSTRE = 72;
constexpr int VSTRE = 232;
constexpr int PSTRE = 232;

__global__ __launch_bounds__(512) void attn_mfma_kernel(
    const u16* __restrict__ qkv, const float* __restrict__ bias,
    u16* __restrict__ o)
{
    const int h = blockIdx.x, b = blockIdx.y;
    const int tid = threadIdx.x, wave = tid >> 6, lane = tid & 63;
    const int lo = lane & 15, hi = lane >> 4;

    __shared__ u16 Ks[208 * KSTRE];       // 29952 B
    __shared__ u16 Vt[64 * VSTRE];        // 29696 B
    __shared__ u16 Ps[8][16 * PSTRE];     // 59392 B  (total 119040 B)

    const u16* qb = qkv + (size_t)b * LL * 2304;

    for (int idx = tid; idx < 208 * 8; idx += 512) {
        int key = idx >> 3, c8 = idx & 7;
        u16x8 v = {};
        if (key < LL) v = *reinterpret_cast<const u16x8*>(qb + (size_t)key * 2304 + 768 + h * 64 + c8 * 8);
        *reinterpret_cast<u16x8*>(&Ks[key * KSTRE + c8 * 8]) = v;
    }
    for (int idx = tid; idx < 224 * 8; idx += 512) {
        int key = idx >> 3, c8 = idx & 7;
        u16x8 v = {};
        if (key < LL) v = *reinterpret_cast<const u16x8*>(qb + (size_t)key * 2304 + 1536 + h * 64 + c8 * 8);
        #pragma unroll
        for (int e = 0; e < 8; ++e) Vt[(c8 * 8 + e) * VSTRE + key] = v[e];
    }
    __syncthreads();

    u16* P = Ps[wave];
    const float* biasbb = bias + (size_t)b * LL * LL;

    for (int rt = wave; rt < 13; rt += 8) {
        int q = rt * 16 + lo; if (q > LL - 1) q = LL - 1;
        const u16* qrow = qb + (size_t)q * 2304 + h * 64;
        bf16x8 qa0 = *reinterpret_cast<const bf16x8*>(qrow + hi * 8);
        bf16x8 qa1 = *reinterpret_cast<const bf16x8*>(qrow + 32 + hi * 8);

        f32x4 st[13];
        #pragma unroll
        for (int t = 0; t < 13; ++t) {
            int keyc = t * 16 + lo;
            bf16x8 kb0 = *reinterpret_cast<const bf16x8*>(&Ks[keyc * KSTRE + hi * 8]);
            bf16x8 kb1 = *reinterpret_cast<const bf16x8*>(&Ks[keyc * KSTRE + 32 + hi * 8]);
            f32x4 a = {};
            a = __builtin_amdgcn_mfma_f32_16x16x32_bf16(qa0, kb0, a, 0, 0, 0);
            a = __builtin_amdgcn_mfma_f32_16x16x32_bf16(qa1, kb1, a, 0, 0, 0);
            st[t] = a;
        }

        #pragma unroll
        for (int r = 0; r < 4; ++r) {
            int qq = rt * 16 + hi * 4 + r;
            int qc = qq > LL - 1 ? LL - 1 : qq;
            const float* brow = biasbb + (size_t)qc * LL;
            float s[13];
            float m = -1e30f;
            #pragma unroll
            for (int t = 0; t < 13; ++t) {
                int col = t * 16 + lo;
                float v;
                if (col < LL) v = st[t][r] * 0.125f + brow[col];
                else          v = -1e30f;
                s[t] = v;
                m = fmaxf(m, v);
            }
            m = fmaxf(m, __shfl_xor(m, 1));
            m = fmaxf(m, __shfl_xor(m, 2));
            m = fmaxf(m, __shfl_xor(m, 4));
            m = fmaxf(m, __shfl_xor(m, 8));
            float sum = 0.f;
            #pragma unroll
            for (int t = 0; t < 13; ++t) { float e = __expf(s[t] - m); s[t] = e; sum += e; }
            sum += __shfl_xor(sum, 1);
            sum += __shfl_xor(sum, 2);
            sum += __shfl_xor(sum, 4);
            sum += __shfl_xor(sum, 8);
            float inv = 1.f / sum;
            int prow = (hi * 4 + r) * PSTRE;
            #pragma unroll
            for (int t = 0; t < 13; ++t) P[prow + t * 16 + lo] = f2bf(s[t] * inv);
            P[prow + 208 + lo] = 0;
        }

        f32x4 oacc[4] = {};
        #pragma unroll
        for (int kt = 0; kt < 7; ++kt) {
            bf16x8 pa = *reinterpret_cast<const bf16x8*>(&P[lo * PSTRE + kt * 32 + hi * 8]);
            #pragma unroll
            for (int dt = 0; dt < 4; ++dt) {
                bf16x8 vb = *reinterpret_cast<const bf16x8*>(&Vt[(dt * 16 + lo) * VSTRE + kt * 32 + hi * 8]);
                oacc[dt] = __builtin_amdgcn_mfma_f32_16x16x32_bf16(pa, vb, oacc[dt], 0, 0, 0);
            }
        }

        #pragma unroll
        for (int dt = 0; dt < 4; ++dt) {
            #pragma unroll
            for (int r = 0; r < 4; ++r) {
                int qq = rt * 16 + hi * 4 + r;
                if (qq < LL)
                    o[((size_t)(b * LL + qq)) * DD + h * 64 + dt * 16 + lo] = f2bf(oacc[dt][r]);
            }
        }
    }
}

// ---------------------------------------------------------------------------
__global__ __launch_bounds__(256) void final_kernel(
    const float* __restrict__ x,
    const float* __restrict__ eg, const float* __restrict__ eb,
    const float* __restrict__ fg, const float* __restrict__ fb,
    const float* __restrict__ hw, const float* __restrict__ hb,
    float* __restrict__ out)
{
    int b = blockIdx.x;
    int tid = threadIdx.x;
    __shared__ float xs[768];
    __shared__ float red[256];
    const float* xr = x + (size_t)b * LL * DD;
    #pragma unroll
    for (int r = 0; r < 3; ++r) xs[tid + r * 256] = xr[tid + r * 256];
    __syncthreads();
    for (int pass = 0; pass < 2; ++pass) {
        const float* g  = pass ? fg : eg;
        const float* bb = pass ? fb : eb;
        red[tid] = xs[tid] + xs[tid + 256] + xs[tid + 512];
        __syncthreads();
        for (int off = 128; off; off >>= 1) {
            if (tid < off) red[tid] += red[tid + off];
            __syncthreads();
        }
        float mean = red[0] * (1.f / 768.f);
        __syncthreads();
        float q = 0.f;
        #pragma unroll
        for (int r = 0; r < 3; ++r) { float dv = xs[tid + r * 256] - mean; q += dv * dv; }
        red[tid] = q;
        __syncthreads();
        for (int off = 128; off; off >>= 1) {
            if (tid < off) red[tid] += red[tid + off];
            __syncthreads();
        }
        float rstd = rsqrtf(red[0] * (1.f / 768.f) + 1e-5f);
        __syncthreads();
        #pragma unroll
        for (int r = 0; r < 3; ++r) {
            int d = tid + r * 256;
            xs[d] = g[d] * (xs[d] - mean) * rstd + bb[d];
        }
        __syncthreads();
    }
    int c = tid >> 6, lane = tid & 63;
    float part = 0.f;
    for (int d = lane; d < 768; d += 64) part += xs[d] * hw[c * 768 + d];
    #pragma unroll
    for (int off = 32; off; off >>= 1) part += __shfl_down(part, off);
    if (lane == 0) out[b * 4 + c] = part + hb[c];
}

// ---------------------------------------------------------------------------
extern "C" void kernel_launch(void* const* d_in, const int* in_sizes, int n_in,
                              void* d_out, int out_size, void* d_ws, size_t ws_size,
                              hipStream_t stream)
{
    const float* img    = (const float*)d_in[0];
    const float* mask   = (const float*)d_in[1];
    const float* pe_iw  = (const float*)d_in[2];
    const float* pe_ib  = (const float*)d_in[3];
    const float* pe_ig  = (const float*)d_in[4];
    const float* pe_ibb = (const float*)d_in[5];
    const float* pe_mw  = (const float*)d_in[6];
    const float* pe_mb  = (const float*)d_in[7];
    const float* pe_mg  = (const float*)d_in[8];
    const float* pe_mbb = (const float*)d_in[9];
    const float* cls    = (const float*)d_in[10];
    const float* pos    = (const float*)d_in[11];
    const float* ln1_g  = (const float*)d_in[12];
    const float* ln1_b  = (const float*)d_in[13];
    const float* w_qkv  = (const float*)d_in[14];
    const float* b_qkv  = (const float*)d_in[15];
    const float* w_out  = (const float*)d_in[16];
    const float* b_out  = (const float*)d_in[17];
    const float* ln2_g  = (const float*)d_in[18];
    const float* ln2_b  = (const float*)d_in[19];
    const float* w_fc1  = (const float*)d_in[20];
    const float* b_fc1  = (const float*)d_in[21];
    const float* w_fc2  = (const float*)d_in[22];
    const float* b_fc2  = (const float*)d_in[23];
    const float* enc_g  = (const float*)d_in[24];
    const float* enc_b  = (const float*)d_in[25];
    const float* fin_g  = (const float*)d_in[26];
    const float* fin_b  = (const float*)d_in[27];
    const float* head_w = (const float*)d_in[28];
    const float* head_b = (const float*)d_in[29];

    char* wsb = (char*)d_ws;
    size_t off = 0;
    auto alloc = [&](size_t bytes) { void* p = wsb + off; off += (bytes + 255) & ~(size_t)255; return p; };

    float* x     = (float*)alloc((size_t)MROWS * DD * 4);
    u16*   qkvb  = (u16*)  alloc((size_t)MROWS * 3 * DD * 2);
    u16*   hbuf  = (u16*)  alloc((size_t)MROWS * DD * 2);
    u16*   fc1b  = (u16*)  alloc((size_t)MROWS * 4 * DD * 2);
    float* biasb = (float*)alloc((size_t)BB * LL * LL * 4);
    u16*   wqb   = (u16*)  alloc((size_t)3 * DD * DD * 2);
    u16*   wob   = (u16*)  alloc((size_t)DD * DD * 2);
    u16*   w1b   = (u16*)  alloc((size_t)4 * DD * DD * 2);
    u16*   w2b   = (u16*)  alloc((size_t)4 * DD * DD * 2);
    float* toki  = (float*)alloc((size_t)MTOK * DD * 4);
    float* tokm  = (float*)alloc((size_t)MTOK * DD * 4);
    u16*   pa    = fc1b;            // patches alias
    float* ttmp  = (float*)qkvb;    // pe-GEMM f32 out alias
    u16*   tokmb = hbuf;            // bf16 tok_m alias
    float* partf = (float*)qkvb;    // split-K partials: 2 x MROWS*DD f32 over qkvb+hbuf

    // ---- patch embed (img) ----
    cast_kernel<<<(DD * DD / 4 + 255) / 256, 256, 0, stream>>>(pe_iw, wob, DD * DD);
    patchify_kernel<<<(MTOK * DD + 255) / 256, 256, 0, stream>>>(img, 3, pa, MTOK * DD);
    gemm_bf16<0><<<dim3(DD / 128, MTOK / 128), 256, 0, stream>>>(
        pa, wob, pe_ib, nullptr, ttmp, MTOK, DD, DD, 0);
    ln_kernel<0><<<MTOK / 4, 256, 0, stream>>>(ttmp, pe_ig, pe_ibb, toki, nullptr, MTOK);

    // ---- patch embed (mask) ----
    cast_kernel<<<(DD * 256 / 4 + 255) / 256, 256, 0, stream>>>(pe_mw, wob, DD * 256);
    patchify_kernel<<<(MTOK * 256 + 255) / 256, 256, 0, stream>>>(mask, 1, pa, MTOK * 256);
    gemm_bf16<0><<<dim3(DD / 128, MTOK / 128), 256, 0, stream>>>(
        pa, wob, pe_mb, nullptr, ttmp, MTOK, DD, 256, 0);
    ln_kernel<2><<<MTOK / 4, 256, 0, stream>>>(ttmp, pe_mg, pe_mbb, tokm, tokmb, MTOK);

    // ---- attention bias ----
    gemm_bf16<3><<<dim3(2, 2, BB), 256, 0, stream>>>(
        tokmb, tokmb, nullptr, nullptr, biasb, NTOK, NTOK, DD, (long long)NTOK * DD);
    bias_edge_kernel<<<BB, 256, 0, stream>>>(biasb);

    // ---- combine ----
    combine_kernel<<<(MROWS * DD + 255) / 256, 256, 0, stream>>>(toki, tokm, cls, pos, x);

    const int mblk = (MROWS + 127) / 128;   // 50
    const int MN = MROWS * DD;
    const int wqn = 3 * DD * DD, won = DD * DD, w1n = 4 * DD * DD, w2n = 4 * DD * DD;
    const int castTot = (wqn + won + w1n + w2n) / 4;
    for (int l = 0; l < 12; ++l) {
        cast4_kernel<<<(castTot + 255) / 256, 256, 0, stream>>>(
            w_qkv + (size_t)l * wqn, wqn, w_out + (size_t)l * won, won,
            w_fc1 + (size_t)l * w1n, w1n, w_fc2 + (size_t)l * w2n, w2n,
            wqb, wob, w1b, w2b);
        ln_kernel<1><<<MROWS / 4, 256, 0, stream>>>(x, ln1_g + l * DD, ln1_b + l * DD, nullptr, hbuf, MROWS);
        gemm_bf16<4><<<dim3(3 * DD / 128, mblk), 256, 0, stream>>>(
            hbuf, wqb, b_qkv + l * 3 * DD, nullptr, qkvb, MROWS, 3 * DD, DD, 0);
        attn_mfma_kernel<<<dim3(HH, BB), 512, 0, stream>>>(qkvb, biasb, hbuf);
        gemm_bf16<2><<<dim3(DD / 128, mblk), 256, 0, stream>>>(
            hbuf, wob, b_out + l * DD, x, x, MROWS, DD, DD, 0);
        ln_kernel<1><<<MROWS / 4, 256, 0, stream>>>(x, ln2_g + l * DD, ln2_b + l * DD, nullptr, hbuf, MROWS);
        gemm_bf16<1><<<dim3(4 * DD / 128, mblk), 256, 0, stream>>>(
            hbuf, w1b, b_fc1 + l * 4 * DD, nullptr, fc1b, MROWS, 4 * DD, DD, 0);
        // fc2 split-K=2: partials into qkvb+hbuf region (both dead here)
        gemm_bf16<5><<<dim3(DD / 128, mblk, 2), 256, 0, stream>>>(
            fc1b, w2b, nullptr, nullptr, partf, MROWS, DD, 4 * DD, 0);
        splitk_reduce_kernel<<<(MN / 4 + 255) / 256, 256, 0, stream>>>(
            x, partf, b_fc2 + l * DD, MN, DD);
    }
    final_kernel<<<BB, 256, 0, stream>>>(x, enc_g, enc_b, fin_g, fin_b, head_w, head_b, (float*)d_out);
}

// Round 14
// 3247.160 us; speedup vs baseline: 1.5949x; 1.0597x over previous
//
#include <hip/hip_runtime.h>
#include <hip/hip_bf16.h>
#include <math.h>

typedef unsigned int   u32;
typedef unsigned short u16;
typedef __bf16 bf16x8 __attribute__((ext_vector_type(8)));
typedef float  f32x4  __attribute__((ext_vector_type(4)));
typedef u16    u16x8  __attribute__((ext_vector_type(8)));
typedef u16    u16x4  __attribute__((ext_vector_type(4)));

constexpr int BB = 32, DD = 768, LL = 197, HH = 12, NTOK = 196;
constexpr int MROWS = BB * LL;        // 6304
constexpr int MTOK  = BB * NTOK;      // 6272

__device__ __forceinline__ u16 f2bf(float f) {
    union { float f; u32 u; } v; v.f = f;
    u32 r = v.u + 0x7fff + ((v.u >> 16) & 1);
    return (u16)(r >> 16);
}
__device__ __forceinline__ float bf2f(u16 u) {
    union { u32 u; float f; } v; v.u = ((u32)u) << 16;
    return v.f;
}

#define AS1 __attribute__((address_space(1)))
#define AS3 __attribute__((address_space(3)))
__device__ __forceinline__ void gload_lds16(const void* g, void* l) {
    __builtin_amdgcn_global_load_lds((const AS1 u32*)g, (AS3 u32*)l, 16, 0, 0);
}

// ---------------------------------------------------------------------------
__global__ void cast_kernel(const float* __restrict__ in, u16* __restrict__ out, int n)
{
    int i4 = (blockIdx.x * 256 + threadIdx.x) * 4;
    if (i4 >= n) return;
    float4 v = *reinterpret_cast<const float4*>(in + i4);
    out[i4]   = f2bf(v.x); out[i4+1] = f2bf(v.y);
    out[i4+2] = f2bf(v.z); out[i4+3] = f2bf(v.w);
}

__global__ void cast4_kernel(const float* s0, int n0, const float* s1, int n1,
                             const float* s2, int n2, const float* s3, int n3,
                             u16* d0, u16* d1, u16* d2, u16* d3)
{
    int i4 = (blockIdx.x * 256 + threadIdx.x) * 4;
    const float* s; u16* d; int off;
    if      (i4 < n0)            { s = s0; d = d0; off = i4; }
    else if (i4 < n0+n1)         { s = s1; d = d1; off = i4 - n0; }
    else if (i4 < n0+n1+n2)      { s = s2; d = d2; off = i4 - n0 - n1; }
    else if (i4 < n0+n1+n2+n3)   { s = s3; d = d3; off = i4 - n0 - n1 - n2; }
    else return;
    float4 v = *reinterpret_cast<const float4*>(s + off);
    d[off]   = f2bf(v.x); d[off+1] = f2bf(v.y);
    d[off+2] = f2bf(v.z); d[off+3] = f2bf(v.w);
}

// ---------------------------------------------------------------------------
__global__ void patchify_kernel(const float* __restrict__ src, int C,
                                u16* __restrict__ out, int total)
{
    int idx = blockIdx.x * 256 + threadIdx.x;
    if (idx >= total) return;
    int K = C * 256;
    int row = idx / K, k = idx % K;
    int b = row / NTOK, n = row % NTOK;
    int c = k >> 8, rem = k & 255, pi = rem >> 4, pj = rem & 15;
    int i14 = n / 14, j14 = n % 14;
    float v = src[(((size_t)b * C + c) * 224 + i14 * 16 + pi) * 224 + j14 * 16 + pj];
    out[idx] = f2bf(v);
}

// ---------------------------------------------------------------------------
// bf16 MFMA GEMM — r11 verified staging (row-contiguous XOR-swizzle source,
// conflict-free reads) + single-barrier double-buffer K-loop (r13; the r13
// failure was a workspace aliasing race in reduce_ln, NOT this pipeline):
//   per step: STAGE(buf^1, t+1) ; COMPUTE(buf) ; __syncthreads()
// nt = Klen/32 is even at every call site (K = 256, 768, 1536, 3072).
// MODE 0: f32 +bias   MODE 1: GELU->bf16 +bias   MODE 2: f32 +bias+res
// MODE 3: batched bias-GEMM   MODE 4: bf16 +bias
// MODE 5: split-K=2, raw f32 partial store to Cout + z*M*N (no bias)
// ---------------------------------------------------------------------------
template<int MODE>
__global__ __launch_bounds__(256) void gemm_bf16(
    const u16* __restrict__ A, const u16* __restrict__ W,
    const float* __restrict__ bias, const float* __restrict__ res,
    void* __restrict__ Cout, int M, int N, int K, long long strideA)
{
    __shared__ u16 As[2][4096];
    __shared__ u16 Bs[2][4096];
    const int tid  = threadIdx.x;
    const int wave = tid >> 6, lane = tid & 63;
    const int lo = lane & 15, hi = lane >> 4;
    const int wr = wave >> 1, wc = wave & 1;

    const int m0 = blockIdx.y * 128, n0 = blockIdx.x * 128;
    if (MODE == 3) { A += blockIdx.z * strideA; W += blockIdx.z * strideA; }

    const int Klen = (MODE == 5) ? (K >> 1) : K;
    const int kb   = (MODE == 5) ? blockIdx.z * Klen : 0;

    const int limA = M - 1;
    const int limB = (MODE == 3 ? M : N) - 1;
    const int srow = lane >> 2;
    const int scol = ((lane & 3) ^ ((lane >> 3) & 3)) << 3;
    int ra0 = m0 + wave * 16 + srow;      if (ra0 > limA) ra0 = limA;
    int ra1 = m0 + 64 + wave * 16 + srow; if (ra1 > limA) ra1 = limA;
    int rb0 = n0 + wave * 16 + srow;      if (rb0 > limB) rb0 = limB;
    int rb1 = n0 + 64 + wave * 16 + srow; if (rb1 > limB) rb1 = limB;
    const u16* Arow0 = A + (size_t)ra0 * K + kb + scol;
    const u16* Arow1 = A + (size_t)ra1 * K + kb + scol;
    const u16* Brow0 = W + (size_t)rb0 * K + kb + scol;
    const u16* Brow1 = W + (size_t)rb1 * K + kb + scol;

    const int fro = lo * 32 + ((hi ^ ((lo >> 1) & 3)) << 3);

    f32x4 acc[4][4] = {};

    #define STAGE(bf_, k0_)                                        \
        do {                                                       \
            gload_lds16(Arow0 + (k0_), &As[bf_][wave * 512]);      \
            gload_lds16(Arow1 + (k0_), &As[bf_][2048 + wave * 512]);\
            gload_lds16(Brow0 + (k0_), &Bs[bf_][wave * 512]);      \
            gload_lds16(Brow1 + (k0_), &Bs[bf_][2048 + wave * 512]);\
        } while (0)

    #define COMPUTE(bf_)                                                         \
        do {                                                                     \
            bf16x8 af[4], bfr[4];                                                \
            _Pragma("unroll")                                                    \
            for (int i = 0; i < 4; ++i)                                          \
                af[i] = *reinterpret_cast<const bf16x8*>(                        \
                    &As[bf_][(wr * 4 + i) * 512 + fro]);                         \
            _Pragma("unroll")                                                    \
            for (int j = 0; j < 4; ++j)                                          \
                bfr[j] = *reinterpret_cast<const bf16x8*>(                       \
                    &Bs[bf_][(wc * 4 + j) * 512 + fro]);                         \
            _Pragma("unroll")                                                    \
            for (int i = 0; i < 4; ++i)                                          \
                _Pragma("unroll")                                                \
                for (int j = 0; j < 4; ++j)                                      \
                    acc[i][j] = __builtin_amdgcn_mfma_f32_16x16x32_bf16(         \
                        af[i], bfr[j], acc[i][j], 0, 0, 0);                      \
        } while (0)

    const int nt = Klen >> 5;   // even (>= 8) at all call sites
    STAGE(0, 0);
    __syncthreads();
    int t = 0;
    for (; t + 2 < nt; t += 2) {
        STAGE(1, (t + 1) * 32);
        COMPUTE(0);
        __syncthreads();
        STAGE(0, (t + 2) * 32);
        COMPUTE(1);
        __syncthreads();
    }
    // remainder: exactly 2 tiles left (nt even)
    STAGE(1, (t + 1) * 32);
    COMPUTE(0);
    __syncthreads();
    COMPUTE(1);
    #undef STAGE
    #undef COMPUTE

    const size_t zoff = (MODE == 5) ? (size_t)blockIdx.z * M * N : 0;
    const int cr = hi * 4;
    const int cc = lo;
    #pragma unroll
    for (int i = 0; i < 4; ++i) {
        #pragma unroll
        for (int r = 0; r < 4; ++r) {
            int m = m0 + wr * 64 + i * 16 + cr + r;
            if (MODE != 3 && m >= M) continue;
            #pragma unroll
            for (int j = 0; j < 4; ++j) {
                int n = n0 + wc * 64 + j * 16 + cc;
                float v = acc[i][j][r];
                if (MODE == 0) {
                    ((float*)Cout)[(size_t)m * N + n] = v + bias[n];
                } else if (MODE == 1) {
                    float t2 = v + bias[n];
                    t2 = 0.5f * t2 * (1.f + erff(t2 * 0.70710678118654752f));
                    ((u16*)Cout)[(size_t)m * N + n] = f2bf(t2);
                } else if (MODE == 2) {
                    ((float*)Cout)[(size_t)m * N + n] = v + bias[n] + res[(size_t)m * N + n];
                } else if (MODE == 4) {
                    ((u16*)Cout)[(size_t)m * N + n] = f2bf(v + bias[n]);
                } else if (MODE == 5) {
                    ((float*)Cout)[zoff + (size_t)m * N + n] = v;
                } else { // MODE 3
                    if (m < M && n < M) {
                        float* C3 = (float*)Cout + (size_t)blockIdx.z * LL * LL;
                        C3[(size_t)(m + 1) * LL + (n + 1)] = v * 0.03608439182435161f;
                    }
                }
            }
        }
    }
}

// x[i] += p0[i] + p1[i] + bias[i % N]   (split-K reduce, N % 4 == 0)
__global__ void splitk_reduce_kernel(float* __restrict__ x, const float* __restrict__ p,
                                     const float* __restrict__ bias, int MN, int N)
{
    int i4 = (blockIdx.x * 256 + threadIdx.x) * 4;
    if (i4 >= MN) return;
    float4 a  = *reinterpret_cast<const float4*>(x + i4);
    float4 p0 = *reinterpret_cast<const float4*>(p + i4);
    float4 p1 = *reinterpret_cast<const float4*>(p + (size_t)MN + i4);
    float4 b  = *reinterpret_cast<const float4*>(bias + (i4 % N));
    a.x += p0.x + p1.x + b.x;
    a.y += p0.y + p1.y + b.y;
    a.z += p0.z + p1.z + b.z;
    a.w += p0.w + p1.w + b.w;
    *reinterpret_cast<float4*>(x + i4) = a;
}

// Fused: x_row += p0+p1+fc2bias, then LayerNorm(x_row) -> bf16 out.
// One wave per row, 4 rows/block. partf now lives in scratch2 (toki/tokm
// region, dead after combine) — NO overlap with outb=hbuf (r13's race).
__global__ __launch_bounds__(256) void reduce_ln_kernel(
    float* __restrict__ x, const float* __restrict__ p,
    const float* __restrict__ bias,
    const float* __restrict__ g, const float* __restrict__ beta,
    u16* __restrict__ outb, int nrows)
{
    int row = blockIdx.x * 4 + (threadIdx.x >> 6);
    if (row >= nrows) return;
    int lane = threadIdx.x & 63;
    size_t MN = (size_t)nrows * DD;
    float4 v[3];
    #pragma unroll
    for (int pp = 0; pp < 3; ++pp) {
        int d0 = pp * 256 + lane * 4;
        size_t ix = (size_t)row * DD + d0;
        float4 xv = *reinterpret_cast<const float4*>(x + ix);
        float4 p0 = *reinterpret_cast<const float4*>(p + ix);
        float4 p1 = *reinterpret_cast<const float4*>(p + MN + ix);
        float4 bv = *reinterpret_cast<const float4*>(bias + d0);
        xv.x += p0.x + p1.x + bv.x;
        xv.y += p0.y + p1.y + bv.y;
        xv.z += p0.z + p1.z + bv.z;
        xv.w += p0.w + p1.w + bv.w;
        *reinterpret_cast<float4*>(x + ix) = xv;
        v[pp] = xv;
    }
    float s = 0.f;
    #pragma unroll
    for (int pp = 0; pp < 3; ++pp) s += v[pp].x + v[pp].y + v[pp].z + v[pp].w;
    #pragma unroll
    for (int off = 32; off; off >>= 1) s += __shfl_xor(s, off);
    float mean = s * (1.f / 768.f);
    float q = 0.f;
    #pragma unroll
    for (int pp = 0; pp < 3; ++pp) {
        float a = v[pp].x - mean, b = v[pp].y - mean, c = v[pp].z - mean, d = v[pp].w - mean;
        q += a * a + b * b + c * c + d * d;
    }
    #pragma unroll
    for (int off = 32; off; off >>= 1) q += __shfl_xor(q, off);
    float rstd = rsqrtf(q * (1.f / 768.f) + 1e-5f);
    #pragma unroll
    for (int pp = 0; pp < 3; ++pp) {
        int d0 = pp * 256 + lane * 4;
        float4 gg = *reinterpret_cast<const float4*>(g + d0);
        float4 bb = *reinterpret_cast<const float4*>(beta + d0);
        u16x4 ob = { f2bf(gg.x * (v[pp].x - mean) * rstd + bb.x),
                     f2bf(gg.y * (v[pp].y - mean) * rstd + bb.y),
                     f2bf(gg.z * (v[pp].z - mean) * rstd + bb.z),
                     f2bf(gg.w * (v[pp].w - mean) * rstd + bb.w) };
        *reinterpret_cast<u16x4*>(outb + (size_t)row * DD + d0) = ob;
    }
}

__global__ void bias_edge_kernel(float* __restrict__ bias)
{
    int b = blockIdx.x, t = threadIdx.x;
    if (t < LL) {
        bias[((size_t)b * LL + 0) * LL + t] = 0.f;
        bias[((size_t)b * LL + t) * LL + 0] = 0.f;
    }
}

// ---------------------------------------------------------------------------
__global__ void combine_kernel(
    const float* __restrict__ toki, const float* __restrict__ tokm,
    const float* __restrict__ cls, const float* __restrict__ pos,
    float* __restrict__ x)
{
    size_t idx = (size_t)blockIdx.x * 256 + threadIdx.x;
    if (idx >= (size_t)MROWS * DD) return;
    int d = (int)(idx % DD);
    size_t bl = idx / DD;
    int l = (int)(bl % LL);
    int b = (int)(bl / LL);
    float v;
    if (l == 0) v = cls[d];
    else {
        size_t tix = ((size_t)b * NTOK + (l - 1)) * DD + d;
        v = toki[tix] + 0.5f * tokm[tix];
    }
    x[idx] = v + pos[(size_t)l * DD + d];
}

// ---------------------------------------------------------------------------
// LayerNorm: one wave per row, shfl-only. 4 rows/block.
// ---------------------------------------------------------------------------
template<int OUT>
__global__ __launch_bounds__(256) void ln_kernel(
    const float* __restrict__ in, const float* __restrict__ g,
    const float* __restrict__ beta, float* __restrict__ outf,
    u16* __restrict__ outb, int nrows)
{
    int row = blockIdx.x * 4 + (threadIdx.x >> 6);
    if (row >= nrows) return;
    int lane = threadIdx.x & 63;
    const float* xr = in + (size_t)row * DD;
    float4 v[3];
    #pragma unroll
    for (int p = 0; p < 3; ++p)
        v[p] = *reinterpret_cast<const float4*>(xr + p * 256 + lane * 4);
    float s = 0.f;
    #pragma unroll
    for (int p = 0; p < 3; ++p) s += v[p].x + v[p].y + v[p].z + v[p].w;
    #pragma unroll
    for (int off = 32; off; off >>= 1) s += __shfl_xor(s, off);
    float mean = s * (1.f / 768.f);
    float q = 0.f;
    #pragma unroll
    for (int p = 0; p < 3; ++p) {
        float a = v[p].x - mean, b = v[p].y - mean, c = v[p].z - mean, d = v[p].w - mean;
        q += a * a + b * b + c * c + d * d;
    }
    #pragma unroll
    for (int off = 32; off; off >>= 1) q += __shfl_xor(q, off);
    float rstd = rsqrtf(q * (1.f / 768.f) + 1e-5f);
    #pragma unroll
    for (int p = 0; p < 3; ++p) {
        int d0 = p * 256 + lane * 4;
        float4 gg = *reinterpret_cast<const float4*>(g + d0);
        float4 bb = *reinterpret_cast<const float4*>(beta + d0);
        float o0 = gg.x * (v[p].x - mean) * rstd + bb.x;
        float o1 = gg.y * (v[p].y - mean) * rstd + bb.y;
        float o2 = gg.z * (v[p].z - mean) * rstd + bb.z;
        float o3 = gg.w * (v[p].w - mean) * rstd + bb.w;
        if (OUT == 0 || OUT == 2) {
            float4 of = make_float4(o0, o1, o2, o3);
            *reinterpret_cast<float4*>(outf + (size_t)row * DD + d0) = of;
        }
        if (OUT == 1 || OUT == 2) {
            u16x4 ob = { f2bf(o0), f2bf(o1), f2bf(o2), f2bf(o3) };
            *reinterpret_cast<u16x4*>(outb + (size_t)row * DD + d0) = ob;
        }
    }
}

// ---------------------------------------------------------------------------
// MFMA attention — 8 waves (r12-verified: -265 us vs 4-wave)
// ---------------------------------------------------------------------------
constexpr int KSTRE = 72;
constexpr int VSTRE = 232;
constexpr int PSTRE = 232;

__global__ __launch_bounds__(512) void attn_mfma_kernel(
    const u16* __restrict__ qkv, const float* __restrict__ bias,
    u16* __restrict__ o)
{
    const int h = blockIdx.x, b = blockIdx.y;
    const int tid = threadIdx.x, wave = tid >> 6, lane = tid & 63;
    const int lo = lane & 15, hi = lane >> 4;

    __shared__ u16 Ks[208 * KSTRE];
    __shared__ u16 Vt[64 * VSTRE];
    __shared__ u16 Ps[8][16 * PSTRE];

    const u16* qb = qkv + (size_t)b * LL * 2304;

    for (int idx = tid; idx < 208 * 8; idx += 512) {
        int key = idx >> 3, c8 = idx & 7;
        u16x8 v = {};
        if (key < LL) v = *reinterpret_cast<const u16x8*>(qb + (size_t)key * 2304 + 768 + h * 64 + c8 * 8);
        *reinterpret_cast<u16x8*>(&Ks[key * KSTRE + c8 * 8]) = v;
    }
    for (int idx = tid; idx < 224 * 8; idx += 512) {
        int key = idx >> 3, c8 = idx & 7;
        u16x8 v = {};
        if (key < LL) v = *reinterpret_cast<const u16x8*>(qb + (size_t)key * 2304 + 1536 + h * 64 + c8 * 8);
        #pragma unroll
        for (int e = 0; e < 8; ++e) Vt[(c8 * 8 + e) * VSTRE + key] = v[e];
    }
    __syncthreads();

    u16* P = Ps[wave];
    const float* biasbb = bias + (size_t)b * LL * LL;

    for (int rt = wave; rt < 13; rt += 8) {
        int q = rt * 16 + lo; if (q > LL - 1) q = LL - 1;
        const u16* qrow = qb + (size_t)q * 2304 + h * 64;
        bf16x8 qa0 = *reinterpret_cast<const bf16x8*>(qrow + hi * 8);
        bf16x8 qa1 = *reinterpret_cast<const bf16x8*>(qrow + 32 + hi * 8);

        f32x4 st[13];
        #pragma unroll
        for (int t = 0; t < 13; ++t) {
            int keyc = t * 16 + lo;
            bf16x8 kb0 = *reinterpret_cast<const bf16x8*>(&Ks[keyc * KSTRE + hi * 8]);
            bf16x8 kb1 = *reinterpret_cast<const bf16x8*>(&Ks[keyc * KSTRE + 32 + hi * 8]);
            f32x4 a = {};
            a = __builtin_amdgcn_mfma_f32_16x16x32_bf16(qa0, kb0, a, 0, 0, 0);
            a = __builtin_amdgcn_mfma_f32_16x16x32_bf16(qa1, kb1, a, 0, 0, 0);
            st[t] = a;
        }

        #pragma unroll
        for (int r = 0; r < 4; ++r) {
            int qq = rt * 16 + hi * 4 + r;
            int qc = qq > LL - 1 ? LL - 1 : qq;
            const float* brow = biasbb + (size_t)qc * LL;
            float s[13];
            float m = -1e30f;
            #pragma unroll
            for (int t = 0; t < 13; ++t) {
                int col = t * 16 + lo;
                float v;
                if (col < LL) v = st[t][r] * 0.125f + brow[col];
                else          v = -1e30f;
                s[t] = v;
                m = fmaxf(m, v);
            }
            m = fmaxf(m, __shfl_xor(m, 1));
            m = fmaxf(m, __shfl_xor(m, 2));
            m = fmaxf(m, __shfl_xor(m, 4));
            m = fmaxf(m, __shfl_xor(m, 8));
            float sum = 0.f;
            #pragma unroll
            for (int t = 0; t < 13; ++t) { float e = __expf(s[t] - m); s[t] = e; sum += e; }
            sum += __shfl_xor(sum, 1);
            sum += __shfl_xor(sum, 2);
            sum += __shfl_xor(sum, 4);
            sum += __shfl_xor(sum, 8);
            float inv = 1.f / sum;
            int prow = (hi * 4 + r) * PSTRE;
            #pragma unroll
            for (int t = 0; t < 13; ++t) P[prow + t * 16 + lo] = f2bf(s[t] * inv);
            P[prow + 208 + lo] = 0;
        }

        f32x4 oacc[4] = {};
        #pragma unroll
        for (int kt = 0; kt < 7; ++kt) {
            bf16x8 pa = *reinterpret_cast<const bf16x8*>(&P[lo * PSTRE + kt * 32 + hi * 8]);
            #pragma unroll
            for (int dt = 0; dt < 4; ++dt) {
                bf16x8 vb = *reinterpret_cast<const bf16x8*>(&Vt[(dt * 16 + lo) * VSTRE + kt * 32 + hi * 8]);
                oacc[dt] = __builtin_amdgcn_mfma_f32_16x16x32_bf16(pa, vb, oacc[dt], 0, 0, 0);
            }
        }

        #pragma unroll
        for (int dt = 0; dt < 4; ++dt) {
            #pragma unroll
            for (int r = 0; r < 4; ++r) {
                int qq = rt * 16 + hi * 4 + r;
                if (qq < LL)
                    o[((size_t)(b * LL + qq)) * DD + h * 64 + dt * 16 + lo] = f2bf(oacc[dt][r]);
            }
        }
    }
}

// ---------------------------------------------------------------------------
__global__ __launch_bounds__(256) void final_kernel(
    const float* __restrict__ x,
    const float* __restrict__ eg, const float* __restrict__ eb,
    const float* __restrict__ fg, const float* __restrict__ fb,
    const float* __restrict__ hw, const float* __restrict__ hb,
    float* __restrict__ out)
{
    int b = blockIdx.x;
    int tid = threadIdx.x;
    __shared__ float xs[768];
    __shared__ float red[256];
    const float* xr = x + (size_t)b * LL * DD;
    #pragma unroll
    for (int r = 0; r < 3; ++r) xs[tid + r * 256] = xr[tid + r * 256];
    __syncthreads();
    for (int pass = 0; pass < 2; ++pass) {
        const float* g  = pass ? fg : eg;
        const float* bb = pass ? fb : eb;
        red[tid] = xs[tid] + xs[tid + 256] + xs[tid + 512];
        __syncthreads();
        for (int off = 128; off; off >>= 1) {
            if (tid < off) red[tid] += red[tid + off];
            __syncthreads();
        }
        float mean = red[0] * (1.f / 768.f);
        __syncthreads();
        float q = 0.f;
        #pragma unroll
        for (int r = 0; r < 3; ++r) { float dv = xs[tid + r * 256] - mean; q += dv * dv; }
        red[tid] = q;
        __syncthreads();
        for (int off = 128; off; off >>= 1) {
            if (tid < off) red[tid] += red[tid + off];
            __syncthreads();
        }
        float rstd = rsqrtf(red[0] * (1.f / 768.f) + 1e-5f);
        __syncthreads();
        #pragma unroll
        for (int r = 0; r < 3; ++r) {
            int d = tid + r * 256;
            xs[d] = g[d] * (xs[d] - mean) * rstd + bb[d];
        }
        __syncthreads();
    }
    int c = tid >> 6, lane = tid & 63;
    float part = 0.f;
    for (int d = lane; d < 768; d += 64) part += xs[d] * hw[c * 768 + d];
    #pragma unroll
    for (int off = 32; off; off >>= 1) part += __shfl_down(part, off);
    if (lane == 0) out[b * 4 + c] = part + hb[c];
}

// ---------------------------------------------------------------------------
extern "C" void kernel_launch(void* const* d_in, const int* in_sizes, int n_in,
                              void* d_out, int out_size, void* d_ws, size_t ws_size,
                              hipStream_t stream)
{
    const float* img    = (const float*)d_in[0];
    const float* mask   = (const float*)d_in[1];
    const float* pe_iw  = (const float*)d_in[2];
    const float* pe_ib  = (const float*)d_in[3];
    const float* pe_ig  = (const float*)d_in[4];
    const float* pe_ibb = (const float*)d_in[5];
    const float* pe_mw  = (const float*)d_in[6];
    const float* pe_mb  = (const float*)d_in[7];
    const float* pe_mg  = (const float*)d_in[8];
    const float* pe_mbb = (const float*)d_in[9];
    const float* cls    = (const float*)d_in[10];
    const float* pos    = (const float*)d_in[11];
    const float* ln1_g  = (const float*)d_in[12];
    const float* ln1_b  = (const float*)d_in[13];
    const float* w_qkv  = (const float*)d_in[14];
    const float* b_qkv  = (const float*)d_in[15];
    const float* w_out  = (const float*)d_in[16];
    const float* b_out  = (const float*)d_in[17];
    const float* ln2_g  = (const float*)d_in[18];
    const float* ln2_b  = (const float*)d_in[19];
    const float* w_fc1  = (const float*)d_in[20];
    const float* b_fc1  = (const float*)d_in[21];
    const float* w_fc2  = (const float*)d_in[22];
    const float* b_fc2  = (const float*)d_in[23];
    const float* enc_g  = (const float*)d_in[24];
    const float* enc_b  = (const float*)d_in[25];
    const float* fin_g  = (const float*)d_in[26];
    const float* fin_b  = (const float*)d_in[27];
    const float* head_w = (const float*)d_in[28];
    const float* head_b = (const float*)d_in[29];

    char* wsb = (char*)d_ws;
    size_t off = 0;
    auto alloc = [&](size_t bytes) { void* p = wsb + off; off += (bytes + 255) & ~(size_t)255; return p; };

    float* x     = (float*)alloc((size_t)MROWS * DD * 4);
    u16*   qkvb  = (u16*)  alloc((size_t)MROWS * 3 * DD * 2);
    u16*   hbuf  = (u16*)  alloc((size_t)MROWS * DD * 2);
    u16*   fc1b  = (u16*)  alloc((size_t)MROWS * 4 * DD * 2);
    float* biasb = (float*)alloc((size_t)BB * LL * LL * 4);
    u16*   wqb   = (u16*)  alloc((size_t)3 * DD * DD * 2);
    u16*   wob   = (u16*)  alloc((size_t)DD * DD * 2);
    u16*   w1b   = (u16*)  alloc((size_t)4 * DD * DD * 2);
    u16*   w2b   = (u16*)  alloc((size_t)4 * DD * DD * 2);
    // scratch2 union: toki+tokm during setup (dead after combine) / split-K
    // partials during the layer loop. NO overlap with hbuf (r13's race fix).
    float* scratch2 = (float*)alloc((size_t)2 * MROWS * DD * 4);   // 38.73 MB
    float* toki  = scratch2;                          // MTOK*DD f32
    float* tokm  = scratch2 + (size_t)MTOK * DD;      // MTOK*DD f32
    float* partf = scratch2;                          // 2 x MROWS*DD f32
    u16*   pa    = fc1b;            // patches alias
    float* ttmp  = (float*)qkvb;    // pe-GEMM f32 out alias
    u16*   tokmb = hbuf;            // bf16 tok_m alias

    // ---- patch embed (img) ----
    cast_kernel<<<(DD * DD / 4 + 255) / 256, 256, 0, stream>>>(pe_iw, wob, DD * DD);
    patchify_kernel<<<(MTOK * DD + 255) / 256, 256, 0, stream>>>(img, 3, pa, MTOK * DD);
    gemm_bf16<0><<<dim3(DD / 128, MTOK / 128), 256, 0, stream>>>(
        pa, wob, pe_ib, nullptr, ttmp, MTOK, DD, DD, 0);
    ln_kernel<0><<<MTOK / 4, 256, 0, stream>>>(ttmp, pe_ig, pe_ibb, toki, nullptr, MTOK);

    // ---- patch embed (mask) ----
    cast_kernel<<<(DD * 256 / 4 + 255) / 256, 256, 0, stream>>>(pe_mw, wob, DD * 256);
    patchify_kernel<<<(MTOK * 256 + 255) / 256, 256, 0, stream>>>(mask, 1, pa, MTOK * 256);
    gemm_bf16<0><<<dim3(DD / 128, MTOK / 128), 256, 0, stream>>>(
        pa, wob, pe_mb, nullptr, ttmp, MTOK, DD, 256, 0);
    ln_kernel<2><<<MTOK / 4, 256, 0, stream>>>(ttmp, pe_mg, pe_mbb, tokm, tokmb, MTOK);

    // ---- attention bias ----
    gemm_bf16<3><<<dim3(2, 2, BB), 256, 0, stream>>>(
        tokmb, tokmb, nullptr, nullptr, biasb, NTOK, NTOK, DD, (long long)NTOK * DD);
    bias_edge_kernel<<<BB, 256, 0, stream>>>(biasb);

    // ---- combine + layer-0 ln1 ----
    combine_kernel<<<(MROWS * DD + 255) / 256, 256, 0, stream>>>(toki, tokm, cls, pos, x);
    ln_kernel<1><<<MROWS / 4, 256, 0, stream>>>(x, ln1_g, ln1_b, nullptr, hbuf, MROWS);

    const int mblk = (MROWS + 127) / 128;   // 50
    const int MN = MROWS * DD;
    const int wqn = 3 * DD * DD, won = DD * DD, w1n = 4 * DD * DD, w2n = 4 * DD * DD;
    const int castTot = (wqn + won + w1n + w2n) / 4;
    for (int l = 0; l < 12; ++l) {
        cast4_kernel<<<(castTot + 255) / 256, 256, 0, stream>>>(
            w_qkv + (size_t)l * wqn, wqn, w_out + (size_t)l * won, won,
            w_fc1 + (size_t)l * w1n, w1n, w_fc2 + (size_t)l * w2n, w2n,
            wqb, wob, w1b, w2b);
        gemm_bf16<4><<<dim3(3 * DD / 128, mblk), 256, 0, stream>>>(
            hbuf, wqb, b_qkv + l * 3 * DD, nullptr, qkvb, MROWS, 3 * DD, DD, 0);
        attn_mfma_kernel<<<dim3(HH, BB), 512, 0, stream>>>(qkvb, biasb, hbuf);
        gemm_bf16<2><<<dim3(DD / 128, mblk), 256, 0, stream>>>(
            hbuf, wob, b_out + l * DD, x, x, MROWS, DD, DD, 0);
        ln_kernel<1><<<MROWS / 4, 256, 0, stream>>>(x, ln2_g + l * DD, ln2_b + l * DD, nullptr, hbuf, MROWS);
        gemm_bf16<1><<<dim3(4 * DD / 128, mblk), 256, 0, stream>>>(
            hbuf, w1b, b_fc1 + l * 4 * DD, nullptr, fc1b, MROWS, 4 * DD, DD, 0);
        gemm_bf16<5><<<dim3(DD / 128, mblk, 2), 256, 0, stream>>>(
            fc1b, w2b, nullptr, nullptr, partf, MROWS, DD, 4 * DD, 0);
        if (l < 11) {
            // fused split-K reduce + next layer's ln1 (partf no longer aliases hbuf)
            reduce_ln_kernel<<<MROWS / 4, 256, 0, stream>>>(
                x, partf, b_fc2 + l * DD, ln1_g + (l + 1) * DD, ln1_b + (l + 1) * DD,
                hbuf, MROWS);
        } else {
            splitk_reduce_kernel<<<(MN / 4 + 255) / 256, 256, 0, stream>>>(
                x, partf, b_fc2 + l * DD, MN, DD);
        }
    }
    final_kernel<<<BB, 256, 0, stream>>>(x, enc_g, enc_b, fin_g, fin_b, head_w, head_b, (float*)d_out);
}

// Round 15
// 3220.529 us; speedup vs baseline: 1.6081x; 1.0083x over previous
//
#include <hip/hip_runtime.h>
#include <hip/hip_bf16.h>
#include <math.h>

typedef unsigned int   u32;
typedef unsigned short u16;
typedef __bf16 bf16x8 __attribute__((ext_vector_type(8)));
typedef float  f32x4  __attribute__((ext_vector_type(4)));
typedef u16    u16x8  __attribute__((ext_vector_type(8)));
typedef u16    u16x4  __attribute__((ext_vector_type(4)));

constexpr int BB = 32, DD = 768, LL = 197, HH = 12, NTOK = 196;
constexpr int MROWS = BB * LL;        // 6304
constexpr int MTOK  = BB * NTOK;      // 6272

__device__ __forceinline__ u16 f2bf(float f) {
    union { float f; u32 u; } v; v.f = f;
    u32 r = v.u + 0x7fff + ((v.u >> 16) & 1);
    return (u16)(r >> 16);
}
__device__ __forceinline__ float bf2f(u16 u) {
    union { u32 u; float f; } v; v.u = ((u32)u) << 16;
    return v.f;
}

#define AS1 __attribute__((address_space(1)))
#define AS3 __attribute__((address_space(3)))
__device__ __forceinline__ void gload_lds16(const void* g, void* l) {
    __builtin_amdgcn_global_load_lds((const AS1 u32*)g, (AS3 u32*)l, 16, 0, 0);
}

// ---------------------------------------------------------------------------
__global__ void cast_kernel(const float* __restrict__ in, u16* __restrict__ out, int n)
{
    int i4 = (blockIdx.x * 256 + threadIdx.x) * 4;
    if (i4 >= n) return;
    float4 v = *reinterpret_cast<const float4*>(in + i4);
    out[i4]   = f2bf(v.x); out[i4+1] = f2bf(v.y);
    out[i4+2] = f2bf(v.z); out[i4+3] = f2bf(v.w);
}

__global__ void cast4_kernel(const float* s0, int n0, const float* s1, int n1,
                             const float* s2, int n2, const float* s3, int n3,
                             u16* d0, u16* d1, u16* d2, u16* d3)
{
    int i4 = (blockIdx.x * 256 + threadIdx.x) * 4;
    const float* s; u16* d; int off;
    if      (i4 < n0)            { s = s0; d = d0; off = i4; }
    else if (i4 < n0+n1)         { s = s1; d = d1; off = i4 - n0; }
    else if (i4 < n0+n1+n2)      { s = s2; d = d2; off = i4 - n0 - n1; }
    else if (i4 < n0+n1+n2+n3)   { s = s3; d = d3; off = i4 - n0 - n1 - n2; }
    else return;
    float4 v = *reinterpret_cast<const float4*>(s + off);
    d[off]   = f2bf(v.x); d[off+1] = f2bf(v.y);
    d[off+2] = f2bf(v.z); d[off+3] = f2bf(v.w);
}

// ---------------------------------------------------------------------------
__global__ void patchify_kernel(const float* __restrict__ src, int C,
                                u16* __restrict__ out, int total)
{
    int idx = blockIdx.x * 256 + threadIdx.x;
    if (idx >= total) return;
    int K = C * 256;
    int row = idx / K, k = idx % K;
    int b = row / NTOK, n = row % NTOK;
    int c = k >> 8, rem = k & 255, pi = rem >> 4, pj = rem & 15;
    int i14 = n / 14, j14 = n % 14;
    float v = src[(((size_t)b * C + c) * 224 + i14 * 16 + pi) * 224 + j14 * 16 + pj];
    out[idx] = f2bf(v);
}

// ---------------------------------------------------------------------------
// bf16 MFMA GEMM — 256x128 tile, 8 waves (512 thr), BK=32.
// Same verified pieces as r14: row-contiguous XOR-swizzle staging
// (conflict-free ds_read, r11-verified), single-barrier double-buffer K-loop
// (r14-verified: VALUBusy 41->29, -5us/dispatch). Scaled so each barrier
// covers 2x FLOPs and B-panel reuse doubles (24KB staged per 4.2 MFLOP vs
// 16KB per 2.1 MFLOP).
// Wave w (wr=w>>1 in 0..3, wc=w&1): output 64x64 at (wr*64, wc*64).
// A: 16 units of 16 rows; wave stages units {w, w+8}. B: 8 units; wave
// stages unit w. Unit-internal lane map unchanged (row=l>>2, chunk XOR).
// LDS 48KB -> 3 blocks/CU (24 waves/CU).
// nt = Klen/32 even at all call sites (K = 256, 768, 1536, 3072).
// MODE 0: f32 +bias   MODE 1: GELU->bf16 +bias   MODE 2: f32 +bias+res
// MODE 3: batched bias-GEMM   MODE 4: bf16 +bias
// MODE 5: split-K=2, raw f32 partial store to Cout + z*M*N (no bias)
// ---------------------------------------------------------------------------
template<int MODE>
__global__ __launch_bounds__(512) void gemm_bf16(
    const u16* __restrict__ A, const u16* __restrict__ W,
    const float* __restrict__ bias, const float* __restrict__ res,
    void* __restrict__ Cout, int M, int N, int K, long long strideA)
{
    __shared__ u16 As[2][8192];   // 256 rows x 32 k
    __shared__ u16 Bs[2][4096];   // 128 rows x 32 k
    const int tid  = threadIdx.x;
    const int wave = tid >> 6, lane = tid & 63;
    const int lo = lane & 15, hi = lane >> 4;
    const int wr = wave >> 1, wc = wave & 1;

    const int m0 = blockIdx.y * 256, n0 = blockIdx.x * 128;
    if (MODE == 3) { A += blockIdx.z * strideA; W += blockIdx.z * strideA; }

    const int Klen = (MODE == 5) ? (K >> 1) : K;
    const int kb   = (MODE == 5) ? blockIdx.z * Klen : 0;

    const int limA = M - 1;
    const int limB = (MODE == 3 ? M : N) - 1;
    const int srow = lane >> 2;
    const int scol = ((lane & 3) ^ ((lane >> 3) & 3)) << 3;
    int ra0 = m0 + wave * 16 + srow;        if (ra0 > limA) ra0 = limA;
    int ra1 = m0 + 128 + wave * 16 + srow;  if (ra1 > limA) ra1 = limA;
    int rb0 = n0 + wave * 16 + srow;        if (rb0 > limB) rb0 = limB;
    const u16* Arow0 = A + (size_t)ra0 * K + kb + scol;
    const u16* Arow1 = A + (size_t)ra1 * K + kb + scol;
    const u16* Brow0 = W + (size_t)rb0 * K + kb + scol;

    const int fro = lo * 32 + ((hi ^ ((lo >> 1) & 3)) << 3);

    f32x4 acc[4][4] = {};

    #define STAGE(bf_, k0_)                                         \
        do {                                                        \
            gload_lds16(Arow0 + (k0_), &As[bf_][wave * 512]);       \
            gload_lds16(Arow1 + (k0_), &As[bf_][4096 + wave * 512]);\
            gload_lds16(Brow0 + (k0_), &Bs[bf_][wave * 512]);       \
        } while (0)

    #define COMPUTE(bf_)                                                         \
        do {                                                                     \
            bf16x8 af[4], bfr[4];                                                \
            _Pragma("unroll")                                                    \
            for (int i = 0; i < 4; ++i)                                          \
                af[i] = *reinterpret_cast<const bf16x8*>(                        \
                    &As[bf_][(wr * 4 + i) * 512 + fro]);                         \
            _Pragma("unroll")                                                    \
            for (int j = 0; j < 4; ++j)                                          \
                bfr[j] = *reinterpret_cast<const bf16x8*>(                       \
                    &Bs[bf_][(wc * 4 + j) * 512 + fro]);                         \
            _Pragma("unroll")                                                    \
            for (int i = 0; i < 4; ++i)                                          \
                _Pragma("unroll")                                                \
                for (int j = 0; j < 4; ++j)                                      \
                    acc[i][j] = __builtin_amdgcn_mfma_f32_16x16x32_bf16(         \
                        af[i], bfr[j], acc[i][j], 0, 0, 0);                      \
        } while (0)

    const int nt = Klen >> 5;   // even (>= 8) at all call sites
    STAGE(0, 0);
    __syncthreads();
    int t = 0;
    for (; t + 2 < nt; t += 2) {
        STAGE(1, (t + 1) * 32);
        COMPUTE(0);
        __syncthreads();
        STAGE(0, (t + 2) * 32);
        COMPUTE(1);
        __syncthreads();
    }
    // remainder: exactly 2 tiles left (nt even)
    STAGE(1, (t + 1) * 32);
    COMPUTE(0);
    __syncthreads();
    COMPUTE(1);
    #undef STAGE
    #undef COMPUTE

    const size_t zoff = (MODE == 5) ? (size_t)blockIdx.z * M * N : 0;
    const int cr = hi * 4;
    const int cc = lo;
    #pragma unroll
    for (int i = 0; i < 4; ++i) {
        #pragma unroll
        for (int r = 0; r < 4; ++r) {
            int m = m0 + wr * 64 + i * 16 + cr + r;
            if (MODE != 3 && m >= M) continue;
            #pragma unroll
            for (int j = 0; j < 4; ++j) {
                int n = n0 + wc * 64 + j * 16 + cc;
                float v = acc[i][j][r];
                if (MODE == 0) {
                    ((float*)Cout)[(size_t)m * N + n] = v + bias[n];
                } else if (MODE == 1) {
                    float t2 = v + bias[n];
                    t2 = 0.5f * t2 * (1.f + erff(t2 * 0.70710678118654752f));
                    ((u16*)Cout)[(size_t)m * N + n] = f2bf(t2);
                } else if (MODE == 2) {
                    ((float*)Cout)[(size_t)m * N + n] = v + bias[n] + res[(size_t)m * N + n];
                } else if (MODE == 4) {
                    ((u16*)Cout)[(size_t)m * N + n] = f2bf(v + bias[n]);
                } else if (MODE == 5) {
                    ((float*)Cout)[zoff + (size_t)m * N + n] = v;
                } else { // MODE 3
                    if (m < M && n < M) {
                        float* C3 = (float*)Cout + (size_t)blockIdx.z * LL * LL;
                        C3[(size_t)(m + 1) * LL + (n + 1)] = v * 0.03608439182435161f;
                    }
                }
            }
        }
    }
}

// x[i] += p0[i] + p1[i] + bias[i % N]   (split-K reduce, N % 4 == 0)
__global__ void splitk_reduce_kernel(float* __restrict__ x, const float* __restrict__ p,
                                     const float* __restrict__ bias, int MN, int N)
{
    int i4 = (blockIdx.x * 256 + threadIdx.x) * 4;
    if (i4 >= MN) return;
    float4 a  = *reinterpret_cast<const float4*>(x + i4);
    float4 p0 = *reinterpret_cast<const float4*>(p + i4);
    float4 p1 = *reinterpret_cast<const float4*>(p + (size_t)MN + i4);
    float4 b  = *reinterpret_cast<const float4*>(bias + (i4 % N));
    a.x += p0.x + p1.x + b.x;
    a.y += p0.y + p1.y + b.y;
    a.z += p0.z + p1.z + b.z;
    a.w += p0.w + p1.w + b.w;
    *reinterpret_cast<float4*>(x + i4) = a;
}

// Fused: x_row += p0+p1+fc2bias, then LayerNorm(x_row) -> bf16 out.
// partf lives in scratch2 (disjoint from outb=hbuf) — r14-verified.
__global__ __launch_bounds__(256) void reduce_ln_kernel(
    float* __restrict__ x, const float* __restrict__ p,
    const float* __restrict__ bias,
    const float* __restrict__ g, const float* __restrict__ beta,
    u16* __restrict__ outb, int nrows)
{
    int row = blockIdx.x * 4 + (threadIdx.x >> 6);
    if (row >= nrows) return;
    int lane = threadIdx.x & 63;
    size_t MN = (size_t)nrows * DD;
    float4 v[3];
    #pragma unroll
    for (int pp = 0; pp < 3; ++pp) {
        int d0 = pp * 256 + lane * 4;
        size_t ix = (size_t)row * DD + d0;
        float4 xv = *reinterpret_cast<const float4*>(x + ix);
        float4 p0 = *reinterpret_cast<const float4*>(p + ix);
        float4 p1 = *reinterpret_cast<const float4*>(p + MN + ix);
        float4 bv = *reinterpret_cast<const float4*>(bias + d0);
        xv.x += p0.x + p1.x + bv.x;
        xv.y += p0.y + p1.y + bv.y;
        xv.z += p0.z + p1.z + bv.z;
        xv.w += p0.w + p1.w + bv.w;
        *reinterpret_cast<float4*>(x + ix) = xv;
        v[pp] = xv;
    }
    float s = 0.f;
    #pragma unroll
    for (int pp = 0; pp < 3; ++pp) s += v[pp].x + v[pp].y + v[pp].z + v[pp].w;
    #pragma unroll
    for (int off = 32; off; off >>= 1) s += __shfl_xor(s, off);
    float mean = s * (1.f / 768.f);
    float q = 0.f;
    #pragma unroll
    for (int pp = 0; pp < 3; ++pp) {
        float a = v[pp].x - mean, b = v[pp].y - mean, c = v[pp].z - mean, d = v[pp].w - mean;
        q += a * a + b * b + c * c + d * d;
    }
    #pragma unroll
    for (int off = 32; off; off >>= 1) q += __shfl_xor(q, off);
    float rstd = rsqrtf(q * (1.f / 768.f) + 1e-5f);
    #pragma unroll
    for (int pp = 0; pp < 3; ++pp) {
        int d0 = pp * 256 + lane * 4;
        float4 gg = *reinterpret_cast<const float4*>(g + d0);
        float4 bb = *reinterpret_cast<const float4*>(beta + d0);
        u16x4 ob = { f2bf(gg.x * (v[pp].x - mean) * rstd + bb.x),
                     f2bf(gg.y * (v[pp].y - mean) * rstd + bb.y),
                     f2bf(gg.z * (v[pp].z - mean) * rstd + bb.z),
                     f2bf(gg.w * (v[pp].w - mean) * rstd + bb.w) };
        *reinterpret_cast<u16x4*>(outb + (size_t)row * DD + d0) = ob;
    }
}

__global__ void bias_edge_kernel(float* __restrict__ bias)
{
    int b = blockIdx.x, t = threadIdx.x;
    if (t < LL) {
        bias[((size_t)b * LL + 0) * LL + t] = 0.f;
        bias[((size_t)b * LL + t) * LL + 0] = 0.f;
    }
}

// ---------------------------------------------------------------------------
__global__ void combine_kernel(
    const float* __restrict__ toki, const float* __restrict__ tokm,
    const float* __restrict__ cls, const float* __restrict__ pos,
    float* __restrict__ x)
{
    size_t idx = (size_t)blockIdx.x * 256 + threadIdx.x;
    if (idx >= (size_t)MROWS * DD) return;
    int d = (int)(idx % DD);
    size_t bl = idx / DD;
    int l = (int)(bl % LL);
    int b = (int)(bl / LL);
    float v;
    if (l == 0) v = cls[d];
    else {
        size_t tix = ((size_t)b * NTOK + (l - 1)) * DD + d;
        v = toki[tix] + 0.5f * tokm[tix];
    }
    x[idx] = v + pos[(size_t)l * DD + d];
}

// ---------------------------------------------------------------------------
// LayerNorm: one wave per row, shfl-only. 4 rows/block.
// ---------------------------------------------------------------------------
template<int OUT>
__global__ __launch_bounds__(256) void ln_kernel(
    const float* __restrict__ in, const float* __restrict__ g,
    const float* __restrict__ beta, float* __restrict__ outf,
    u16* __restrict__ outb, int nrows)
{
    int row = blockIdx.x * 4 + (threadIdx.x >> 6);
    if (row >= nrows) return;
    int lane = threadIdx.x & 63;
    const float* xr = in + (size_t)row * DD;
    float4 v[3];
    #pragma unroll
    for (int p = 0; p < 3; ++p)
        v[p] = *reinterpret_cast<const float4*>(xr + p * 256 + lane * 4);
    float s = 0.f;
    #pragma unroll
    for (int p = 0; p < 3; ++p) s += v[p].x + v[p].y + v[p].z + v[p].w;
    #pragma unroll
    for (int off = 32; off; off >>= 1) s += __shfl_xor(s, off);
    float mean = s * (1.f / 768.f);
    float q = 0.f;
    #pragma unroll
    for (int p = 0; p < 3; ++p) {
        float a = v[p].x - mean, b = v[p].y - mean, c = v[p].z - mean, d = v[p].w - mean;
        q += a * a + b * b + c * c + d * d;
    }
    #pragma unroll
    for (int off = 32; off; off >>= 1) q += __shfl_xor(q, off);
    float rstd = rsqrtf(q * (1.f / 768.f) + 1e-5f);
    #pragma unroll
    for (int p = 0; p < 3; ++p) {
        int d0 = p * 256 + lane * 4;
        float4 gg = *reinterpret_cast<const float4*>(g + d0);
        float4 bb = *reinterpret_cast<const float4*>(beta + d0);
        float o0 = gg.x * (v[p].x - mean) * rstd + bb.x;
        float o1 = gg.y * (v[p].y - mean) * rstd + bb.y;
        float o2 = gg.z * (v[p].z - mean) * rstd + bb.z;
        float o3 = gg.w * (v[p].w - mean) * rstd + bb.w;
        if (OUT == 0 || OUT == 2) {
            float4 of = make_float4(o0, o1, o2, o3);
            *reinterpret_cast<float4*>(outf + (size_t)row * DD + d0) = of;
        }
        if (OUT == 1 || OUT == 2) {
            u16x4 ob = { f2bf(o0), f2bf(o1), f2bf(o2), f2bf(o3) };
            *reinterpret_cast<u16x4*>(outb + (size_t)row * DD + d0) = ob;
        }
    }
}

// ---------------------------------------------------------------------------
// MFMA attention — 8 waves (r12-verified)
// ---------------------------------------------------------------------------
constexpr int KSTRE = 72;
constexpr int VSTRE = 232;
constexpr int PSTRE = 232;

__global__ __launch_bounds__(512) void attn_mfma_kernel(
    const u16* __restrict__ qkv, const float* __restrict__ bias,
    u16* __restrict__ o)
{
    const int h = blockIdx.x, b = blockIdx.y;
    const int tid = threadIdx.x, wave = tid >> 6, lane = tid & 63;
    const int lo = lane & 15, hi = lane >> 4;

    __shared__ u16 Ks[208 * KSTRE];
    __shared__ u16 Vt[64 * VSTRE];
    __shared__ u16 Ps[8][16 * PSTRE];

    const u16* qb = qkv + (size_t)b * LL * 2304;

    for (int idx = tid; idx < 208 * 8; idx += 512) {
        int key = idx >> 3, c8 = idx & 7;
        u16x8 v = {};
        if (key < LL) v = *reinterpret_cast<const u16x8*>(qb + (size_t)key * 2304 + 768 + h * 64 + c8 * 8);
        *reinterpret_cast<u16x8*>(&Ks[key * KSTRE + c8 * 8]) = v;
    }
    for (int idx = tid; idx < 224 * 8; idx += 512) {
        int key = idx >> 3, c8 = idx & 7;
        u16x8 v = {};
        if (key < LL) v = *reinterpret_cast<const u16x8*>(qb + (size_t)key * 2304 + 1536 + h * 64 + c8 * 8);
        #pragma unroll
        for (int e = 0; e < 8; ++e) Vt[(c8 * 8 + e) * VSTRE + key] = v[e];
    }
    __syncthreads();

    u16* P = Ps[wave];
    const float* biasbb = bias + (size_t)b * LL * LL;

    for (int rt = wave; rt < 13; rt += 8) {
        int q = rt * 16 + lo; if (q > LL - 1) q = LL - 1;
        const u16* qrow = qb + (size_t)q * 2304 + h * 64;
        bf16x8 qa0 = *reinterpret_cast<const bf16x8*>(qrow + hi * 8);
        bf16x8 qa1 = *reinterpret_cast<const bf16x8*>(qrow + 32 + hi * 8);

        f32x4 st[13];
        #pragma unroll
        for (int t = 0; t < 13; ++t) {
            int keyc = t * 16 + lo;
            bf16x8 kb0 = *reinterpret_cast<const bf16x8*>(&Ks[keyc * KSTRE + hi * 8]);
            bf16x8 kb1 = *reinterpret_cast<const bf16x8*>(&Ks[keyc * KSTRE + 32 + hi * 8]);
            f32x4 a = {};
            a = __builtin_amdgcn_mfma_f32_16x16x32_bf16(qa0, kb0, a, 0, 0, 0);
            a = __builtin_amdgcn_mfma_f32_16x16x32_bf16(qa1, kb1, a, 0, 0, 0);
            st[t] = a;
        }

        #pragma unroll
        for (int r = 0; r < 4; ++r) {
            int qq = rt * 16 + hi * 4 + r;
            int qc = qq > LL - 1 ? LL - 1 : qq;
            const float* brow = biasbb + (size_t)qc * LL;
            float s[13];
            float m = -1e30f;
            #pragma unroll
            for (int t = 0; t < 13; ++t) {
                int col = t * 16 + lo;
                float v;
                if (col < LL) v = st[t][r] * 0.125f + brow[col];
                else          v = -1e30f;
                s[t] = v;
                m = fmaxf(m, v);
            }
            m = fmaxf(m, __shfl_xor(m, 1));
            m = fmaxf(m, __shfl_xor(m, 2));
            m = fmaxf(m, __shfl_xor(m, 4));
            m = fmaxf(m, __shfl_xor(m, 8));
            float sum = 0.f;
            #pragma unroll
            for (int t = 0; t < 13; ++t) { float e = __expf(s[t] - m); s[t] = e; sum += e; }
            sum += __shfl_xor(sum, 1);
            sum += __shfl_xor(sum, 2);
            sum += __shfl_xor(sum, 4);
            sum += __shfl_xor(sum, 8);
            float inv = 1.f / sum;
            int prow = (hi * 4 + r) * PSTRE;
            #pragma unroll
            for (int t = 0; t < 13; ++t) P[prow + t * 16 + lo] = f2bf(s[t] * inv);
            P[prow + 208 + lo] = 0;
        }

        f32x4 oacc[4] = {};
        #pragma unroll
        for (int kt = 0; kt < 7; ++kt) {
            bf16x8 pa = *reinterpret_cast<const bf16x8*>(&P[lo * PSTRE + kt * 32 + hi * 8]);
            #pragma unroll
            for (int dt = 0; dt < 4; ++dt) {
                bf16x8 vb = *reinterpret_cast<const bf16x8*>(&Vt[(dt * 16 + lo) * VSTRE + kt * 32 + hi * 8]);
                oacc[dt] = __builtin_amdgcn_mfma_f32_16x16x32_bf16(pa, vb, oacc[dt], 0, 0, 0);
            }
        }

        #pragma unroll
        for (int dt = 0; dt < 4; ++dt) {
            #pragma unroll
            for (int r = 0; r < 4; ++r) {
                int qq = rt * 16 + hi * 4 + r;
                if (qq < LL)
                    o[((size_t)(b * LL + qq)) * DD + h * 64 + dt * 16 + lo] = f2bf(oacc[dt][r]);
            }
        }
    }
}

// ---------------------------------------------------------------------------
__global__ __launch_bounds__(256) void final_kernel(
    const float* __restrict__ x,
    const float* __restrict__ eg, const float* __restrict__ eb,
    const float* __restrict__ fg, const float* __restrict__ fb,
    const float* __restrict__ hw, const float* __restrict__ hb,
    float* __restrict__ out)
{
    int b = blockIdx.x;
    int tid = threadIdx.x;
    __shared__ float xs[768];
    __shared__ float red[256];
    const float* xr = x + (size_t)b * LL * DD;
    #pragma unroll
    for (int r = 0; r < 3; ++r) xs[tid + r * 256] = xr[tid + r * 256];
    __syncthreads();
    for (int pass = 0; pass < 2; ++pass) {
        const float* g  = pass ? fg : eg;
        const float* bb = pass ? fb : eb;
        red[tid] = xs[tid] + xs[tid + 256] + xs[tid + 512];
        __syncthreads();
        for (int off = 128; off; off >>= 1) {
            if (tid < off) red[tid] += red[tid + off];
            __syncthreads();
        }
        float mean = red[0] * (1.f / 768.f);
        __syncthreads();
        float q = 0.f;
        #pragma unroll
        for (int r = 0; r < 3; ++r) { float dv = xs[tid + r * 256] - mean; q += dv * dv; }
        red[tid] = q;
        __syncthreads();
        for (int off = 128; off; off >>= 1) {
            if (tid < off) red[tid] += red[tid + off];
            __syncthreads();
        }
        float rstd = rsqrtf(red[0] * (1.f / 768.f) + 1e-5f);
        __syncthreads();
        #pragma unroll
        for (int r = 0; r < 3; ++r) {
            int d = tid + r * 256;
            xs[d] = g[d] * (xs[d] - mean) * rstd + bb[d];
        }
        __syncthreads();
    }
    int c = tid >> 6, lane = tid & 63;
    float part = 0.f;
    for (int d = lane; d < 768; d += 64) part += xs[d] * hw[c * 768 + d];
    #pragma unroll
    for (int off = 32; off; off >>= 1) part += __shfl_down(part, off);
    if (lane == 0) out[b * 4 + c] = part + hb[c];
}

// ---------------------------------------------------------------------------
extern "C" void kernel_launch(void* const* d_in, const int* in_sizes, int n_in,
                              void* d_out, int out_size, void* d_ws, size_t ws_size,
                              hipStream_t stream)
{
    const float* img    = (const float*)d_in[0];
    const float* mask   = (const float*)d_in[1];
    const float* pe_iw  = (const float*)d_in[2];
    const float* pe_ib  = (const float*)d_in[3];
    const float* pe_ig  = (const float*)d_in[4];
    const float* pe_ibb = (const float*)d_in[5];
    const float* pe_mw  = (const float*)d_in[6];
    const float* pe_mb  = (const float*)d_in[7];
    const float* pe_mg  = (const float*)d_in[8];
    const float* pe_mbb = (const float*)d_in[9];
    const float* cls    = (const float*)d_in[10];
    const float* pos    = (const float*)d_in[11];
    const float* ln1_g  = (const float*)d_in[12];
    const float* ln1_b  = (const float*)d_in[13];
    const float* w_qkv  = (const float*)d_in[14];
    const float* b_qkv  = (const float*)d_in[15];
    const float* w_out  = (const float*)d_in[16];
    const float* b_out  = (const float*)d_in[17];
    const float* ln2_g  = (const float*)d_in[18];
    const float* ln2_b  = (const float*)d_in[19];
    const float* w_fc1  = (const float*)d_in[20];
    const float* b_fc1  = (const float*)d_in[21];
    const float* w_fc2  = (const float*)d_in[22];
    const float* b_fc2  = (const float*)d_in[23];
    const float* enc_g  = (const float*)d_in[24];
    const float* enc_b  = (const float*)d_in[25];
    const float* fin_g  = (const float*)d_in[26];
    const float* fin_b  = (const float*)d_in[27];
    const float* head_w = (const float*)d_in[28];
    const float* head_b = (const float*)d_in[29];

    char* wsb = (char*)d_ws;
    size_t off = 0;
    auto alloc = [&](size_t bytes) { void* p = wsb + off; off += (bytes + 255) & ~(size_t)255; return p; };

    float* x     = (float*)alloc((size_t)MROWS * DD * 4);
    u16*   qkvb  = (u16*)  alloc((size_t)MROWS * 3 * DD * 2);
    u16*   hbuf  = (u16*)  alloc((size_t)MROWS * DD * 2);
    u16*   fc1b  = (u16*)  alloc((size_t)MROWS * 4 * DD * 2);
    float* biasb = (float*)alloc((size_t)BB * LL * LL * 4);
    u16*   wqb   = (u16*)  alloc((size_t)3 * DD * DD * 2);
    u16*   wob   = (u16*)  alloc((size_t)DD * DD * 2);
    u16*   w1b   = (u16*)  alloc((size_t)4 * DD * DD * 2);
    u16*   w2b   = (u16*)  alloc((size_t)4 * DD * DD * 2);
    // scratch2 union: toki+tokm during setup / split-K partials during loop
    float* scratch2 = (float*)alloc((size_t)2 * MROWS * DD * 4);
    float* toki  = scratch2;
    float* tokm  = scratch2 + (size_t)MTOK * DD;
    float* partf = scratch2;
    u16*   pa    = fc1b;
    float* ttmp  = (float*)qkvb;
    u16*   tokmb = hbuf;

    // ---- patch embed (img) ----
    cast_kernel<<<(DD * DD / 4 + 255) / 256, 256, 0, stream>>>(pe_iw, wob, DD * DD);
    patchify_kernel<<<(MTOK * DD + 255) / 256, 256, 0, stream>>>(img, 3, pa, MTOK * DD);
    gemm_bf16<0><<<dim3(DD / 128, (MTOK + 255) / 256), 512, 0, stream>>>(
        pa, wob, pe_ib, nullptr, ttmp, MTOK, DD, DD, 0);
    ln_kernel<0><<<MTOK / 4, 256, 0, stream>>>(ttmp, pe_ig, pe_ibb, toki, nullptr, MTOK);

    // ---- patch embed (mask) ----
    cast_kernel<<<(DD * 256 / 4 + 255) / 256, 256, 0, stream>>>(pe_mw, wob, DD * 256);
    patchify_kernel<<<(MTOK * 256 + 255) / 256, 256, 0, stream>>>(mask, 1, pa, MTOK * 256);
    gemm_bf16<0><<<dim3(DD / 128, (MTOK + 255) / 256), 512, 0, stream>>>(
        pa, wob, pe_mb, nullptr, ttmp, MTOK, DD, 256, 0);
    ln_kernel<2><<<MTOK / 4, 256, 0, stream>>>(ttmp, pe_mg, pe_mbb, tokm, tokmb, MTOK);

    // ---- attention bias ----
    gemm_bf16<3><<<dim3(2, 1, BB), 512, 0, stream>>>(
        tokmb, tokmb, nullptr, nullptr, biasb, NTOK, NTOK, DD, (long long)NTOK * DD);
    bias_edge_kernel<<<BB, 256, 0, stream>>>(biasb);

    // ---- combine + layer-0 ln1 ----
    combine_kernel<<<(MROWS * DD + 255) / 256, 256, 0, stream>>>(toki, tokm, cls, pos, x);
    ln_kernel<1><<<MROWS / 4, 256, 0, stream>>>(x, ln1_g, ln1_b, nullptr, hbuf, MROWS);

    const int mblk = (MROWS + 255) / 256;   // 25
    const int MN = MROWS * DD;
    const int wqn = 3 * DD * DD, won = DD * DD, w1n = 4 * DD * DD, w2n = 4 * DD * DD;
    const int castTot = (wqn + won + w1n + w2n) / 4;
    for (int l = 0; l < 12; ++l) {
        cast4_kernel<<<(castTot + 255) / 256, 256, 0, stream>>>(
            w_qkv + (size_t)l * wqn, wqn, w_out + (size_t)l * won, won,
            w_fc1 + (size_t)l * w1n, w1n, w_fc2 + (size_t)l * w2n, w2n,
            wqb, wob, w1b, w2b);
        gemm_bf16<4><<<dim3(3 * DD / 128, mblk), 512, 0, stream>>>(
            hbuf, wqb, b_qkv + l * 3 * DD, nullptr, qkvb, MROWS, 3 * DD, DD, 0);
        attn_mfma_kernel<<<dim3(HH, BB), 512, 0, stream>>>(qkvb, biasb, hbuf);
        gemm_bf16<2><<<dim3(DD / 128, mblk), 512, 0, stream>>>(
            hbuf, wob, b_out + l * DD, x, x, MROWS, DD, DD, 0);
        ln_kernel<1><<<MROWS / 4, 256, 0, stream>>>(x, ln2_g + l * DD, ln2_b + l * DD, nullptr, hbuf, MROWS);
        gemm_bf16<1><<<dim3(4 * DD / 128, mblk), 512, 0, stream>>>(
            hbuf, w1b, b_fc1 + l * 4 * DD, nullptr, fc1b, MROWS, 4 * DD, DD, 0);
        gemm_bf16<5><<<dim3(DD / 128, mblk, 2), 512, 0, stream>>>(
            fc1b, w2b, nullptr, nullptr, partf, MROWS, DD, 4 * DD, 0);
        if (l < 11) {
            reduce_ln_kernel<<<MROWS / 4, 256, 0, stream>>>(
                x, partf, b_fc2 + l * DD, ln1_g + (l + 1) * DD, ln1_b + (l + 1) * DD,
                hbuf, MROWS);
        } else {
            splitk_reduce_kernel<<<(MN / 4 + 255) / 256, 256, 0, stream>>>(
                x, partf, b_fc2 + l * DD, MN, DD);
        }
    }
    final_kernel<<<BB, 256, 0, stream>>>(x, enc_g, enc_b, fin_g, fin_b, head_w, head_b, (float*)d_out);
}